// Round 7
// baseline (459.789 us; speedup 1.0000x reference)
//
#include <hip/hip_runtime.h>
#include <hip/hip_bf16.h>

#define BB 4
#define TT 1024
#define DD 1024
#define HH 16
#define DKK 64
#define FFF 4096

typedef unsigned short u16;
typedef unsigned int u32;
typedef __attribute__((ext_vector_type(8))) short s16x8;
typedef __attribute__((ext_vector_type(4))) float f32x4;

static __device__ __forceinline__ float bf2f(u16 s) {
  union { u32 u; float f; } v; v.u = ((u32)s) << 16; return v.f;
}
static __device__ __forceinline__ u16 f2bf(float f) {
  union { float f; u32 u; } v; v.f = f;
  u32 r = v.u + 0x7FFFu + ((v.u >> 16) & 1u);
  return (u16)(r >> 16);
}

#define GLDS(gp, lp) __builtin_amdgcn_global_load_lds( \
    (const __attribute__((address_space(1))) u32*)(gp), \
    (__attribute__((address_space(3))) u32*)(lp), 16, 0, 0)

// XCD-chunked bijective block swizzle (m204 formula), 8-row supertiles.
static __device__ __forceinline__ void swz_block(int& bx, int& by) {
  int gx = gridDim.x, gy = gridDim.y;
  int nwg = gx * gy;
  int orig = by * gx + bx;
  int q = nwg >> 3, r = nwg & 7;
  int xcd = orig & 7, sl = orig >> 3;
  int wgid = (xcd < r ? xcd * (q + 1) : r * (q + 1) + (xcd - r) * q) + sl;
  int g = gx << 3;
  int grp = wgid / g, rem = wgid % g;
  bx = rem >> 3;
  by = (grp << 3) + (rem & 7);
}

// ---------------- f32 -> bf16 elementwise ----------------
__global__ __launch_bounds__(256) void k_f2bf(const float* __restrict__ s, u16* __restrict__ d, int n) {
  int i = (blockIdx.x * 256 + threadIdx.x) * 4;
  if (i < n) {
    float4 v = *(const float4*)(s + i);
    u16 o[4] = { f2bf(v.x), f2bf(v.y), f2bf(v.z), f2bf(v.w) };
    *(ushort4*)(d + i) = *(ushort4*)o;
  }
}

// ---------------- x passthrough to d_out + bf16 convert, one read ----------------
__global__ __launch_bounds__(256) void k_xprep(const float* __restrict__ x, float* __restrict__ dout,
                                               u16* __restrict__ xb, int n) {
  int i = (blockIdx.x * 256 + threadIdx.x) * 4;
  if (i < n) {
    float4 v = *(const float4*)(x + i);
    *(float4*)(dout + i) = v;
    u16 o[4] = { f2bf(v.x), f2bf(v.y), f2bf(v.z), f2bf(v.w) };
    *(ushort4*)(xb + i) = *(ushort4*)o;
  }
}

// ---------------- masked softmax over d (axis -2), write bf16 B[n= h*64+k][d] ----------------
__global__ __launch_bounds__(256) void k_softmax_w_bf(const float* __restrict__ W, u16* __restrict__ Bt) {
  int col = blockIdx.x;           // h*64 + k
  int h = col >> 6, k = col & 63;
  int tid = threadIdx.x;
  const float* w = W + ((size_t)h * DD) * DKK + k;
  __shared__ float red[256];
  float m = -1e30f;
  for (int d = k + tid; d < DD; d += 256) m = fmaxf(m, w[(size_t)d * DKK]);
  red[tid] = m; __syncthreads();
  for (int s = 128; s > 0; s >>= 1) { if (tid < s) red[tid] = fmaxf(red[tid], red[tid + s]); __syncthreads(); }
  m = red[0]; __syncthreads();
  float sum = 0.f;
  for (int d = k + tid; d < DD; d += 256) sum += __expf(w[(size_t)d * DKK] - m);
  red[tid] = sum; __syncthreads();
  for (int s = 128; s > 0; s >>= 1) { if (tid < s) red[tid] += red[tid + s]; __syncthreads(); }
  float inv = 1.f / red[0];
  for (int d = tid; d < DD; d += 256) {
    float v = (d >= k) ? __expf(w[(size_t)d * DKK] - m) * inv : 0.f;
    Bt[(size_t)col * DD + d] = f2bf(v);
  }
}

// ---------------- reorder (H, D, DK) -> bf16 B[n=h*64+k][d] ----------------
__global__ __launch_bounds__(256) void k_reorder_w_bf(const float* __restrict__ W, u16* __restrict__ Bt) {
  int d0 = blockIdx.x << 6, h = blockIdx.y;
  __shared__ float t[64][65];
  int tid = threadIdx.x;
  const float* src = W + (size_t)h * DD * DKK + (size_t)d0 * DKK;
  #pragma unroll
  for (int i = 0; i < 16; ++i) {
    int e = i * 256 + tid; int r = e >> 6, c = e & 63;
    t[r][c] = src[(size_t)r * DKK + c];
  }
  __syncthreads();
  #pragma unroll
  for (int i = 0; i < 16; ++i) {
    int e = i * 256 + tid; int c = e >> 6, r = e & 63;
    Bt[((size_t)(h * 64 + c)) * DD + d0 + r] = f2bf(t[r][c]);
  }
}

// ---------------- transpose (K,N) f32 -> bf16 B[n][k] ----------------
__global__ __launch_bounds__(256) void k_transpose_bf(const float* __restrict__ W, u16* __restrict__ Bt) {
  int k0 = blockIdx.x << 6, n0 = blockIdx.y << 6;
  __shared__ float t[64][65];
  int tid = threadIdx.x;
  #pragma unroll
  for (int i = 0; i < 16; ++i) {
    int e = i * 256 + tid; int r = e >> 6, c = e & 63;
    t[r][c] = W[(size_t)(k0 + r) * DD + n0 + c];
  }
  __syncthreads();
  #pragma unroll
  for (int i = 0; i < 16; ++i) {
    int e = i * 256 + tid; int c = e >> 6, r = e & 63;
    Bt[(size_t)(n0 + c) * DD + k0 + r] = f2bf(t[r][c]);
  }
}

// ---------------- MFMA NT GEMM: C = A(MxK) * B(NxK)^T (bf16 in, f32 acc) ----------------
// 128x128 tile, BK=32, 256 threads (4 waves 2x2, wave-tile 64x64 = m97 geometry),
// 2-phase dbuf LDS, GLDS staging, XCD swizzle, optional split-K via blockIdx.z.
// mode 0: Cf/Cf2 (f32 partials by z) or Cb (bf16) row-major + bias/relu.
// mode 1 (QKV, N=3072): col<1024 -> Cb, <2048 -> Cb2, else col-major Ct (pitch M).
// mode 2 (KV,  N=2048): col<1024 -> Cb, else col-major Ct.
__global__ __launch_bounds__(256) void k_mfma_nt(
    const u16* __restrict__ A, const u16* __restrict__ B,
    float* __restrict__ Cf, float* __restrict__ Cf2,
    u16* __restrict__ Cb, u16* __restrict__ Cb2, u16* __restrict__ Ct,
    const float* __restrict__ bias, int relu, int mode, int M, int N, int K) {
  __shared__ u16 As[2 * 4096];
  __shared__ u16 Bs[2 * 4096];
  int bx = blockIdx.x, by = blockIdx.y;
  swz_block(bx, by);
  int tid = threadIdx.x, wave = tid >> 6, lane = tid & 63;
  int row0 = by << 7, col0 = bx << 7;
  int wm = (wave >> 1) << 6, wn = (wave & 1) << 6;

  int Ksl = K / gridDim.z;
  int kbase = blockIdx.z * Ksl;
  int kend = kbase + Ksl;

  f32x4 acc[4][4];
  #pragma unroll
  for (int m = 0; m < 4; ++m)
    #pragma unroll
    for (int n = 0; n < 4; ++n) acc[m][n] = f32x4{0.f, 0.f, 0.f, 0.f};

  // staging: [128][32] bf16 = 8 KB = 8 chunks of 1 KB (16 rows each); wave w owns chunks 2w, 2w+1
  int c0 = wave * 2, c1 = wave * 2 + 1;
  int r0 = (c0 << 4) + (lane >> 2);
  int r1 = (c1 << 4) + (lane >> 2);
  int ce = (lane & 3) << 3;
  const u16* Ag0 = A + (size_t)(row0 + r0) * K + ce;
  const u16* Ag1 = A + (size_t)(row0 + r1) * K + ce;
  const u16* Bg0 = B + (size_t)(col0 + r0) * K + ce;
  const u16* Bg1 = B + (size_t)(col0 + r1) * K + ce;

  int fr = lane & 15, kg = (lane >> 4) << 3;
  int ardo = (wm + fr) * 32 + kg;
  int brdo = (wn + fr) * 32 + kg;

  auto STAGE = [&](int buf, int k0) {
    u16* Ab = As + buf * 4096;
    u16* Bb = Bs + buf * 4096;
    GLDS(Ag0 + k0, Ab + c0 * 512);
    GLDS(Ag1 + k0, Ab + c1 * 512);
    GLDS(Bg0 + k0, Bb + c0 * 512);
    GLDS(Bg1 + k0, Bb + c1 * 512);
  };

  STAGE(0, kbase);
  __syncthreads();
  int cur = 0;
  for (int k0 = kbase; k0 < kend; k0 += 32) {
    int nxt = k0 + 32;
    if (nxt < kend) STAGE(cur ^ 1, nxt);   // next-tile loads fly under current MFMA
    const u16* Ard = As + cur * 4096 + ardo;
    const u16* Brd = Bs + cur * 4096 + brdo;
    s16x8 aF[4], bF[4];
    #pragma unroll
    for (int m = 0; m < 4; ++m) aF[m] = *(const s16x8*)(Ard + m * 16 * 32);
    #pragma unroll
    for (int n = 0; n < 4; ++n) bF[n] = *(const s16x8*)(Brd + n * 16 * 32);
    #pragma unroll
    for (int m = 0; m < 4; ++m)
      #pragma unroll
      for (int n = 0; n < 4; ++n)
        acc[m][n] = __builtin_amdgcn_mfma_f32_16x16x32_bf16(aF[m], bF[n], acc[m][n], 0, 0, 0);
    __syncthreads();                       // drains vmcnt(0): next buf ready, cur free
    cur ^= 1;
  }

  float* Cpart = (blockIdx.z == 0) ? Cf : Cf2;
  int fq = (lane >> 4) << 2;
  #pragma unroll
  for (int n = 0; n < 4; ++n) {
    int col = col0 + wn + n * 16 + fr;
    float bs = bias ? bias[col] : 0.f;
    #pragma unroll
    for (int m = 0; m < 4; ++m) {
      float v[4];
      #pragma unroll
      for (int r = 0; r < 4; ++r) {
        v[r] = acc[m][n][r] + bs;
        if (relu) v[r] = fmaxf(v[r], 0.f);
      }
      int rowb = row0 + wm + m * 16 + fq;
      if (mode == 0) {
        if (Cpart) {
          #pragma unroll
          for (int r = 0; r < 4; ++r) Cpart[(size_t)(rowb + r) * N + col] = v[r];
        }
        if (Cb) {
          #pragma unroll
          for (int r = 0; r < 4; ++r) Cb[(size_t)(rowb + r) * N + col] = f2bf(v[r]);
        }
      } else {
        int q = col >> 10, lc = col & 1023;
        u16* dstRM = nullptr;
        if (mode == 1) dstRM = (q == 0) ? Cb : ((q == 1) ? Cb2 : nullptr);
        else           dstRM = (q == 0) ? Cb : nullptr;
        if (dstRM) {
          #pragma unroll
          for (int r = 0; r < 4; ++r) dstRM[(size_t)(rowb + r) * 1024 + lc] = f2bf(v[r]);
        } else {
          u16 pb[4] = { f2bf(v[0]), f2bf(v[1]), f2bf(v[2]), f2bf(v[3]) };
          uint2 wv; wv.x = (u32)pb[0] | ((u32)pb[1] << 16); wv.y = (u32)pb[2] | ((u32)pb[3] << 16);
          *(uint2*)(Ct + (size_t)lc * 4096 + rowb) = wv;
        }
      }
    }
  }
}

// ---------------- stage one 64x64 bf16 tile (512 threads, 1 uint4 each) -> LDS [64][72] ----------------
static __device__ __forceinline__ void stage_tile512(const u16* __restrict__ g, int gp, u16* L, int tid) {
  int row = tid >> 3, col8 = (tid & 7) << 3;
  *(uint4*)(L + row * 72 + col8) = *(const uint4*)(g + (size_t)row * gp + col8);
}

// ---------------- attention pass 1 (MFMA, 8 waves, 2 s-tiles/block) ----------------
// S[t][s] = dot(Q[t],K[s])/8 ; softmax over t. mfma(Q,K): lane holds s fixed, 16 t vals.
__global__ __launch_bounds__(512) void k_attn_stats_mfma(const u16* __restrict__ Qb, const u16* __restrict__ Kb,
                                                         float* __restrict__ cmax, float* __restrict__ csum) {
  __shared__ u16 Ks[2 * 4608];
  __shared__ u16 Qs[4608];
  int tid = threadIdx.x, wave = tid >> 6, lane = tid & 63;
  int bh = blockIdx.x, b = bh >> 4, h = bh & 15;
  int s0 = blockIdx.y << 7;               // 128 s-cols per block
  int tile = wave >> 2, sw = wave & 3;
  stage_tile512(Kb + ((size_t)(b * TT + s0)) * DD + h * 64, DD, Ks, tid);
  stage_tile512(Kb + ((size_t)(b * TT + s0 + 64)) * DD + h * 64, DD, Ks + 4608, tid);
  __syncthreads();
  int fr = lane & 15, g = lane >> 4;
  const u16* Bbase = Ks + tile * 4608 + (sw * 16 + fr) * 72 + g * 8;   // B-frag: K rows (n = s)
  const u16* Abase = Qs + fr * 72 + g * 8;                             // A-frag: Q rows (m = t)
  s16x8 bF0 = *(const s16x8*)(Bbase);
  s16x8 bF1 = *(const s16x8*)(Bbase + 32);
  float m = -1e30f, sum = 0.f;
  for (int t0 = 0; t0 < TT; t0 += 64) {
    __syncthreads();
    stage_tile512(Qb + ((size_t)(b * TT + t0)) * DD + h * 64, DD, Qs, tid);
    __syncthreads();
    #pragma unroll
    for (int mt = 0; mt < 4; ++mt) {
      f32x4 acc = f32x4{0.f, 0.f, 0.f, 0.f};
      s16x8 a0 = *(const s16x8*)(Abase + mt * 16 * 72);
      s16x8 a1 = *(const s16x8*)(Abase + mt * 16 * 72 + 32);
      acc = __builtin_amdgcn_mfma_f32_16x16x32_bf16(a0, bF0, acc, 0, 0, 0);
      acc = __builtin_amdgcn_mfma_f32_16x16x32_bf16(a1, bF1, acc, 0, 0, 0);
      float v0 = acc[0] * 0.125f, v1 = acc[1] * 0.125f, v2 = acc[2] * 0.125f, v3 = acc[3] * 0.125f;
      float tm = fmaxf(fmaxf(v0, v1), fmaxf(v2, v3));
      float nm = fmaxf(m, tm);
      sum = sum * __expf(m - nm) + __expf(v0 - nm) + __expf(v1 - nm) + __expf(v2 - nm) + __expf(v3 - nm);
      m = nm;
    }
  }
  #pragma unroll
  for (int mask = 16; mask <= 32; mask <<= 1) {
    float m2 = __shfl_xor(m, mask, 64);
    float s2 = __shfl_xor(sum, mask, 64);
    float nm = fmaxf(m, m2);
    sum = sum * __expf(m - nm) + s2 * __expf(m2 - nm);
    m = nm;
  }
  if (lane < 16) {
    size_t o = (size_t)bh * TT + s0 + tile * 64 + sw * 16 + lane;
    cmax[o] = m; csum[o] = sum;
  }
}

// ---------------- attention pass 2 (MFMA, 8 waves, 2 t-tiles/block) ----------------
__global__ __launch_bounds__(512) void k_attn_apply_mfma(const u16* __restrict__ Qb, const u16* __restrict__ Kb,
                                                         const u16* __restrict__ Vt,
                                                         const float* __restrict__ cmax, const float* __restrict__ csum,
                                                         u16* __restrict__ Op) {
  __shared__ u16 Qs[2 * 4608];
  __shared__ u16 Ks[4608];
  __shared__ u16 VTs[4608];
  __shared__ u16 Pl[8 * 1024];     // per-wave [16 t][64 s] bf16, XOR-swizzled
  __shared__ float cmL[64];
  __shared__ float rcsL[64];
  int tid = threadIdx.x, wave = tid >> 6, lane = tid & 63;
  int bh = blockIdx.x, b = bh >> 4, h = bh & 15;
  int t0 = blockIdx.y << 7;               // 128 t-rows per block
  int tile = wave >> 2, tw = wave & 3;
  stage_tile512(Qb + ((size_t)(b * TT + t0)) * DD + h * 64, DD, Qs, tid);
  stage_tile512(Qb + ((size_t)(b * TT + t0 + 64)) * DD + h * 64, DD, Qs + 4608, tid);
  __syncthreads();
  int fr = lane & 15, g = lane >> 4;
  const u16* QbF = Qs + tile * 4608 + (tw * 16 + fr) * 72 + g * 8;   // B-frag (n = t)
  const u16* KaF = Ks + fr * 72 + g * 8;                             // A-frag rows s
  char* Pw = (char*)(Pl + wave * 1024);
  uint swz = ((uint)(lane & 7)) << 4;
  s16x8 qF0 = *(const s16x8*)(QbF);
  s16x8 qF1 = *(const s16x8*)(QbF + 32);
  f32x4 acc_o[4];
  #pragma unroll
  for (int nt = 0; nt < 4; ++nt) acc_o[nt] = f32x4{0.f, 0.f, 0.f, 0.f};
  const size_t cbase = (size_t)bh * TT;

  for (int s0 = 0; s0 < TT; s0 += 64) {
    __syncthreads();
    stage_tile512(Kb + ((size_t)(b * TT + s0)) * DD + h * 64, DD, Ks, tid);
    stage_tile512(Vt + (size_t)(h * 64) * 4096 + (size_t)b * TT + s0, 4096, VTs, tid);
    if (tid < 64) cmL[tid] = cmax[cbase + s0 + tid];
    else if (tid < 128) rcsL[tid - 64] = 1.f / csum[cbase + s0 + tid - 64];
    __syncthreads();
    // S^T tiles + exp -> P (per-wave)
    #pragma unroll
    for (int mt = 0; mt < 4; ++mt) {
      f32x4 acc = f32x4{0.f, 0.f, 0.f, 0.f};
      s16x8 a0 = *(const s16x8*)(KaF + mt * 16 * 72);
      s16x8 a1 = *(const s16x8*)(KaF + mt * 16 * 72 + 32);
      acc = __builtin_amdgcn_mfma_f32_16x16x32_bf16(a0, qF0, acc, 0, 0, 0);
      acc = __builtin_amdgcn_mfma_f32_16x16x32_bf16(a1, qF1, acc, 0, 0, 0);
      f32x4 cm4 = *(const f32x4*)&cmL[mt * 16 + g * 4];
      f32x4 rc4 = *(const f32x4*)&rcsL[mt * 16 + g * 4];
      u16 pb[4];
      #pragma unroll
      for (int r = 0; r < 4; ++r)
        pb[r] = f2bf(__expf(acc[r] * 0.125f - cm4[r]) * rc4[r]);
      uint woff = (uint)fr * 128 + (uint)(mt * 16 + g * 4) * 2;
      uint2 wv; wv.x = (u32)pb[0] | ((u32)pb[1] << 16); wv.y = (u32)pb[2] | ((u32)pb[3] << 16);
      *(uint2*)(Pw + (woff ^ swz)) = wv;
    }
    // PV: A = P (own wave's tile), B = V^T
    uint rbase = (uint)fr * 128;
    s16x8 pF0 = *(const s16x8*)(Pw + ((rbase + g * 16) ^ swz));
    s16x8 pF1 = *(const s16x8*)(Pw + ((rbase + 64 + g * 16) ^ swz));
    #pragma unroll
    for (int nt = 0; nt < 4; ++nt) {
      s16x8 v0 = *(const s16x8*)(VTs + (nt * 16 + fr) * 72 + g * 8);
      s16x8 v1 = *(const s16x8*)(VTs + (nt * 16 + fr) * 72 + 32 + g * 8);
      acc_o[nt] = __builtin_amdgcn_mfma_f32_16x16x32_bf16(pF0, v0, acc_o[nt], 0, 0, 0);
      acc_o[nt] = __builtin_amdgcn_mfma_f32_16x16x32_bf16(pF1, v1, acc_o[nt], 0, 0, 0);
    }
  }
  int tg = t0 + tile * 64 + tw * 16 + g * 4;
  #pragma unroll
  for (int nt = 0; nt < 4; ++nt) {
    #pragma unroll
    for (int r = 0; r < 4; ++r) {
      Op[((size_t)(b * TT + tg + r)) * DD + h * 64 + nt * 16 + fr] = f2bf(acc_o[nt][r]);
    }
  }
}

// ---------------- O = norm(sum of partials + bias + residual), ddof=1 ----------------
__global__ __launch_bounds__(256) void k_add_norm(const float* __restrict__ A, const float* __restrict__ A2,
                                                  const float* __restrict__ A3, const float* __restrict__ A4,
                                                  const float* __restrict__ bias,
                                                  const float* __restrict__ Bv,
                                                  float* __restrict__ O, u16* __restrict__ Ob) {
  int row = blockIdx.x, tid = threadIdx.x;
  size_t base = (size_t)row * DD;
  __shared__ float red[256];
  float v[4]; float s = 0.f;
  #pragma unroll
  for (int i = 0; i < 4; ++i) {
    int c = tid + (i << 8);
    float t = A[base + c] + Bv[base + c];
    if (A2) t += A2[base + c];
    if (A3) t += A3[base + c];
    if (A4) t += A4[base + c];
    if (bias) t += bias[c];
    v[i] = t; s += t;
  }
  red[tid] = s; __syncthreads();
  for (int t = 128; t > 0; t >>= 1) { if (tid < t) red[tid] += red[tid + t]; __syncthreads(); }
  float mean = red[0] * (1.f / 1024.f);
  __syncthreads();
  float vs = 0.f;
  #pragma unroll
  for (int i = 0; i < 4; ++i) { float d = v[i] - mean; vs += d * d; }
  red[tid] = vs; __syncthreads();
  for (int t = 128; t > 0; t >>= 1) { if (tid < t) red[tid] += red[tid + t]; __syncthreads(); }
  float inv = rsqrtf(red[0] * (1.f / 1023.f));
  #pragma unroll
  for (int i = 0; i < 4; ++i) {
    float o = (v[i] - mean) * inv;
    O[base + tid + (i << 8)] = o;
    if (Ob) Ob[base + tid + (i << 8)] = f2bf(o);
  }
}

extern "C" void kernel_launch(void* const* d_in, const int* in_sizes, int n_in,
                              void* d_out, int out_size, void* d_ws, size_t ws_size,
                              hipStream_t stream) {
  (void)in_sizes; (void)n_in; (void)out_size; (void)ws_size;
  const float* x    = (const float*)d_in[0];
  const float* y    = (const float*)d_in[1];
  const float* Wq1  = (const float*)d_in[2];
  const float* Wk1  = (const float*)d_in[3];
  const float* Wv1  = (const float*)d_in[4];
  const float* Wo1  = (const float*)d_in[5];
  const float* Wq2  = (const float*)d_in[6];
  const float* Wk2  = (const float*)d_in[7];
  const float* Wv2  = (const float*)d_in[8];
  const float* Wo2  = (const float*)d_in[9];
  const float* w_in  = (const float*)d_in[10];
  const float* b_in  = (const float*)d_in[11];
  const float* w_out = (const float*)d_in[12];
  const float* b_out = (const float*)d_in[13];

  float* ws = (float*)d_ws;
  size_t off = 0;
  auto allocw = [&](size_t nw) { float* p = ws + off; off += nw; return p; };
  const size_t MR = (size_t)BB * TT;           // 4096
  const size_t ND = MR * DD;                   // 4.19M elems

  u16* Bq   = (u16*)allocw(512 * 1024);        // Bq|Bk|Bv contiguous => fused B (3072 x 1024)
  u16* Bk   = (u16*)allocw(512 * 1024);
  u16* Bv   = (u16*)allocw(512 * 1024);
  u16* Bwo  = (u16*)allocw(512 * 1024);
  u16* Wi   = (u16*)allocw(2 * 1024 * 1024);
  u16* Wob  = (u16*)allocw(2 * 1024 * 1024);
  u16* xbf  = (u16*)allocw(ND / 2);
  u16* ybf  = (u16*)allocw(ND / 2);
  u16* REG  = (u16*)allocw(ND * 2);
  float* ff2  = allocw(ND);
  float* out1 = allocw(ND);
  float* out2 = allocw(ND);
  float* cmax = allocw((size_t)BB * HH * TT);
  float* csum = allocw((size_t)BB * HH * TT);

  u16* Qb = REG;
  u16* Kb = REG + ND;
  u16* Vt = REG + 2 * ND;   // V col-major (1024 x 4096), pitch 4096
  u16* Mb = REG + 3 * ND;   // mhaO; also out1_bf between layers
  u16* ff1b = REG;
  u16* out2bf = ybf;
  float* doutHi = (float*)d_out + ND;  // free until final add_norm writes it

  dim3 blk(256), blkA(512);
  dim3 gConv(4096);
  dim3 gSm(1024);
  dim3 gRw(16, 16);
  dim3 gQKV(24, 32);         // N=3072
  dim3 gKV(16, 32);          // N=2048
  dim3 gP(8, 32);            // N=1024, no split
  dim3 gP2(8, 32, 2);        // N=1024, split-K=2
  dim3 gF1(32, 32);          // N=4096
  dim3 gFF2(8, 32, 2);       // N=1024, split-K=2 (K=4096)
  dim3 gAttn(BB * HH, TT / 128);
  dim3 gNorm(MR);

  // x passthrough + bf16 convert, one pass
  k_xprep<<<gConv, blk, 0, stream>>>(x, (float*)d_out, xbf, (int)ND);
  k_f2bf<<<gConv, blk, 0, stream>>>(y, ybf, (int)ND);
  k_f2bf<<<gConv, blk, 0, stream>>>(w_in, Wi, FFF * DD);
  k_f2bf<<<gConv, blk, 0, stream>>>(w_out, Wob, DD * FFF);

  // ---- Layer 1: masked self-attention on y ----
  k_softmax_w_bf<<<gSm, blk, 0, stream>>>(Wq1, Bq);
  k_softmax_w_bf<<<gSm, blk, 0, stream>>>(Wk1, Bk);
  k_reorder_w_bf<<<gRw, blk, 0, stream>>>(Wv1, Bv);
  k_transpose_bf<<<gRw, blk, 0, stream>>>(Wo1, Bwo);
  k_mfma_nt<<<gQKV, blk, 0, stream>>>(ybf, Bq, nullptr, nullptr, Qb, Kb, Vt, nullptr, 0, 1, 4096, 3072, 1024);
  k_attn_stats_mfma<<<gAttn, blkA, 0, stream>>>(Qb, Kb, cmax, csum);
  k_attn_apply_mfma<<<gAttn, blkA, 0, stream>>>(Qb, Kb, Vt, cmax, csum, Mb);
  // out-proj split-K=2: partials ff2 + out2 (out2 unused until layer 2)
  k_mfma_nt<<<gP2, blk, 0, stream>>>(Mb, Bwo, ff2, out2, nullptr, nullptr, nullptr, nullptr, 0, 0, 4096, 1024, 1024);
  k_add_norm<<<gNorm, blk, 0, stream>>>(ff2, out2, nullptr, nullptr, nullptr, y, out1, Mb /* out1_bf */);

  // ---- Layer 2: cross-attention (Q from out1, K/V from x) ----
  k_reorder_w_bf<<<gRw, blk, 0, stream>>>(Wq2, Bq);
  k_reorder_w_bf<<<gRw, blk, 0, stream>>>(Wk2, Bk);
  k_reorder_w_bf<<<gRw, blk, 0, stream>>>(Wv2, Bv);
  k_transpose_bf<<<gRw, blk, 0, stream>>>(Wo2, Bwo);
  k_mfma_nt<<<gP, blk, 0, stream>>>(Mb /* out1_bf */, Bq, nullptr, nullptr, Qb, nullptr, nullptr, nullptr, 0, 0, 4096, 1024, 1024);
  k_mfma_nt<<<gKV, blk, 0, stream>>>(xbf, Bk, nullptr, nullptr, Kb, nullptr, Vt, nullptr, 0, 2, 4096, 2048, 1024);
  k_attn_stats_mfma<<<gAttn, blkA, 0, stream>>>(Qb, Kb, cmax, csum);
  k_attn_apply_mfma<<<gAttn, blkA, 0, stream>>>(Qb, Kb, Vt, cmax, csum, Mb);
  // out-proj split-K=2: partials ff2 + doutHi
  k_mfma_nt<<<gP2, blk, 0, stream>>>(Mb, Bwo, ff2, doutHi, nullptr, nullptr, nullptr, nullptr, 0, 0, 4096, 1024, 1024);
  k_add_norm<<<gNorm, blk, 0, stream>>>(ff2, doutHi, nullptr, nullptr, nullptr, out1, out2, out2bf);

  // ---- FF ----
  k_mfma_nt<<<gF1, blk, 0, stream>>>(out2bf, Wi, nullptr, nullptr, ff1b, nullptr, nullptr, b_in, 1, 0, 4096, 4096, 1024);
  // FF2 split-K=2: partials ff2 + doutHi; bias applied ONCE in the final add_norm
  k_mfma_nt<<<gFF2, blk, 0, stream>>>(ff1b, Wob, ff2, doutHi, nullptr, nullptr, nullptr, nullptr, 0, 0, 4096, 1024, 4096);
  k_add_norm<<<gNorm, blk, 0, stream>>>(ff2, doutHi, nullptr, nullptr, b_out, out2, doutHi, nullptr);
}

// Round 8
// 456.034 us; speedup vs baseline: 1.0082x; 1.0082x over previous
//
#include <hip/hip_runtime.h>
#include <hip/hip_bf16.h>

#define BB 4
#define TT 1024
#define DD 1024
#define HH 16
#define DKK 64
#define FFF 4096

typedef unsigned short u16;
typedef unsigned int u32;
typedef __attribute__((ext_vector_type(8))) short s16x8;
typedef __attribute__((ext_vector_type(4))) float f32x4;

static __device__ __forceinline__ float bf2f(u16 s) {
  union { u32 u; float f; } v; v.u = ((u32)s) << 16; return v.f;
}
static __device__ __forceinline__ u16 f2bf(float f) {
  union { float f; u32 u; } v; v.f = f;
  u32 r = v.u + 0x7FFFu + ((v.u >> 16) & 1u);
  return (u16)(r >> 16);
}

#define GLDS(gp, lp) __builtin_amdgcn_global_load_lds( \
    (const __attribute__((address_space(1))) u32*)(gp), \
    (__attribute__((address_space(3))) u32*)(lp), 16, 0, 0)

// XCD-chunked bijective block swizzle (m204 formula), 8-row supertiles.
static __device__ __forceinline__ void swz_block(int& bx, int& by) {
  int gx = gridDim.x, gy = gridDim.y;
  int nwg = gx * gy;
  int orig = by * gx + bx;
  int q = nwg >> 3, r = nwg & 7;
  int xcd = orig & 7, sl = orig >> 3;
  int wgid = (xcd < r ? xcd * (q + 1) : r * (q + 1) + (xcd - r) * q) + sl;
  int g = gx << 3;
  int grp = wgid / g, rem = wgid % g;
  bx = rem >> 3;
  by = (grp << 3) + (rem & 7);
}

// ---------------- f32 -> bf16 elementwise ----------------
__global__ __launch_bounds__(256) void k_f2bf(const float* __restrict__ s, u16* __restrict__ d, int n) {
  int i = (blockIdx.x * 256 + threadIdx.x) * 4;
  if (i < n) {
    float4 v = *(const float4*)(s + i);
    u16 o[4] = { f2bf(v.x), f2bf(v.y), f2bf(v.z), f2bf(v.w) };
    *(ushort4*)(d + i) = *(ushort4*)o;
  }
}

// ---------------- a+b -> bf16 (split-K combine) ----------------
__global__ __launch_bounds__(256) void k_combine_bf(const float* __restrict__ a, const float* __restrict__ b,
                                                    u16* __restrict__ d, int n) {
  int i = (blockIdx.x * 256 + threadIdx.x) * 4;
  if (i < n) {
    float4 va = *(const float4*)(a + i);
    float4 vb = *(const float4*)(b + i);
    u16 o[4] = { f2bf(va.x + vb.x), f2bf(va.y + vb.y), f2bf(va.z + vb.z), f2bf(va.w + vb.w) };
    *(ushort4*)(d + i) = *(ushort4*)o;
  }
}

// ---------------- x passthrough to d_out + bf16 convert, one read ----------------
__global__ __launch_bounds__(256) void k_xprep(const float* __restrict__ x, float* __restrict__ dout,
                                               u16* __restrict__ xb, int n) {
  int i = (blockIdx.x * 256 + threadIdx.x) * 4;
  if (i < n) {
    float4 v = *(const float4*)(x + i);
    *(float4*)(dout + i) = v;
    u16 o[4] = { f2bf(v.x), f2bf(v.y), f2bf(v.z), f2bf(v.w) };
    *(ushort4*)(xb + i) = *(ushort4*)o;
  }
}

// ---------------- masked softmax over d (axis -2), write bf16 B[n= h*64+k][d] ----------------
__global__ __launch_bounds__(256) void k_softmax_w_bf(const float* __restrict__ W, u16* __restrict__ Bt) {
  int col = blockIdx.x;           // h*64 + k
  int h = col >> 6, k = col & 63;
  int tid = threadIdx.x;
  const float* w = W + ((size_t)h * DD) * DKK + k;
  __shared__ float red[256];
  float m = -1e30f;
  for (int d = k + tid; d < DD; d += 256) m = fmaxf(m, w[(size_t)d * DKK]);
  red[tid] = m; __syncthreads();
  for (int s = 128; s > 0; s >>= 1) { if (tid < s) red[tid] = fmaxf(red[tid], red[tid + s]); __syncthreads(); }
  m = red[0]; __syncthreads();
  float sum = 0.f;
  for (int d = k + tid; d < DD; d += 256) sum += __expf(w[(size_t)d * DKK] - m);
  red[tid] = sum; __syncthreads();
  for (int s = 128; s > 0; s >>= 1) { if (tid < s) red[tid] += red[tid + s]; __syncthreads(); }
  float inv = 1.f / red[0];
  for (int d = tid; d < DD; d += 256) {
    float v = (d >= k) ? __expf(w[(size_t)d * DKK] - m) * inv : 0.f;
    Bt[(size_t)col * DD + d] = f2bf(v);
  }
}

// ---------------- reorder (H, D, DK) -> bf16 B[n=h*64+k][d] ----------------
__global__ __launch_bounds__(256) void k_reorder_w_bf(const float* __restrict__ W, u16* __restrict__ Bt) {
  int d0 = blockIdx.x << 6, h = blockIdx.y;
  __shared__ float t[64][65];
  int tid = threadIdx.x;
  const float* src = W + (size_t)h * DD * DKK + (size_t)d0 * DKK;
  #pragma unroll
  for (int i = 0; i < 16; ++i) {
    int e = i * 256 + tid; int r = e >> 6, c = e & 63;
    t[r][c] = src[(size_t)r * DKK + c];
  }
  __syncthreads();
  #pragma unroll
  for (int i = 0; i < 16; ++i) {
    int e = i * 256 + tid; int c = e >> 6, r = e & 63;
    Bt[((size_t)(h * 64 + c)) * DD + d0 + r] = f2bf(t[r][c]);
  }
}

// ---------------- transpose (K,N) f32 -> bf16 B[n][k] ----------------
__global__ __launch_bounds__(256) void k_transpose_bf(const float* __restrict__ W, u16* __restrict__ Bt) {
  int k0 = blockIdx.x << 6, n0 = blockIdx.y << 6;
  __shared__ float t[64][65];
  int tid = threadIdx.x;
  #pragma unroll
  for (int i = 0; i < 16; ++i) {
    int e = i * 256 + tid; int r = e >> 6, c = e & 63;
    t[r][c] = W[(size_t)(k0 + r) * DD + n0 + c];
  }
  __syncthreads();
  #pragma unroll
  for (int i = 0; i < 16; ++i) {
    int e = i * 256 + tid; int c = e >> 6, r = e & 63;
    Bt[(size_t)(n0 + c) * DD + k0 + r] = f2bf(t[r][c]);
  }
}

// ---------------- MFMA NT GEMM: C = A(MxK) * B(NxK)^T (bf16 in, f32 acc) ----------------
// 128x128 tile, BK=32, 256 threads (4 waves 2x2, wave-tile 64x64), 2-phase dbuf LDS,
// GLDS staging, XCD swizzle, split-K via blockIdx.z.
// mode 0: Cf/Cf2 (f32 partials, direct coalesced) OR Cb (bf16 row-major via LDS transpose).
// mode 1 (QKV, N=3072): block col0 uniform -> Cb (Q) / Cb2 (K) row-major, Ct (V) col-major.
// mode 2 (KV,  N=2048): -> Cb row-major or Ct col-major.
// All bf16 outputs go through a per-wave LDS transpose for fully-coalesced 64B stores.
__global__ __launch_bounds__(256) void k_mfma_nt(
    const u16* __restrict__ A, const u16* __restrict__ B,
    float* __restrict__ Cf, float* __restrict__ Cf2,
    u16* __restrict__ Cb, u16* __restrict__ Cb2, u16* __restrict__ Ct,
    const float* __restrict__ bias, int relu, int mode, int M, int N, int K) {
  __shared__ u16 SLDS[4 * 4096];   // [0,8192)=A bufs, [8192,16384)=B bufs; epilogue reuses [0,8704)
  int bx = blockIdx.x, by = blockIdx.y;
  swz_block(bx, by);
  int tid = threadIdx.x, wave = tid >> 6, lane = tid & 63;
  int row0 = by << 7, col0 = bx << 7;
  int wm = (wave >> 1) << 6, wn = (wave & 1) << 6;

  int Ksl = K / gridDim.z;
  int kbase = blockIdx.z * Ksl;
  int kend = kbase + Ksl;

  f32x4 acc[4][4];
  #pragma unroll
  for (int m = 0; m < 4; ++m)
    #pragma unroll
    for (int n = 0; n < 4; ++n) acc[m][n] = f32x4{0.f, 0.f, 0.f, 0.f};

  // staging: [128][32] bf16 = 8 KB = 8 chunks of 1 KB (16 rows each); wave w owns chunks 2w, 2w+1
  int c0 = wave * 2, c1 = wave * 2 + 1;
  int r0 = (c0 << 4) + (lane >> 2);
  int r1 = (c1 << 4) + (lane >> 2);
  int ce = (lane & 3) << 3;
  const u16* Ag0 = A + (size_t)(row0 + r0) * K + ce;
  const u16* Ag1 = A + (size_t)(row0 + r1) * K + ce;
  const u16* Bg0 = B + (size_t)(col0 + r0) * K + ce;
  const u16* Bg1 = B + (size_t)(col0 + r1) * K + ce;

  int fr = lane & 15, kg = (lane >> 4) << 3;
  int ardo = (wm + fr) * 32 + kg;
  int brdo = 8192 + (wn + fr) * 32 + kg;

  auto STAGE = [&](int buf, int k0) {
    u16* Ab = SLDS + buf * 4096;
    u16* Bb = SLDS + 8192 + buf * 4096;
    GLDS(Ag0 + k0, Ab + c0 * 512);
    GLDS(Ag1 + k0, Ab + c1 * 512);
    GLDS(Bg0 + k0, Bb + c0 * 512);
    GLDS(Bg1 + k0, Bb + c1 * 512);
  };

  STAGE(0, kbase);
  __syncthreads();
  int cur = 0;
  for (int k0 = kbase; k0 < kend; k0 += 32) {
    int nxt = k0 + 32;
    if (nxt < kend) STAGE(cur ^ 1, nxt);   // next-tile loads fly under current MFMA
    const u16* Ard = SLDS + cur * 4096 + ardo;
    const u16* Brd = SLDS + cur * 4096 + brdo;
    s16x8 aF[4], bF[4];
    #pragma unroll
    for (int m = 0; m < 4; ++m) aF[m] = *(const s16x8*)(Ard + m * 16 * 32);
    #pragma unroll
    for (int n = 0; n < 4; ++n) bF[n] = *(const s16x8*)(Brd + n * 16 * 32);
    #pragma unroll
    for (int m = 0; m < 4; ++m)
      #pragma unroll
      for (int n = 0; n < 4; ++n)
        acc[m][n] = __builtin_amdgcn_mfma_f32_16x16x32_bf16(aF[m], bF[n], acc[m][n], 0, 0, 0);
    __syncthreads();                       // drains vmcnt(0): next buf ready, cur free
    cur ^= 1;
  }

  int fq = (lane >> 4) << 2;

  // ---- f32 partial outputs: direct stores (16 fr-lanes x 4B = full 64B lines) ----
  if (mode == 0 && (Cf || Cf2)) {
    float* Cpart = (blockIdx.z == 0) ? Cf : Cf2;
    #pragma unroll
    for (int n = 0; n < 4; ++n) {
      int col = col0 + wn + n * 16 + fr;
      float bs = bias ? bias[col] : 0.f;
      #pragma unroll
      for (int m = 0; m < 4; ++m) {
        #pragma unroll
        for (int r = 0; r < 4; ++r) {
          float v = acc[m][n][r] + bs;
          if (relu) v = fmaxf(v, 0.f);
          Cpart[(size_t)(row0 + wm + m * 16 + fq + r) * N + col] = v;
        }
      }
    }
    return;
  }

  // ---- bf16 outputs: per-wave LDS transpose -> coalesced 64B/lane stores ----
  u16* dstRow = nullptr; u16* dstCol = nullptr;
  int rowPitch = 1024, colBase = col0 & 1023;
  if (mode == 0) { dstRow = Cb; rowPitch = N; colBase = col0; }
  else if (mode == 1) { int q = col0 >> 10; if (q == 0) dstRow = Cb; else if (q == 1) dstRow = Cb2; else dstCol = Ct; }
  else { int q = col0 >> 10; if (q == 0) dstRow = Cb; else dstCol = Ct; }

  u16* Ep = SLDS + wave * 2176;   // per-wave [32][68] u16 (wave-private, no barrier needed)
  #pragma unroll
  for (int c = 0; c < 2; ++c) {
    #pragma unroll
    for (int m2 = 0; m2 < 2; ++m2) {
      int m = c * 2 + m2;
      #pragma unroll
      for (int n = 0; n < 4; ++n) {
        int col = col0 + wn + n * 16 + fr;
        float bs = bias ? bias[col] : 0.f;
        #pragma unroll
        for (int r = 0; r < 4; ++r) {
          float v = acc[m][n][r] + bs;
          if (relu) v = fmaxf(v, 0.f);
          Ep[(m2 * 16 + fq + r) * 68 + n * 16 + fr] = f2bf(v);
        }
      }
    }
    if (dstRow) {
      int rl = lane >> 1, half = lane & 1;
      const u16* src = Ep + rl * 68 + half * 32;
      u16* gd = dstRow + (size_t)(row0 + wm + c * 32 + rl) * rowPitch + colBase + wn + half * 32;
      #pragma unroll
      for (int i = 0; i < 8; ++i) *(uint2*)(gd + i * 4) = *(const uint2*)(src + i * 4);
    } else {
      u16 tmp[32];
      #pragma unroll
      for (int s = 0; s < 32; ++s) tmp[s] = Ep[s * 68 + lane];
      u16* gd = dstCol + (size_t)(colBase + wn + lane) * 4096 + row0 + wm + c * 32;
      #pragma unroll
      for (int i = 0; i < 4; ++i) *(uint4*)(gd + i * 8) = ((const uint4*)tmp)[i];
    }
  }
}

// ---------------- stage one 64x64 bf16 tile (512 threads, 1 uint4 each) -> LDS [64][72] ----------------
static __device__ __forceinline__ void stage_tile512(const u16* __restrict__ g, int gp, u16* L, int tid) {
  int row = tid >> 3, col8 = (tid & 7) << 3;
  *(uint4*)(L + row * 72 + col8) = *(const uint4*)(g + (size_t)row * gp + col8);
}

// ---------------- attention pass 1 (MFMA, 8 waves, 2 s-tiles/block) ----------------
__global__ __launch_bounds__(512) void k_attn_stats_mfma(const u16* __restrict__ Qb, const u16* __restrict__ Kb,
                                                         float* __restrict__ cmax, float* __restrict__ csum) {
  __shared__ u16 Ks[2 * 4608];
  __shared__ u16 Qs[4608];
  int tid = threadIdx.x, wave = tid >> 6, lane = tid & 63;
  int bh = blockIdx.x, b = bh >> 4, h = bh & 15;
  int s0 = blockIdx.y << 7;               // 128 s-cols per block
  int tile = wave >> 2, sw = wave & 3;
  stage_tile512(Kb + ((size_t)(b * TT + s0)) * DD + h * 64, DD, Ks, tid);
  stage_tile512(Kb + ((size_t)(b * TT + s0 + 64)) * DD + h * 64, DD, Ks + 4608, tid);
  __syncthreads();
  int fr = lane & 15, g = lane >> 4;
  const u16* Bbase = Ks + tile * 4608 + (sw * 16 + fr) * 72 + g * 8;   // B-frag: K rows (n = s)
  const u16* Abase = Qs + fr * 72 + g * 8;                             // A-frag: Q rows (m = t)
  s16x8 bF0 = *(const s16x8*)(Bbase);
  s16x8 bF1 = *(const s16x8*)(Bbase + 32);
  float m = -1e30f, sum = 0.f;
  for (int t0 = 0; t0 < TT; t0 += 64) {
    __syncthreads();
    stage_tile512(Qb + ((size_t)(b * TT + t0)) * DD + h * 64, DD, Qs, tid);
    __syncthreads();
    #pragma unroll
    for (int mt = 0; mt < 4; ++mt) {
      f32x4 acc = f32x4{0.f, 0.f, 0.f, 0.f};
      s16x8 a0 = *(const s16x8*)(Abase + mt * 16 * 72);
      s16x8 a1 = *(const s16x8*)(Abase + mt * 16 * 72 + 32);
      acc = __builtin_amdgcn_mfma_f32_16x16x32_bf16(a0, bF0, acc, 0, 0, 0);
      acc = __builtin_amdgcn_mfma_f32_16x16x32_bf16(a1, bF1, acc, 0, 0, 0);
      float v0 = acc[0] * 0.125f, v1 = acc[1] * 0.125f, v2 = acc[2] * 0.125f, v3 = acc[3] * 0.125f;
      float tm = fmaxf(fmaxf(v0, v1), fmaxf(v2, v3));
      float nm = fmaxf(m, tm);
      sum = sum * __expf(m - nm) + __expf(v0 - nm) + __expf(v1 - nm) + __expf(v2 - nm) + __expf(v3 - nm);
      m = nm;
    }
  }
  #pragma unroll
  for (int mask = 16; mask <= 32; mask <<= 1) {
    float m2 = __shfl_xor(m, mask, 64);
    float s2 = __shfl_xor(sum, mask, 64);
    float nm = fmaxf(m, m2);
    sum = sum * __expf(m - nm) + s2 * __expf(m2 - nm);
    m = nm;
  }
  if (lane < 16) {
    size_t o = (size_t)bh * TT + s0 + tile * 64 + sw * 16 + lane;
    cmax[o] = m; csum[o] = sum;
  }
}

// ---------------- attention pass 2 (MFMA, 8 waves, 2 t-tiles/block) ----------------
__global__ __launch_bounds__(512) void k_attn_apply_mfma(const u16* __restrict__ Qb, const u16* __restrict__ Kb,
                                                         const u16* __restrict__ Vt,
                                                         const float* __restrict__ cmax, const float* __restrict__ csum,
                                                         u16* __restrict__ Op) {
  __shared__ u16 Qs[2 * 4608];
  __shared__ u16 KV2[2 * 4608];    // Ks | VTs; reused by the write epilogue
  __shared__ u16 Pl[8 * 1024];     // per-wave [16 t][64 s] bf16, XOR-swizzled
  __shared__ float cmL[64];
  __shared__ float rcsL[64];
  u16* Ks = KV2;
  u16* VTs = KV2 + 4608;
  int tid = threadIdx.x, wave = tid >> 6, lane = tid & 63;
  int bh = blockIdx.x, b = bh >> 4, h = bh & 15;
  int t0 = blockIdx.y << 7;               // 128 t-rows per block
  int tile = wave >> 2, tw = wave & 3;
  stage_tile512(Qb + ((size_t)(b * TT + t0)) * DD + h * 64, DD, Qs, tid);
  stage_tile512(Qb + ((size_t)(b * TT + t0 + 64)) * DD + h * 64, DD, Qs + 4608, tid);
  __syncthreads();
  int fr = lane & 15, g = lane >> 4;
  const u16* QbF = Qs + tile * 4608 + (tw * 16 + fr) * 72 + g * 8;   // B-frag (n = t)
  const u16* KaF = Ks + fr * 72 + g * 8;                             // A-frag rows s
  char* Pw = (char*)(Pl + wave * 1024);
  uint swz = ((uint)(lane & 7)) << 4;
  s16x8 qF0 = *(const s16x8*)(QbF);
  s16x8 qF1 = *(const s16x8*)(QbF + 32);
  f32x4 acc_o[4];
  #pragma unroll
  for (int nt = 0; nt < 4; ++nt) acc_o[nt] = f32x4{0.f, 0.f, 0.f, 0.f};
  const size_t cbase = (size_t)bh * TT;

  for (int s0 = 0; s0 < TT; s0 += 64) {
    __syncthreads();
    stage_tile512(Kb + ((size_t)(b * TT + s0)) * DD + h * 64, DD, Ks, tid);
    stage_tile512(Vt + (size_t)(h * 64) * 4096 + (size_t)b * TT + s0, 4096, VTs, tid);
    if (tid < 64) cmL[tid] = cmax[cbase + s0 + tid];
    else if (tid < 128) rcsL[tid - 64] = 1.f / csum[cbase + s0 + tid - 64];
    __syncthreads();
    // S^T tiles + exp -> P (per-wave)
    #pragma unroll
    for (int mt = 0; mt < 4; ++mt) {
      f32x4 acc = f32x4{0.f, 0.f, 0.f, 0.f};
      s16x8 a0 = *(const s16x8*)(KaF + mt * 16 * 72);
      s16x8 a1 = *(const s16x8*)(KaF + mt * 16 * 72 + 32);
      acc = __builtin_amdgcn_mfma_f32_16x16x32_bf16(a0, qF0, acc, 0, 0, 0);
      acc = __builtin_amdgcn_mfma_f32_16x16x32_bf16(a1, qF1, acc, 0, 0, 0);
      f32x4 cm4 = *(const f32x4*)&cmL[mt * 16 + g * 4];
      f32x4 rc4 = *(const f32x4*)&rcsL[mt * 16 + g * 4];
      u16 pb[4];
      #pragma unroll
      for (int r = 0; r < 4; ++r)
        pb[r] = f2bf(__expf(acc[r] * 0.125f - cm4[r]) * rc4[r]);
      uint woff = (uint)fr * 128 + (uint)(mt * 16 + g * 4) * 2;
      uint2 wv; wv.x = (u32)pb[0] | ((u32)pb[1] << 16); wv.y = (u32)pb[2] | ((u32)pb[3] << 16);
      *(uint2*)(Pw + (woff ^ swz)) = wv;
    }
    // PV: A = P (own wave's tile), B = V^T
    uint rbase = (uint)fr * 128;
    s16x8 pF0 = *(const s16x8*)(Pw + ((rbase + g * 16) ^ swz));
    s16x8 pF1 = *(const s16x8*)(Pw + ((rbase + 64 + g * 16) ^ swz));
    #pragma unroll
    for (int nt = 0; nt < 4; ++nt) {
      s16x8 v0 = *(const s16x8*)(VTs + (nt * 16 + fr) * 72 + g * 8);
      s16x8 v1 = *(const s16x8*)(VTs + (nt * 16 + fr) * 72 + 32 + g * 8);
      acc_o[nt] = __builtin_amdgcn_mfma_f32_16x16x32_bf16(pF0, v0, acc_o[nt], 0, 0, 0);
      acc_o[nt] = __builtin_amdgcn_mfma_f32_16x16x32_bf16(pF1, v1, acc_o[nt], 0, 0, 0);
    }
  }
  // write epilogue: per-wave LDS transpose (reuse KV2) -> coalesced 32B/lane stores
  __syncthreads();                         // all waves done reading Ks/VTs
  u16* Ep = KV2 + wave * 1088;             // per-wave [16][68]
  #pragma unroll
  for (int nt = 0; nt < 4; ++nt)
    #pragma unroll
    for (int r = 0; r < 4; ++r)
      Ep[(g * 4 + r) * 68 + nt * 16 + fr] = f2bf(acc_o[nt][r]);
  {
    int row = lane >> 2, seg = lane & 3;
    const u16* src = Ep + row * 68 + seg * 16;
    u16* gd = Op + ((size_t)(b * TT + t0 + tile * 64 + tw * 16 + row)) * DD + h * 64 + seg * 16;
    #pragma unroll
    for (int i = 0; i < 4; ++i) *(uint2*)(gd + i * 4) = *(const uint2*)(src + i * 4);
  }
}

// ---------------- O = norm(sum of partials + bias + residual), ddof=1 ----------------
__global__ __launch_bounds__(256) void k_add_norm(const float* __restrict__ A, const float* __restrict__ A2,
                                                  const float* __restrict__ A3, const float* __restrict__ A4,
                                                  const float* __restrict__ bias,
                                                  const float* __restrict__ Bv,
                                                  float* __restrict__ O, u16* __restrict__ Ob) {
  int row = blockIdx.x, tid = threadIdx.x;
  size_t base = (size_t)row * DD;
  __shared__ float red[256];
  float v[4]; float s = 0.f;
  #pragma unroll
  for (int i = 0; i < 4; ++i) {
    int c = tid + (i << 8);
    float t = A[base + c] + Bv[base + c];
    if (A2) t += A2[base + c];
    if (A3) t += A3[base + c];
    if (A4) t += A4[base + c];
    if (bias) t += bias[c];
    v[i] = t; s += t;
  }
  red[tid] = s; __syncthreads();
  for (int t = 128; t > 0; t >>= 1) { if (tid < t) red[tid] += red[tid + t]; __syncthreads(); }
  float mean = red[0] * (1.f / 1024.f);
  __syncthreads();
  float vs = 0.f;
  #pragma unroll
  for (int i = 0; i < 4; ++i) { float d = v[i] - mean; vs += d * d; }
  red[tid] = vs; __syncthreads();
  for (int t = 128; t > 0; t >>= 1) { if (tid < t) red[tid] += red[tid + t]; __syncthreads(); }
  float inv = rsqrtf(red[0] * (1.f / 1023.f));
  #pragma unroll
  for (int i = 0; i < 4; ++i) {
    float o = (v[i] - mean) * inv;
    O[base + tid + (i << 8)] = o;
    if (Ob) Ob[base + tid + (i << 8)] = f2bf(o);
  }
}

extern "C" void kernel_launch(void* const* d_in, const int* in_sizes, int n_in,
                              void* d_out, int out_size, void* d_ws, size_t ws_size,
                              hipStream_t stream) {
  (void)in_sizes; (void)n_in; (void)out_size; (void)ws_size;
  const float* x    = (const float*)d_in[0];
  const float* y    = (const float*)d_in[1];
  const float* Wq1  = (const float*)d_in[2];
  const float* Wk1  = (const float*)d_in[3];
  const float* Wv1  = (const float*)d_in[4];
  const float* Wo1  = (const float*)d_in[5];
  const float* Wq2  = (const float*)d_in[6];
  const float* Wk2  = (const float*)d_in[7];
  const float* Wv2  = (const float*)d_in[8];
  const float* Wo2  = (const float*)d_in[9];
  const float* w_in  = (const float*)d_in[10];
  const float* b_in  = (const float*)d_in[11];
  const float* w_out = (const float*)d_in[12];
  const float* b_out = (const float*)d_in[13];

  float* ws = (float*)d_ws;
  size_t off = 0;
  auto allocw = [&](size_t nw) { float* p = ws + off; off += nw; return p; };
  const size_t MR = (size_t)BB * TT;           // 4096
  const size_t ND = MR * DD;                   // 4.19M elems

  u16* Bq   = (u16*)allocw(512 * 1024);        // Bq|Bk|Bv contiguous => fused B (3072 x 1024)
  u16* Bk   = (u16*)allocw(512 * 1024);
  u16* Bv   = (u16*)allocw(512 * 1024);
  u16* Bwo  = (u16*)allocw(512 * 1024);
  u16* Wi   = (u16*)allocw(2 * 1024 * 1024);
  u16* Wob  = (u16*)allocw(2 * 1024 * 1024);
  u16* xbf  = (u16*)allocw(ND / 2);
  u16* ybf  = (u16*)allocw(ND / 2);
  u16* REG  = (u16*)allocw(ND * 2);
  float* ff2  = allocw(ND);
  float* out1 = allocw(ND);
  float* out2 = allocw(ND);
  float* cmax = allocw((size_t)BB * HH * TT);
  float* csum = allocw((size_t)BB * HH * TT);

  u16* Qb = REG;
  u16* Kb = REG + ND;
  u16* Vt = REG + 2 * ND;   // V col-major (1024 x 4096), pitch 4096
  u16* Mb = REG + 3 * ND;   // mhaO; also out1_bf between layers
  u16* ff1b = REG;
  u16* out2bf = ybf;
  float* doutHi = (float*)d_out + ND;  // free until final add_norm writes it

  dim3 blk(256), blkA(512);
  dim3 gConv(4096);
  dim3 gSm(1024);
  dim3 gRw(16, 16);
  dim3 gQKV(24, 32);         // N=3072
  dim3 gKV(16, 32);          // N=2048
  dim3 gP2(8, 32, 2);        // N=1024, split-K=2
  dim3 gF1(32, 32);          // N=4096
  dim3 gFF2(8, 32, 2);       // N=1024, split-K=2 (K=4096)
  dim3 gAttn(BB * HH, TT / 128);
  dim3 gNorm(MR);

  // x passthrough + bf16 convert, one pass
  k_xprep<<<gConv, blk, 0, stream>>>(x, (float*)d_out, xbf, (int)ND);
  k_f2bf<<<gConv, blk, 0, stream>>>(y, ybf, (int)ND);
  k_f2bf<<<gConv, blk, 0, stream>>>(w_in, Wi, FFF * DD);
  k_f2bf<<<gConv, blk, 0, stream>>>(w_out, Wob, DD * FFF);

  // ---- Layer 1: masked self-attention on y ----
  k_softmax_w_bf<<<gSm, blk, 0, stream>>>(Wq1, Bq);
  k_softmax_w_bf<<<gSm, blk, 0, stream>>>(Wk1, Bk);
  k_reorder_w_bf<<<gRw, blk, 0, stream>>>(Wv1, Bv);
  k_transpose_bf<<<gRw, blk, 0, stream>>>(Wo1, Bwo);
  k_mfma_nt<<<gQKV, blk, 0, stream>>>(ybf, Bq, nullptr, nullptr, Qb, Kb, Vt, nullptr, 0, 1, 4096, 3072, 1024);
  k_attn_stats_mfma<<<gAttn, blkA, 0, stream>>>(Qb, Kb, cmax, csum);
  k_attn_apply_mfma<<<gAttn, blkA, 0, stream>>>(Qb, Kb, Vt, cmax, csum, Mb);
  // out-proj split-K=2: partials ff2 + out2 (out2 unused until layer 2)
  k_mfma_nt<<<gP2, blk, 0, stream>>>(Mb, Bwo, ff2, out2, nullptr, nullptr, nullptr, nullptr, 0, 0, 4096, 1024, 1024);
  k_add_norm<<<gNorm, blk, 0, stream>>>(ff2, out2, nullptr, nullptr, nullptr, y, out1, Mb /* out1_bf */);

  // ---- Layer 2: cross-attention (Q from out1, K/V from x) ----
  k_reorder_w_bf<<<gRw, blk, 0, stream>>>(Wq2, Bq);
  k_reorder_w_bf<<<gRw, blk, 0, stream>>>(Wk2, Bk);
  k_reorder_w_bf<<<gRw, blk, 0, stream>>>(Wv2, Bv);
  k_transpose_bf<<<gRw, blk, 0, stream>>>(Wo2, Bwo);
  // Q2 proj split-K=2 into dead f32 buffers, then combine -> Qb bf16
  k_mfma_nt<<<gP2, blk, 0, stream>>>(Mb /* out1_bf */, Bq, ff2, out2, nullptr, nullptr, nullptr, nullptr, 0, 0, 4096, 1024, 1024);
  k_combine_bf<<<gConv, blk, 0, stream>>>(ff2, out2, Qb, (int)ND);
  k_mfma_nt<<<gKV, blk, 0, stream>>>(xbf, Bk, nullptr, nullptr, Kb, nullptr, Vt, nullptr, 0, 2, 4096, 2048, 1024);
  k_attn_stats_mfma<<<gAttn, blkA, 0, stream>>>(Qb, Kb, cmax, csum);
  k_attn_apply_mfma<<<gAttn, blkA, 0, stream>>>(Qb, Kb, Vt, cmax, csum, Mb);
  // out-proj split-K=2: partials ff2 + doutHi
  k_mfma_nt<<<gP2, blk, 0, stream>>>(Mb, Bwo, ff2, doutHi, nullptr, nullptr, nullptr, nullptr, 0, 0, 4096, 1024, 1024);
  k_add_norm<<<gNorm, blk, 0, stream>>>(ff2, doutHi, nullptr, nullptr, nullptr, out1, out2, out2bf);

  // ---- FF ----
  k_mfma_nt<<<gF1, blk, 0, stream>>>(out2bf, Wi, nullptr, nullptr, ff1b, nullptr, nullptr, b_in, 1, 0, 4096, 4096, 1024);
  // FF2 split-K=2: partials ff2 + doutHi; bias applied ONCE in the final add_norm
  k_mfma_nt<<<gFF2, blk, 0, stream>>>(ff1b, Wob, ff2, doutHi, nullptr, nullptr, nullptr, nullptr, 0, 0, 4096, 1024, 4096);
  k_add_norm<<<gNorm, blk, 0, stream>>>(ff2, doutHi, nullptr, nullptr, b_out, out2, doutHi, nullptr);
}

// Round 9
// 452.156 us; speedup vs baseline: 1.0169x; 1.0086x over previous
//
#include <hip/hip_runtime.h>
#include <hip/hip_bf16.h>

#define BB 4
#define TT 1024
#define DD 1024
#define HH 16
#define DKK 64
#define FFF 4096

typedef unsigned short u16;
typedef unsigned int u32;
typedef __attribute__((ext_vector_type(8))) short s16x8;
typedef __attribute__((ext_vector_type(4))) float f32x4;

static __device__ __forceinline__ float bf2f(u16 s) {
  union { u32 u; float f; } v; v.u = ((u32)s) << 16; return v.f;
}
static __device__ __forceinline__ u16 f2bf(float f) {
  union { float f; u32 u; } v; v.f = f;
  u32 r = v.u + 0x7FFFu + ((v.u >> 16) & 1u);
  return (u16)(r >> 16);
}

#define GLDS(gp, lp) __builtin_amdgcn_global_load_lds( \
    (const __attribute__((address_space(1))) u32*)(gp), \
    (__attribute__((address_space(3))) u32*)(lp), 16, 0, 0)

// XCD-chunked bijective block swizzle (m204 formula), 8-row supertiles.
static __device__ __forceinline__ void swz_block(int& bx, int& by) {
  int gx = gridDim.x, gy = gridDim.y;
  int nwg = gx * gy;
  int orig = by * gx + bx;
  int q = nwg >> 3, r = nwg & 7;
  int xcd = orig & 7, sl = orig >> 3;
  int wgid = (xcd < r ? xcd * (q + 1) : r * (q + 1) + (xcd - r) * q) + sl;
  int g = gx << 3;
  int grp = wgid / g, rem = wgid % g;
  bx = rem >> 3;
  by = (grp << 3) + (rem & 7);
}

// ---------------- f32 -> bf16 elementwise ----------------
__global__ __launch_bounds__(256) void k_f2bf(const float* __restrict__ s, u16* __restrict__ d, int n) {
  int i = (blockIdx.x * 256 + threadIdx.x) * 4;
  if (i < n) {
    float4 v = *(const float4*)(s + i);
    u16 o[4] = { f2bf(v.x), f2bf(v.y), f2bf(v.z), f2bf(v.w) };
    *(ushort4*)(d + i) = *(ushort4*)o;
  }
}

// ---------------- a+b -> bf16 (split-K combine) ----------------
__global__ __launch_bounds__(256) void k_combine_bf(const float* __restrict__ a, const float* __restrict__ b,
                                                    u16* __restrict__ d, int n) {
  int i = (blockIdx.x * 256 + threadIdx.x) * 4;
  if (i < n) {
    float4 va = *(const float4*)(a + i);
    float4 vb = *(const float4*)(b + i);
    u16 o[4] = { f2bf(va.x + vb.x), f2bf(va.y + vb.y), f2bf(va.z + vb.z), f2bf(va.w + vb.w) };
    *(ushort4*)(d + i) = *(ushort4*)o;
  }
}

// ---------------- x passthrough to d_out + bf16 convert, one read ----------------
__global__ __launch_bounds__(256) void k_xprep(const float* __restrict__ x, float* __restrict__ dout,
                                               u16* __restrict__ xb, int n) {
  int i = (blockIdx.x * 256 + threadIdx.x) * 4;
  if (i < n) {
    float4 v = *(const float4*)(x + i);
    *(float4*)(dout + i) = v;
    u16 o[4] = { f2bf(v.x), f2bf(v.y), f2bf(v.z), f2bf(v.w) };
    *(ushort4*)(xb + i) = *(ushort4*)o;
  }
}

// ---------------- masked softmax over d (axis -2), write bf16 B[n= h*64+k][d] ----------------
__global__ __launch_bounds__(256) void k_softmax_w_bf(const float* __restrict__ W, u16* __restrict__ Bt) {
  int col = blockIdx.x;           // h*64 + k
  int h = col >> 6, k = col & 63;
  int tid = threadIdx.x;
  const float* w = W + ((size_t)h * DD) * DKK + k;
  __shared__ float red[256];
  float m = -1e30f;
  for (int d = k + tid; d < DD; d += 256) m = fmaxf(m, w[(size_t)d * DKK]);
  red[tid] = m; __syncthreads();
  for (int s = 128; s > 0; s >>= 1) { if (tid < s) red[tid] = fmaxf(red[tid], red[tid + s]); __syncthreads(); }
  m = red[0]; __syncthreads();
  float sum = 0.f;
  for (int d = k + tid; d < DD; d += 256) sum += __expf(w[(size_t)d * DKK] - m);
  red[tid] = sum; __syncthreads();
  for (int s = 128; s > 0; s >>= 1) { if (tid < s) red[tid] += red[tid + s]; __syncthreads(); }
  float inv = 1.f / red[0];
  for (int d = tid; d < DD; d += 256) {
    float v = (d >= k) ? __expf(w[(size_t)d * DKK] - m) * inv : 0.f;
    Bt[(size_t)col * DD + d] = f2bf(v);
  }
}

// ---------------- reorder (H, D, DK) -> bf16 B[n=h*64+k][d] ----------------
__global__ __launch_bounds__(256) void k_reorder_w_bf(const float* __restrict__ W, u16* __restrict__ Bt) {
  int d0 = blockIdx.x << 6, h = blockIdx.y;
  __shared__ float t[64][65];
  int tid = threadIdx.x;
  const float* src = W + (size_t)h * DD * DKK + (size_t)d0 * DKK;
  #pragma unroll
  for (int i = 0; i < 16; ++i) {
    int e = i * 256 + tid; int r = e >> 6, c = e & 63;
    t[r][c] = src[(size_t)r * DKK + c];
  }
  __syncthreads();
  #pragma unroll
  for (int i = 0; i < 16; ++i) {
    int e = i * 256 + tid; int c = e >> 6, r = e & 63;
    Bt[((size_t)(h * 64 + c)) * DD + d0 + r] = f2bf(t[r][c]);
  }
}

// ---------------- transpose (K,N) f32 -> bf16 B[n][k] ----------------
__global__ __launch_bounds__(256) void k_transpose_bf(const float* __restrict__ W, u16* __restrict__ Bt) {
  int k0 = blockIdx.x << 6, n0 = blockIdx.y << 6;
  __shared__ float t[64][65];
  int tid = threadIdx.x;
  #pragma unroll
  for (int i = 0; i < 16; ++i) {
    int e = i * 256 + tid; int r = e >> 6, c = e & 63;
    t[r][c] = W[(size_t)(k0 + r) * DD + n0 + c];
  }
  __syncthreads();
  #pragma unroll
  for (int i = 0; i < 16; ++i) {
    int e = i * 256 + tid; int c = e >> 6, r = e & 63;
    Bt[(size_t)(n0 + c) * DD + k0 + r] = f2bf(t[r][c]);
  }
}

// ---------------- MFMA NT GEMM: C = A(MxK) * B(NxK)^T (bf16 in, f32 acc) ----------------
// 128x128 tile, BK=32, 256 threads (4 waves 2x2, wave-tile 64x64), 2-phase dbuf LDS,
// GLDS staging, XCD swizzle, split-K via blockIdx.z (up to 4 f32 partial buffers).
__global__ __launch_bounds__(256) void k_mfma_nt(
    const u16* __restrict__ A, const u16* __restrict__ B,
    float* __restrict__ Cf, float* __restrict__ Cf2, float* __restrict__ Cf3, float* __restrict__ Cf4,
    u16* __restrict__ Cb, u16* __restrict__ Cb2, u16* __restrict__ Ct,
    const float* __restrict__ bias, int relu, int mode, int M, int N, int K) {
  __shared__ u16 SLDS[4 * 4096];   // [0,8192)=A bufs, [8192,16384)=B bufs; epilogue reuses [0,8704)
  int bx = blockIdx.x, by = blockIdx.y;
  swz_block(bx, by);
  int tid = threadIdx.x, wave = tid >> 6, lane = tid & 63;
  int row0 = by << 7, col0 = bx << 7;
  int wm = (wave >> 1) << 6, wn = (wave & 1) << 6;

  int Ksl = K / gridDim.z;
  int kbase = blockIdx.z * Ksl;
  int kend = kbase + Ksl;

  f32x4 acc[4][4];
  #pragma unroll
  for (int m = 0; m < 4; ++m)
    #pragma unroll
    for (int n = 0; n < 4; ++n) acc[m][n] = f32x4{0.f, 0.f, 0.f, 0.f};

  // staging: [128][32] bf16 = 8 KB = 8 chunks of 1 KB (16 rows each); wave w owns chunks 2w, 2w+1
  int c0 = wave * 2, c1 = wave * 2 + 1;
  int r0 = (c0 << 4) + (lane >> 2);
  int r1 = (c1 << 4) + (lane >> 2);
  int ce = (lane & 3) << 3;
  const u16* Ag0 = A + (size_t)(row0 + r0) * K + ce;
  const u16* Ag1 = A + (size_t)(row0 + r1) * K + ce;
  const u16* Bg0 = B + (size_t)(col0 + r0) * K + ce;
  const u16* Bg1 = B + (size_t)(col0 + r1) * K + ce;

  int fr = lane & 15, kg = (lane >> 4) << 3;
  int ardo = (wm + fr) * 32 + kg;
  int brdo = 8192 + (wn + fr) * 32 + kg;

  auto STAGE = [&](int buf, int k0) {
    u16* Ab = SLDS + buf * 4096;
    u16* Bb = SLDS + 8192 + buf * 4096;
    GLDS(Ag0 + k0, Ab + c0 * 512);
    GLDS(Ag1 + k0, Ab + c1 * 512);
    GLDS(Bg0 + k0, Bb + c0 * 512);
    GLDS(Bg1 + k0, Bb + c1 * 512);
  };

  STAGE(0, kbase);
  __syncthreads();
  int cur = 0;
  for (int k0 = kbase; k0 < kend; k0 += 32) {
    int nxt = k0 + 32;
    if (nxt < kend) STAGE(cur ^ 1, nxt);   // next-tile loads fly under current MFMA
    const u16* Ard = SLDS + cur * 4096 + ardo;
    const u16* Brd = SLDS + cur * 4096 + brdo;
    s16x8 aF[4], bF[4];
    #pragma unroll
    for (int m = 0; m < 4; ++m) aF[m] = *(const s16x8*)(Ard + m * 16 * 32);
    #pragma unroll
    for (int n = 0; n < 4; ++n) bF[n] = *(const s16x8*)(Brd + n * 16 * 32);
    #pragma unroll
    for (int m = 0; m < 4; ++m)
      #pragma unroll
      for (int n = 0; n < 4; ++n)
        acc[m][n] = __builtin_amdgcn_mfma_f32_16x16x32_bf16(aF[m], bF[n], acc[m][n], 0, 0, 0);
    __syncthreads();                       // drains vmcnt(0): next buf ready, cur free
    cur ^= 1;
  }

  int fq = (lane >> 4) << 2;

  // ---- f32 partial outputs: direct stores (16 fr-lanes x 4B = full 64B lines) ----
  if (mode == 0 && (Cf || Cf2)) {
    int z = blockIdx.z;
    float* Cpart = (z == 0) ? Cf : ((z == 1) ? Cf2 : ((z == 2) ? Cf3 : Cf4));
    #pragma unroll
    for (int n = 0; n < 4; ++n) {
      int col = col0 + wn + n * 16 + fr;
      float bs = bias ? bias[col] : 0.f;
      #pragma unroll
      for (int m = 0; m < 4; ++m) {
        #pragma unroll
        for (int r = 0; r < 4; ++r) {
          float v = acc[m][n][r] + bs;
          if (relu) v = fmaxf(v, 0.f);
          Cpart[(size_t)(row0 + wm + m * 16 + fq + r) * N + col] = v;
        }
      }
    }
    return;
  }

  // ---- bf16 outputs: per-wave LDS transpose -> coalesced 64B/lane stores ----
  u16* dstRow = nullptr; u16* dstCol = nullptr;
  int rowPitch = 1024, colBase = col0 & 1023;
  if (mode == 0) { dstRow = Cb; rowPitch = N; colBase = col0; }
  else if (mode == 1) { int q = col0 >> 10; if (q == 0) dstRow = Cb; else if (q == 1) dstRow = Cb2; else dstCol = Ct; }
  else { int q = col0 >> 10; if (q == 0) dstRow = Cb; else dstCol = Ct; }

  u16* Ep = SLDS + wave * 2176;   // per-wave [32][68] u16 (wave-private, no barrier needed)
  #pragma unroll
  for (int c = 0; c < 2; ++c) {
    #pragma unroll
    for (int m2 = 0; m2 < 2; ++m2) {
      int m = c * 2 + m2;
      #pragma unroll
      for (int n = 0; n < 4; ++n) {
        int col = col0 + wn + n * 16 + fr;
        float bs = bias ? bias[col] : 0.f;
        #pragma unroll
        for (int r = 0; r < 4; ++r) {
          float v = acc[m][n][r] + bs;
          if (relu) v = fmaxf(v, 0.f);
          Ep[(m2 * 16 + fq + r) * 68 + n * 16 + fr] = f2bf(v);
        }
      }
    }
    if (dstRow) {
      int rl = lane >> 1, half = lane & 1;
      const u16* src = Ep + rl * 68 + half * 32;
      u16* gd = dstRow + (size_t)(row0 + wm + c * 32 + rl) * rowPitch + colBase + wn + half * 32;
      #pragma unroll
      for (int i = 0; i < 8; ++i) *(uint2*)(gd + i * 4) = *(const uint2*)(src + i * 4);
    } else {
      u16 tmp[32];
      #pragma unroll
      for (int s = 0; s < 32; ++s) tmp[s] = Ep[s * 68 + lane];
      u16* gd = dstCol + (size_t)(colBase + wn + lane) * 4096 + row0 + wm + c * 32;
      #pragma unroll
      for (int i = 0; i < 4; ++i) *(uint4*)(gd + i * 8) = ((const uint4*)tmp)[i];
    }
  }
}

// ---------------- stage one 64x64 bf16 tile (512 threads, 1 uint4 each) -> LDS [64][72] ----------------
static __device__ __forceinline__ void stage_tile512(const u16* __restrict__ g, int gp, u16* L, int tid) {
  int row = tid >> 3, col8 = (tid & 7) << 3;
  *(uint4*)(L + row * 72 + col8) = *(const uint4*)(g + (size_t)row * gp + col8);
}

// ---------------- attention pass 1 (MFMA, 8 waves, 2 s-tiles/block) ----------------
// csum[s] = sum_t exp(S[t][s]); no-max softmax (S small, exp-safe; shift-invariant).
// T14: next Q-tile global loads issue right after LDS write -> latency under MFMA.
__global__ __launch_bounds__(512) void k_attn_stats_mfma(const u16* __restrict__ Qb, const u16* __restrict__ Kb,
                                                         float* __restrict__ csum) {
  __shared__ u16 Ks[2 * 4608];
  __shared__ u16 Qs[4608];
  int tid = threadIdx.x, wave = tid >> 6, lane = tid & 63;
  int bh = blockIdx.x, b = bh >> 4, h = bh & 15;
  int s0 = blockIdx.y << 7;               // 128 s-cols per block
  int tile = wave >> 2, sw = wave & 3;
  stage_tile512(Kb + ((size_t)(b * TT + s0)) * DD + h * 64, DD, Ks, tid);
  stage_tile512(Kb + ((size_t)(b * TT + s0 + 64)) * DD + h * 64, DD, Ks + 4608, tid);
  int row = tid >> 3, col8 = (tid & 7) << 3;
  const u16* Qg = Qb + ((size_t)(b * TT) + row) * DD + h * 64 + col8;
  uint4 qreg = *(const uint4*)Qg;          // tile t0=0
  __syncthreads();                          // Ks visible
  int fr = lane & 15, g = lane >> 4;
  const u16* Bbase = Ks + tile * 4608 + (sw * 16 + fr) * 72 + g * 8;   // B-frag: K rows (n = s)
  const u16* Abase = Qs + fr * 72 + g * 8;                             // A-frag: Q rows (m = t)
  s16x8 bF0 = *(const s16x8*)(Bbase);
  s16x8 bF1 = *(const s16x8*)(Bbase + 32);
  float sum = 0.f;
  for (int t0 = 0; t0 < TT; t0 += 64) {
    __syncthreads();                        // prior Qs reads done
    *(uint4*)(Qs + row * 72 + col8) = qreg;
    __syncthreads();                        // Qs visible
    if (t0 + 64 < TT) qreg = *(const uint4*)(Qg + (size_t)(t0 + 64) * DD);
    #pragma unroll
    for (int mt = 0; mt < 4; ++mt) {
      f32x4 acc = f32x4{0.f, 0.f, 0.f, 0.f};
      s16x8 a0 = *(const s16x8*)(Abase + mt * 16 * 72);
      s16x8 a1 = *(const s16x8*)(Abase + mt * 16 * 72 + 32);
      acc = __builtin_amdgcn_mfma_f32_16x16x32_bf16(a0, bF0, acc, 0, 0, 0);
      acc = __builtin_amdgcn_mfma_f32_16x16x32_bf16(a1, bF1, acc, 0, 0, 0);
      sum += __expf(acc[0] * 0.125f) + __expf(acc[1] * 0.125f)
           + __expf(acc[2] * 0.125f) + __expf(acc[3] * 0.125f);
    }
  }
  sum += __shfl_xor(sum, 16, 64);
  sum += __shfl_xor(sum, 32, 64);
  if (lane < 16) csum[(size_t)bh * TT + s0 + tile * 64 + sw * 16 + lane] = sum;
}

// ---------------- attention pass 2 (MFMA, 8 waves, 2 t-tiles/block) ----------------
// P = exp(S)/csum (no max). T14: K/V/csum loads for tile s0+64 issue under tile-s0 compute.
__global__ __launch_bounds__(512) void k_attn_apply_mfma(const u16* __restrict__ Qb, const u16* __restrict__ Kb,
                                                         const u16* __restrict__ Vt,
                                                         const float* __restrict__ csum,
                                                         u16* __restrict__ Op) {
  __shared__ u16 Qs[2 * 4608];
  __shared__ u16 KV2[2 * 4608];    // Ks | VTs; reused by the write epilogue
  __shared__ u16 Pl[8 * 1024];     // per-wave [16 t][64 s] bf16, XOR-swizzled
  __shared__ float rcsL[64];
  u16* Ks = KV2;
  u16* VTs = KV2 + 4608;
  int tid = threadIdx.x, wave = tid >> 6, lane = tid & 63;
  int bh = blockIdx.x, b = bh >> 4, h = bh & 15;
  int t0 = blockIdx.y << 7;               // 128 t-rows per block
  int tile = wave >> 2, tw = wave & 3;
  stage_tile512(Qb + ((size_t)(b * TT + t0)) * DD + h * 64, DD, Qs, tid);
  stage_tile512(Qb + ((size_t)(b * TT + t0 + 64)) * DD + h * 64, DD, Qs + 4608, tid);
  int row = tid >> 3, col8 = (tid & 7) << 3;
  const u16* Kg = Kb + ((size_t)(b * TT) + row) * DD + h * 64 + col8;
  const u16* Vg = Vt + ((size_t)(h * 64) + row) * 4096 + (size_t)b * TT + col8;
  const size_t cbase = (size_t)bh * TT;
  uint4 kreg = *(const uint4*)Kg;          // s0 = 0
  uint4 vreg = *(const uint4*)Vg;
  float rc0 = (tid < 64) ? csum[cbase + tid] : 0.f;
  __syncthreads();                          // Qs visible
  int fr = lane & 15, g = lane >> 4;
  const u16* QbF = Qs + tile * 4608 + (tw * 16 + fr) * 72 + g * 8;   // B-frag (n = t)
  const u16* KaF = Ks + fr * 72 + g * 8;                             // A-frag rows s
  char* Pw = (char*)(Pl + wave * 1024);
  uint swz = ((uint)(lane & 7)) << 4;
  s16x8 qF0 = *(const s16x8*)(QbF);
  s16x8 qF1 = *(const s16x8*)(QbF + 32);
  f32x4 acc_o[4];
  #pragma unroll
  for (int nt = 0; nt < 4; ++nt) acc_o[nt] = f32x4{0.f, 0.f, 0.f, 0.f};

  for (int s0 = 0; s0 < TT; s0 += 64) {
    __syncthreads();                        // prior Ks/VTs reads done
    *(uint4*)(Ks + row * 72 + col8) = kreg;
    *(uint4*)(VTs + row * 72 + col8) = vreg;
    if (tid < 64) rcsL[tid] = 1.f / rc0;
    __syncthreads();                        // visible
    if (s0 + 64 < TT) {                     // issue next-tile loads; hide under compute
      kreg = *(const uint4*)(Kg + (size_t)(s0 + 64) * DD);
      vreg = *(const uint4*)(Vg + s0 + 64);
      if (tid < 64) rc0 = csum[cbase + s0 + 64 + tid];
    }
    // S^T tiles + exp -> P (per-wave)
    #pragma unroll
    for (int mt = 0; mt < 4; ++mt) {
      f32x4 acc = f32x4{0.f, 0.f, 0.f, 0.f};
      s16x8 a0 = *(const s16x8*)(KaF + mt * 16 * 72);
      s16x8 a1 = *(const s16x8*)(KaF + mt * 16 * 72 + 32);
      acc = __builtin_amdgcn_mfma_f32_16x16x32_bf16(a0, qF0, acc, 0, 0, 0);
      acc = __builtin_amdgcn_mfma_f32_16x16x32_bf16(a1, qF1, acc, 0, 0, 0);
      f32x4 rc4 = *(const f32x4*)&rcsL[mt * 16 + g * 4];
      u16 pb[4];
      #pragma unroll
      for (int r = 0; r < 4; ++r)
        pb[r] = f2bf(__expf(acc[r] * 0.125f) * rc4[r]);
      uint woff = (uint)fr * 128 + (uint)(mt * 16 + g * 4) * 2;
      uint2 wv; wv.x = (u32)pb[0] | ((u32)pb[1] << 16); wv.y = (u32)pb[2] | ((u32)pb[3] << 16);
      *(uint2*)(Pw + (woff ^ swz)) = wv;
    }
    // PV: A = P (own wave's tile), B = V^T
    uint rbase = (uint)fr * 128;
    s16x8 pF0 = *(const s16x8*)(Pw + ((rbase + g * 16) ^ swz));
    s16x8 pF1 = *(const s16x8*)(Pw + ((rbase + 64 + g * 16) ^ swz));
    #pragma unroll
    for (int nt = 0; nt < 4; ++nt) {
      s16x8 v0 = *(const s16x8*)(VTs + (nt * 16 + fr) * 72 + g * 8);
      s16x8 v1 = *(const s16x8*)(VTs + (nt * 16 + fr) * 72 + 32 + g * 8);
      acc_o[nt] = __builtin_amdgcn_mfma_f32_16x16x32_bf16(pF0, v0, acc_o[nt], 0, 0, 0);
      acc_o[nt] = __builtin_amdgcn_mfma_f32_16x16x32_bf16(pF1, v1, acc_o[nt], 0, 0, 0);
    }
  }
  // write epilogue: per-wave LDS transpose (reuse KV2) -> coalesced 32B/lane stores
  __syncthreads();                         // all waves done reading Ks/VTs
  u16* Ep = KV2 + wave * 1088;             // per-wave [16][68]
  #pragma unroll
  for (int nt = 0; nt < 4; ++nt)
    #pragma unroll
    for (int r = 0; r < 4; ++r)
      Ep[(g * 4 + r) * 68 + nt * 16 + fr] = f2bf(acc_o[nt][r]);
  {
    int rw = lane >> 2, seg = lane & 3;
    const u16* src = Ep + rw * 68 + seg * 16;
    u16* gd = Op + ((size_t)(b * TT + t0 + tile * 64 + tw * 16 + rw)) * DD + h * 64 + seg * 16;
    #pragma unroll
    for (int i = 0; i < 4; ++i) *(uint2*)(gd + i * 4) = *(const uint2*)(src + i * 4);
  }
}

// ---------------- O = norm(sum of partials + bias + residual), ddof=1 ----------------
__global__ __launch_bounds__(256) void k_add_norm(const float* __restrict__ A, const float* __restrict__ A2,
                                                  const float* __restrict__ A3, const float* __restrict__ A4,
                                                  const float* __restrict__ bias,
                                                  const float* __restrict__ Bv,
                                                  float* __restrict__ O, u16* __restrict__ Ob) {
  int row = blockIdx.x, tid = threadIdx.x;
  size_t base = (size_t)row * DD;
  __shared__ float red[256];
  float v[4]; float s = 0.f;
  #pragma unroll
  for (int i = 0; i < 4; ++i) {
    int c = tid + (i << 8);
    float t = A[base + c] + Bv[base + c];
    if (A2) t += A2[base + c];
    if (A3) t += A3[base + c];
    if (A4) t += A4[base + c];
    if (bias) t += bias[c];
    v[i] = t; s += t;
  }
  red[tid] = s; __syncthreads();
  for (int t = 128; t > 0; t >>= 1) { if (tid < t) red[tid] += red[tid + t]; __syncthreads(); }
  float mean = red[0] * (1.f / 1024.f);
  __syncthreads();
  float vs = 0.f;
  #pragma unroll
  for (int i = 0; i < 4; ++i) { float d = v[i] - mean; vs += d * d; }
  red[tid] = vs; __syncthreads();
  for (int t = 128; t > 0; t >>= 1) { if (tid < t) red[tid] += red[tid + t]; __syncthreads(); }
  float inv = rsqrtf(red[0] * (1.f / 1023.f));
  #pragma unroll
  for (int i = 0; i < 4; ++i) {
    float o = (v[i] - mean) * inv;
    O[base + tid + (i << 8)] = o;
    if (Ob) Ob[base + tid + (i << 8)] = f2bf(o);
  }
}

extern "C" void kernel_launch(void* const* d_in, const int* in_sizes, int n_in,
                              void* d_out, int out_size, void* d_ws, size_t ws_size,
                              hipStream_t stream) {
  (void)in_sizes; (void)n_in; (void)out_size; (void)ws_size;
  const float* x    = (const float*)d_in[0];
  const float* y    = (const float*)d_in[1];
  const float* Wq1  = (const float*)d_in[2];
  const float* Wk1  = (const float*)d_in[3];
  const float* Wv1  = (const float*)d_in[4];
  const float* Wo1  = (const float*)d_in[5];
  const float* Wq2  = (const float*)d_in[6];
  const float* Wk2  = (const float*)d_in[7];
  const float* Wv2  = (const float*)d_in[8];
  const float* Wo2  = (const float*)d_in[9];
  const float* w_in  = (const float*)d_in[10];
  const float* b_in  = (const float*)d_in[11];
  const float* w_out = (const float*)d_in[12];
  const float* b_out = (const float*)d_in[13];

  float* ws = (float*)d_ws;
  size_t off = 0;
  auto allocw = [&](size_t nw) { float* p = ws + off; off += nw; return p; };
  const size_t MR = (size_t)BB * TT;           // 4096
  const size_t ND = MR * DD;                   // 4.19M elems

  u16* Bq   = (u16*)allocw(512 * 1024);        // Bq|Bk|Bv contiguous => fused B (3072 x 1024)
  u16* Bk   = (u16*)allocw(512 * 1024);
  u16* Bv   = (u16*)allocw(512 * 1024);
  u16* Bwo  = (u16*)allocw(512 * 1024);
  u16* Wi   = (u16*)allocw(2 * 1024 * 1024);
  u16* Wob  = (u16*)allocw(2 * 1024 * 1024);
  u16* xbf  = (u16*)allocw(ND / 2);            // xbf|ybf f32 span = FF2 partial 4
  u16* ybf  = (u16*)allocw(ND / 2);
  u16* REG  = (u16*)allocw(ND * 2);
  float* ff2  = allocw(ND);
  float* out1 = allocw(ND);
  float* out2 = allocw(ND);
  float* csum = allocw((size_t)BB * HH * TT);

  u16* Qb = REG;
  u16* Kb = REG + ND;
  u16* Vt = REG + 2 * ND;   // V col-major (1024 x 4096), pitch 4096
  u16* Mb = REG + 3 * ND;   // mhaO; also out1_bf between layers
  u16* ff1b = REG;
  u16* out2bf = ybf;
  float* doutHi = (float*)d_out + ND;  // free until final add_norm writes it
  float* pXY = (float*)xbf;            // xbf|ybf span (dead after KV proj / FF1)

  dim3 blk(256), blkA(512);
  dim3 gConv(4096);
  dim3 gSm(1024);
  dim3 gRw(16, 16);
  dim3 gQKV(24, 32);         // N=3072
  dim3 gKV(16, 32);          // N=2048
  dim3 gP2(8, 32, 2);        // N=1024, split-K=2
  dim3 gF1(32, 32);          // N=4096
  dim3 gFF2(8, 32, 4);       // N=1024, split-K=4 (K=4096)
  dim3 gAttn(BB * HH, TT / 128);
  dim3 gNorm(MR);

  // x passthrough + bf16 convert, one pass
  k_xprep<<<gConv, blk, 0, stream>>>(x, (float*)d_out, xbf, (int)ND);
  k_f2bf<<<gConv, blk, 0, stream>>>(y, ybf, (int)ND);
  k_f2bf<<<gConv, blk, 0, stream>>>(w_in, Wi, FFF * DD);
  k_f2bf<<<gConv, blk, 0, stream>>>(w_out, Wob, DD * FFF);

  // ---- Layer 1: masked self-attention on y ----
  k_softmax_w_bf<<<gSm, blk, 0, stream>>>(Wq1, Bq);
  k_softmax_w_bf<<<gSm, blk, 0, stream>>>(Wk1, Bk);
  k_reorder_w_bf<<<gRw, blk, 0, stream>>>(Wv1, Bv);
  k_transpose_bf<<<gRw, blk, 0, stream>>>(Wo1, Bwo);
  k_mfma_nt<<<gQKV, blk, 0, stream>>>(ybf, Bq, nullptr, nullptr, nullptr, nullptr, Qb, Kb, Vt, nullptr, 0, 1, 4096, 3072, 1024);
  k_attn_stats_mfma<<<gAttn, blkA, 0, stream>>>(Qb, Kb, csum);
  k_attn_apply_mfma<<<gAttn, blkA, 0, stream>>>(Qb, Kb, Vt, csum, Mb);
  // out-proj split-K=2: partials ff2 + out2 (out2 unused until layer 2)
  k_mfma_nt<<<gP2, blk, 0, stream>>>(Mb, Bwo, ff2, out2, nullptr, nullptr, nullptr, nullptr, nullptr, nullptr, 0, 0, 4096, 1024, 1024);
  k_add_norm<<<gNorm, blk, 0, stream>>>(ff2, out2, nullptr, nullptr, nullptr, y, out1, Mb /* out1_bf */);

  // ---- Layer 2: cross-attention (Q from out1, K/V from x) ----
  k_reorder_w_bf<<<gRw, blk, 0, stream>>>(Wq2, Bq);
  k_reorder_w_bf<<<gRw, blk, 0, stream>>>(Wk2, Bk);
  k_reorder_w_bf<<<gRw, blk, 0, stream>>>(Wv2, Bv);
  k_transpose_bf<<<gRw, blk, 0, stream>>>(Wo2, Bwo);
  // Q2 proj split-K=2 into dead f32 buffers, then combine -> Qb bf16
  k_mfma_nt<<<gP2, blk, 0, stream>>>(Mb /* out1_bf */, Bq, ff2, out2, nullptr, nullptr, nullptr, nullptr, nullptr, nullptr, 0, 0, 4096, 1024, 1024);
  k_combine_bf<<<gConv, blk, 0, stream>>>(ff2, out2, Qb, (int)ND);
  k_mfma_nt<<<gKV, blk, 0, stream>>>(xbf, Bk, nullptr, nullptr, nullptr, nullptr, Kb, nullptr, Vt, nullptr, 0, 2, 4096, 2048, 1024);
  k_attn_stats_mfma<<<gAttn, blkA, 0, stream>>>(Qb, Kb, csum);
  k_attn_apply_mfma<<<gAttn, blkA, 0, stream>>>(Qb, Kb, Vt, csum, Mb);
  // out-proj split-K=2: partials ff2 + doutHi
  k_mfma_nt<<<gP2, blk, 0, stream>>>(Mb, Bwo, ff2, doutHi, nullptr, nullptr, nullptr, nullptr, nullptr, nullptr, 0, 0, 4096, 1024, 1024);
  k_add_norm<<<gNorm, blk, 0, stream>>>(ff2, doutHi, nullptr, nullptr, nullptr, out1, out2, out2bf);

  // ---- FF ----
  k_mfma_nt<<<gF1, blk, 0, stream>>>(out2bf, Wi, nullptr, nullptr, nullptr, nullptr, ff1b, nullptr, nullptr, b_in, 1, 0, 4096, 4096, 1024);
  // FF2 split-K=4: partials ff2, doutHi, out1, pXY (all dead here); bias ONCE in final norm
  k_mfma_nt<<<gFF2, blk, 0, stream>>>(ff1b, Wob, ff2, doutHi, out1, pXY, nullptr, nullptr, nullptr, nullptr, 0, 0, 4096, 1024, 4096);
  k_add_norm<<<gNorm, blk, 0, stream>>>(ff2, doutHi, out1, pXY, b_out, out2, doutHi, nullptr);
}

// Round 10
// 433.521 us; speedup vs baseline: 1.0606x; 1.0430x over previous
//
#include <hip/hip_runtime.h>
#include <hip/hip_bf16.h>

#define BB 4
#define TT 1024
#define DD 1024
#define HH 16
#define DKK 64
#define FFF 4096

typedef unsigned short u16;
typedef unsigned int u32;
typedef __attribute__((ext_vector_type(8))) short s16x8;
typedef __attribute__((ext_vector_type(4))) float f32x4;

static __device__ __forceinline__ float bf2f(u16 s) {
  union { u32 u; float f; } v; v.u = ((u32)s) << 16; return v.f;
}
static __device__ __forceinline__ u16 f2bf(float f) {
  union { float f; u32 u; } v; v.f = f;
  u32 r = v.u + 0x7FFFu + ((v.u >> 16) & 1u);
  return (u16)(r >> 16);
}

#define GLDS(gp, lp) __builtin_amdgcn_global_load_lds( \
    (const __attribute__((address_space(1))) u32*)(gp), \
    (__attribute__((address_space(3))) u32*)(lp), 16, 0, 0)

// XCD-chunked bijective block swizzle (m204 formula), 8-row supertiles.
static __device__ __forceinline__ void swz_block(int& bx, int& by) {
  int gx = gridDim.x, gy = gridDim.y;
  int nwg = gx * gy;
  int orig = by * gx + bx;
  int q = nwg >> 3, r = nwg & 7;
  int xcd = orig & 7, sl = orig >> 3;
  int wgid = (xcd < r ? xcd * (q + 1) : r * (q + 1) + (xcd - r) * q) + sl;
  int g = gx << 3;
  int grp = wgid / g, rem = wgid % g;
  bx = rem >> 3;
  by = (grp << 3) + (rem & 7);
}

// ---------------- f32 -> bf16 elementwise ----------------
__global__ __launch_bounds__(256) void k_f2bf(const float* __restrict__ s, u16* __restrict__ d, int n) {
  int i = (blockIdx.x * 256 + threadIdx.x) * 4;
  if (i < n) {
    float4 v = *(const float4*)(s + i);
    u16 o[4] = { f2bf(v.x), f2bf(v.y), f2bf(v.z), f2bf(v.w) };
    *(ushort4*)(d + i) = *(ushort4*)o;
  }
}

// ---------------- a+b -> bf16 (split-K combine) ----------------
__global__ __launch_bounds__(256) void k_combine_bf(const float* __restrict__ a, const float* __restrict__ b,
                                                    u16* __restrict__ d, int n) {
  int i = (blockIdx.x * 256 + threadIdx.x) * 4;
  if (i < n) {
    float4 va = *(const float4*)(a + i);
    float4 vb = *(const float4*)(b + i);
    u16 o[4] = { f2bf(va.x + vb.x), f2bf(va.y + vb.y), f2bf(va.z + vb.z), f2bf(va.w + vb.w) };
    *(ushort4*)(d + i) = *(ushort4*)o;
  }
}

// ---------------- x passthrough to d_out + bf16 convert, one read ----------------
__global__ __launch_bounds__(256) void k_xprep(const float* __restrict__ x, float* __restrict__ dout,
                                               u16* __restrict__ xb, int n) {
  int i = (blockIdx.x * 256 + threadIdx.x) * 4;
  if (i < n) {
    float4 v = *(const float4*)(x + i);
    *(float4*)(dout + i) = v;
    u16 o[4] = { f2bf(v.x), f2bf(v.y), f2bf(v.z), f2bf(v.w) };
    *(ushort4*)(xb + i) = *(ushort4*)o;
  }
}

// ---------------- masked softmax over d (axis -2), write bf16 B[n= h*64+k][d] ----------------
__global__ __launch_bounds__(256) void k_softmax_w_bf(const float* __restrict__ W, u16* __restrict__ Bt) {
  int col = blockIdx.x;           // h*64 + k
  int h = col >> 6, k = col & 63;
  int tid = threadIdx.x;
  const float* w = W + ((size_t)h * DD) * DKK + k;
  __shared__ float red[256];
  float m = -1e30f;
  for (int d = k + tid; d < DD; d += 256) m = fmaxf(m, w[(size_t)d * DKK]);
  red[tid] = m; __syncthreads();
  for (int s = 128; s > 0; s >>= 1) { if (tid < s) red[tid] = fmaxf(red[tid], red[tid + s]); __syncthreads(); }
  m = red[0]; __syncthreads();
  float sum = 0.f;
  for (int d = k + tid; d < DD; d += 256) sum += __expf(w[(size_t)d * DKK] - m);
  red[tid] = sum; __syncthreads();
  for (int s = 128; s > 0; s >>= 1) { if (tid < s) red[tid] += red[tid + s]; __syncthreads(); }
  float inv = 1.f / red[0];
  for (int d = tid; d < DD; d += 256) {
    float v = (d >= k) ? __expf(w[(size_t)d * DKK] - m) * inv : 0.f;
    Bt[(size_t)col * DD + d] = f2bf(v);
  }
}

// ---------------- reorder (H, D, DK) -> bf16 B[n=h*64+k][d] ----------------
__global__ __launch_bounds__(256) void k_reorder_w_bf(const float* __restrict__ W, u16* __restrict__ Bt) {
  int d0 = blockIdx.x << 6, h = blockIdx.y;
  __shared__ float t[64][65];
  int tid = threadIdx.x;
  const float* src = W + (size_t)h * DD * DKK + (size_t)d0 * DKK;
  #pragma unroll
  for (int i = 0; i < 16; ++i) {
    int e = i * 256 + tid; int r = e >> 6, c = e & 63;
    t[r][c] = src[(size_t)r * DKK + c];
  }
  __syncthreads();
  #pragma unroll
  for (int i = 0; i < 16; ++i) {
    int e = i * 256 + tid; int c = e >> 6, r = e & 63;
    Bt[((size_t)(h * 64 + c)) * DD + d0 + r] = f2bf(t[r][c]);
  }
}

// ---------------- transpose (K,N) f32 -> bf16 B[n][k] ----------------
__global__ __launch_bounds__(256) void k_transpose_bf(const float* __restrict__ W, u16* __restrict__ Bt) {
  int k0 = blockIdx.x << 6, n0 = blockIdx.y << 6;
  __shared__ float t[64][65];
  int tid = threadIdx.x;
  #pragma unroll
  for (int i = 0; i < 16; ++i) {
    int e = i * 256 + tid; int r = e >> 6, c = e & 63;
    t[r][c] = W[(size_t)(k0 + r) * DD + n0 + c];
  }
  __syncthreads();
  #pragma unroll
  for (int i = 0; i < 16; ++i) {
    int e = i * 256 + tid; int c = e >> 6, r = e & 63;
    Bt[(size_t)(n0 + c) * DD + k0 + r] = f2bf(t[r][c]);
  }
}

// ---------------- MFMA NT GEMM: C = A(MxK) * B(NxK)^T (bf16 in, f32 acc) ----------------
// 128x128 tile, BK=32, 512 threads (8 waves 2x4, wave-tile 64x32), 2-phase dbuf LDS,
// GLDS staging (1 load/thread), XCD swizzle, split-K via blockIdx.z (up to 4 partials).
// mode 0: Cf..Cf4 (f32 partials, direct) or Cb (bf16 row-major via per-wave LDS slab).
// mode 1 (QKV, N=3072): q=0 -> Cb, q=1 -> Cb2, q=2 -> col-major Ct (pitch M).
// mode 2 (KV,  N=2048): q=0 -> Cb, q=1 -> col-major Ct.
__global__ __launch_bounds__(512) void k_mfma_nt(
    const u16* __restrict__ A, const u16* __restrict__ B,
    float* __restrict__ Cf, float* __restrict__ Cf2, float* __restrict__ Cf3, float* __restrict__ Cf4,
    u16* __restrict__ Cb, u16* __restrict__ Cb2, u16* __restrict__ Ct,
    const float* __restrict__ bias, int relu, int mode, int M, int N, int K) {
  __shared__ u16 SLDS[4 * 4096];   // [0,8192)=A bufs, [8192,16384)=B bufs; epilogue: wave*2048 slabs
  int bx = blockIdx.x, by = blockIdx.y;
  swz_block(bx, by);
  int tid = threadIdx.x, wave = tid >> 6, lane = tid & 63;
  int row0 = by << 7, col0 = bx << 7;
  int wm = (wave >> 2) << 6;        // 0 / 64
  int wn = (wave & 3) << 5;         // 0 / 32 / 64 / 96

  int Ksl = K / gridDim.z;
  int kbase = blockIdx.z * Ksl;
  int kend = kbase + Ksl;

  f32x4 acc[4][2];
  #pragma unroll
  for (int m = 0; m < 4; ++m)
    #pragma unroll
    for (int n = 0; n < 2; ++n) acc[m][n] = f32x4{0.f, 0.f, 0.f, 0.f};

  // staging: [128][32] bf16 = 8 KB per matrix; 512 threads x 16B = exactly one GLDS each.
  // wave w covers rows [w*16, w*16+16): LDS dest = wave-uniform base + lane*16 (GLDS rule).
  int srow = tid >> 2, scol = (tid & 3) << 3;
  const u16* Ag = A + (size_t)(row0 + srow) * K + scol;
  const u16* Bg = B + (size_t)(col0 + srow) * K + scol;
  int wbase = wave << 9;            // u16 offset of this wave's 1KB chunk

  int fr = lane & 15, kg = (lane >> 4) << 3;
  int ardo = (wm + fr) * 32 + kg;
  int brdo = 8192 + (wn + fr) * 32 + kg;

  auto STAGE = [&](int buf, int k0) {
    GLDS(Ag + k0, SLDS + buf * 4096 + wbase);
    GLDS(Bg + k0, SLDS + 8192 + buf * 4096 + wbase);
  };

  STAGE(0, kbase);
  __syncthreads();
  int cur = 0;
  for (int k0 = kbase; k0 < kend; k0 += 32) {
    int nxt = k0 + 32;
    if (nxt < kend) STAGE(cur ^ 1, nxt);   // next-tile loads fly under current MFMA
    const u16* Ard = SLDS + cur * 4096 + ardo;
    const u16* Brd = SLDS + cur * 4096 + brdo;
    s16x8 aF[4], bF[2];
    #pragma unroll
    for (int m = 0; m < 4; ++m) aF[m] = *(const s16x8*)(Ard + m * 16 * 32);
    #pragma unroll
    for (int n = 0; n < 2; ++n) bF[n] = *(const s16x8*)(Brd + n * 16 * 32);
    #pragma unroll
    for (int m = 0; m < 4; ++m)
      #pragma unroll
      for (int n = 0; n < 2; ++n)
        acc[m][n] = __builtin_amdgcn_mfma_f32_16x16x32_bf16(aF[m], bF[n], acc[m][n], 0, 0, 0);
    __syncthreads();                       // drains vmcnt(0): next buf ready, cur free
    cur ^= 1;
  }

  int fq = (lane >> 4) << 2;

  // ---- f32 partial outputs: direct stores (16 fr-lanes x 4B = full 64B lines) ----
  if (mode == 0 && (Cf || Cf2)) {
    int z = blockIdx.z;
    float* Cpart = (z == 0) ? Cf : ((z == 1) ? Cf2 : ((z == 2) ? Cf3 : Cf4));
    #pragma unroll
    for (int n = 0; n < 2; ++n) {
      int col = col0 + wn + n * 16 + fr;
      float bs = bias ? bias[col] : 0.f;
      #pragma unroll
      for (int m = 0; m < 4; ++m) {
        #pragma unroll
        for (int r = 0; r < 4; ++r) {
          float v = acc[m][n][r] + bs;
          if (relu) v = fmaxf(v, 0.f);
          Cpart[(size_t)(row0 + wm + m * 16 + fq + r) * N + col] = v;
        }
      }
    }
    return;
  }

  // ---- bf16 outputs: per-wave [16][40] LDS slab, 4 m-passes -> coalesced stores ----
  u16* dstRow = nullptr; u16* dstCol = nullptr;
  int rowPitch = 1024, colBase = col0 & 1023;
  if (mode == 0) { dstRow = Cb; rowPitch = N; colBase = col0; }
  else if (mode == 1) { int q = col0 >> 10; if (q == 0) dstRow = Cb; else if (q == 1) dstRow = Cb2; else dstCol = Ct; }
  else { int q = col0 >> 10; if (q == 0) dstRow = Cb; else dstCol = Ct; }

  u16* Ep = SLDS + wave * 2048;   // wave-private slab (16*40=640 u16 used)
  #pragma unroll
  for (int m = 0; m < 4; ++m) {
    #pragma unroll
    for (int n = 0; n < 2; ++n) {
      int col = col0 + wn + n * 16 + fr;
      float bs = bias ? bias[col] : 0.f;
      #pragma unroll
      for (int r = 0; r < 4; ++r) {
        float v = acc[m][n][r] + bs;
        if (relu) v = fmaxf(v, 0.f);
        Ep[(fq + r) * 40 + n * 16 + fr] = f2bf(v);
      }
    }
    if (dstRow) {
      int rw = lane >> 2, seg = lane & 3;                  // 16 rows x 4 segs of 8
      const u16* src = Ep + rw * 40 + seg * 8;
      u16* gd = dstRow + (size_t)(row0 + wm + m * 16 + rw) * rowPitch + colBase + wn + seg * 8;
      *(uint4*)gd = *(const uint4*)src;                    // 4 lanes x 16B = 64B line
    } else {
      int c = lane >> 1, half = lane & 1;                  // 32 cols x 2 halves of 8 rows
      u16 tmp[8];
      #pragma unroll
      for (int j = 0; j < 8; ++j) tmp[j] = Ep[(half * 8 + j) * 40 + c];
      u16* gd = dstCol + (size_t)(colBase + wn + c) * 4096 + row0 + wm + m * 16 + half * 8;
      *(uint4*)gd = *(const uint4*)tmp;                    // 2 lanes x 16B = 32B per col
    }
  }
}

// ---------------- stage one 64x64 bf16 tile (512 threads, 1 uint4 each) -> LDS [64][72] ----------------
static __device__ __forceinline__ void stage_tile512(const u16* __restrict__ g, int gp, u16* L, int tid) {
  int row = tid >> 3, col8 = (tid & 7) << 3;
  *(uint4*)(L + row * 72 + col8) = *(const uint4*)(g + (size_t)row * gp + col8);
}

// ---------------- attention pass 1 (MFMA, 8 waves, 2 s-tiles/block) ----------------
// csum[s] = sum_t exp(S[t][s]); no-max softmax (S small, exp-safe; shift-invariant).
__global__ __launch_bounds__(512) void k_attn_stats_mfma(const u16* __restrict__ Qb, const u16* __restrict__ Kb,
                                                         float* __restrict__ csum) {
  __shared__ u16 Ks[2 * 4608];
  __shared__ u16 Qs[4608];
  int tid = threadIdx.x, wave = tid >> 6, lane = tid & 63;
  int bh = blockIdx.x, b = bh >> 4, h = bh & 15;
  int s0 = blockIdx.y << 7;               // 128 s-cols per block
  int tile = wave >> 2, sw = wave & 3;
  stage_tile512(Kb + ((size_t)(b * TT + s0)) * DD + h * 64, DD, Ks, tid);
  stage_tile512(Kb + ((size_t)(b * TT + s0 + 64)) * DD + h * 64, DD, Ks + 4608, tid);
  int row = tid >> 3, col8 = (tid & 7) << 3;
  const u16* Qg = Qb + ((size_t)(b * TT) + row) * DD + h * 64 + col8;
  uint4 qreg = *(const uint4*)Qg;          // tile t0=0
  __syncthreads();                          // Ks visible
  int fr = lane & 15, g = lane >> 4;
  const u16* Bbase = Ks + tile * 4608 + (sw * 16 + fr) * 72 + g * 8;   // B-frag: K rows (n = s)
  const u16* Abase = Qs + fr * 72 + g * 8;                             // A-frag: Q rows (m = t)
  s16x8 bF0 = *(const s16x8*)(Bbase);
  s16x8 bF1 = *(const s16x8*)(Bbase + 32);
  float sum = 0.f;
  for (int t0 = 0; t0 < TT; t0 += 64) {
    __syncthreads();                        // prior Qs reads done
    *(uint4*)(Qs + row * 72 + col8) = qreg;
    __syncthreads();                        // Qs visible
    if (t0 + 64 < TT) qreg = *(const uint4*)(Qg + (size_t)(t0 + 64) * DD);
    #pragma unroll
    for (int mt = 0; mt < 4; ++mt) {
      f32x4 acc = f32x4{0.f, 0.f, 0.f, 0.f};
      s16x8 a0 = *(const s16x8*)(Abase + mt * 16 * 72);
      s16x8 a1 = *(const s16x8*)(Abase + mt * 16 * 72 + 32);
      acc = __builtin_amdgcn_mfma_f32_16x16x32_bf16(a0, bF0, acc, 0, 0, 0);
      acc = __builtin_amdgcn_mfma_f32_16x16x32_bf16(a1, bF1, acc, 0, 0, 0);
      sum += __expf(acc[0] * 0.125f) + __expf(acc[1] * 0.125f)
           + __expf(acc[2] * 0.125f) + __expf(acc[3] * 0.125f);
    }
  }
  sum += __shfl_xor(sum, 16, 64);
  sum += __shfl_xor(sum, 32, 64);
  if (lane < 16) csum[(size_t)bh * TT + s0 + tile * 64 + sw * 16 + lane] = sum;
}

// ---------------- attention pass 2 (MFMA, 8 waves, 2 t-tiles/block) ----------------
__global__ __launch_bounds__(512) void k_attn_apply_mfma(const u16* __restrict__ Qb, const u16* __restrict__ Kb,
                                                         const u16* __restrict__ Vt,
                                                         const float* __restrict__ csum,
                                                         u16* __restrict__ Op) {
  __shared__ u16 Qs[2 * 4608];
  __shared__ u16 KV2[2 * 4608];    // Ks | VTs; reused by the write epilogue
  __shared__ u16 Pl[8 * 1024];     // per-wave [16 t][64 s] bf16, XOR-swizzled
  __shared__ float rcsL[64];
  u16* Ks = KV2;
  u16* VTs = KV2 + 4608;
  int tid = threadIdx.x, wave = tid >> 6, lane = tid & 63;
  int bh = blockIdx.x, b = bh >> 4, h = bh & 15;
  int t0 = blockIdx.y << 7;               // 128 t-rows per block
  int tile = wave >> 2, tw = wave & 3;
  stage_tile512(Qb + ((size_t)(b * TT + t0)) * DD + h * 64, DD, Qs, tid);
  stage_tile512(Qb + ((size_t)(b * TT + t0 + 64)) * DD + h * 64, DD, Qs + 4608, tid);
  int row = tid >> 3, col8 = (tid & 7) << 3;
  const u16* Kg = Kb + ((size_t)(b * TT) + row) * DD + h * 64 + col8;
  const u16* Vg = Vt + ((size_t)(h * 64) + row) * 4096 + (size_t)b * TT + col8;
  const size_t cbase = (size_t)bh * TT;
  uint4 kreg = *(const uint4*)Kg;          // s0 = 0
  uint4 vreg = *(const uint4*)Vg;
  float rc0 = (tid < 64) ? csum[cbase + tid] : 0.f;
  __syncthreads();                          // Qs visible
  int fr = lane & 15, g = lane >> 4;
  const u16* QbF = Qs + tile * 4608 + (tw * 16 + fr) * 72 + g * 8;   // B-frag (n = t)
  const u16* KaF = Ks + fr * 72 + g * 8;                             // A-frag rows s
  char* Pw = (char*)(Pl + wave * 1024);
  uint swz = ((uint)(lane & 7)) << 4;
  s16x8 qF0 = *(const s16x8*)(QbF);
  s16x8 qF1 = *(const s16x8*)(QbF + 32);
  f32x4 acc_o[4];
  #pragma unroll
  for (int nt = 0; nt < 4; ++nt) acc_o[nt] = f32x4{0.f, 0.f, 0.f, 0.f};

  for (int s0 = 0; s0 < TT; s0 += 64) {
    __syncthreads();                        // prior Ks/VTs reads done
    *(uint4*)(Ks + row * 72 + col8) = kreg;
    *(uint4*)(VTs + row * 72 + col8) = vreg;
    if (tid < 64) rcsL[tid] = 1.f / rc0;
    __syncthreads();                        // visible
    if (s0 + 64 < TT) {                     // issue next-tile loads; hide under compute
      kreg = *(const uint4*)(Kg + (size_t)(s0 + 64) * DD);
      vreg = *(const uint4*)(Vg + s0 + 64);
      if (tid < 64) rc0 = csum[cbase + s0 + 64 + tid];
    }
    // S^T tiles + exp -> P (per-wave)
    #pragma unroll
    for (int mt = 0; mt < 4; ++mt) {
      f32x4 acc = f32x4{0.f, 0.f, 0.f, 0.f};
      s16x8 a0 = *(const s16x8*)(KaF + mt * 16 * 72);
      s16x8 a1 = *(const s16x8*)(KaF + mt * 16 * 72 + 32);
      acc = __builtin_amdgcn_mfma_f32_16x16x32_bf16(a0, qF0, acc, 0, 0, 0);
      acc = __builtin_amdgcn_mfma_f32_16x16x32_bf16(a1, qF1, acc, 0, 0, 0);
      f32x4 rc4 = *(const f32x4*)&rcsL[mt * 16 + g * 4];
      u16 pb[4];
      #pragma unroll
      for (int r = 0; r < 4; ++r)
        pb[r] = f2bf(__expf(acc[r] * 0.125f) * rc4[r]);
      uint woff = (uint)fr * 128 + (uint)(mt * 16 + g * 4) * 2;
      uint2 wv; wv.x = (u32)pb[0] | ((u32)pb[1] << 16); wv.y = (u32)pb[2] | ((u32)pb[3] << 16);
      *(uint2*)(Pw + (woff ^ swz)) = wv;
    }
    // PV: A = P (own wave's tile), B = V^T
    uint rbase = (uint)fr * 128;
    s16x8 pF0 = *(const s16x8*)(Pw + ((rbase + g * 16) ^ swz));
    s16x8 pF1 = *(const s16x8*)(Pw + ((rbase + 64 + g * 16) ^ swz));
    #pragma unroll
    for (int nt = 0; nt < 4; ++nt) {
      s16x8 v0 = *(const s16x8*)(VTs + (nt * 16 + fr) * 72 + g * 8);
      s16x8 v1 = *(const s16x8*)(VTs + (nt * 16 + fr) * 72 + 32 + g * 8);
      acc_o[nt] = __builtin_amdgcn_mfma_f32_16x16x32_bf16(pF0, v0, acc_o[nt], 0, 0, 0);
      acc_o[nt] = __builtin_amdgcn_mfma_f32_16x16x32_bf16(pF1, v1, acc_o[nt], 0, 0, 0);
    }
  }
  // write epilogue: per-wave LDS transpose (reuse KV2) -> coalesced 32B/lane stores
  __syncthreads();                         // all waves done reading Ks/VTs
  u16* Ep = KV2 + wave * 1088;             // per-wave [16][68]
  #pragma unroll
  for (int nt = 0; nt < 4; ++nt)
    #pragma unroll
    for (int r = 0; r < 4; ++r)
      Ep[(g * 4 + r) * 68 + nt * 16 + fr] = f2bf(acc_o[nt][r]);
  {
    int rw = lane >> 2, seg = lane & 3;
    const u16* src = Ep + rw * 68 + seg * 16;
    u16* gd = Op + ((size_t)(b * TT + t0 + tile * 64 + tw * 16 + rw)) * DD + h * 64 + seg * 16;
    #pragma unroll
    for (int i = 0; i < 4; ++i) *(uint2*)(gd + i * 4) = *(const uint2*)(src + i * 4);
  }
}

// ---------------- O = norm(sum of partials + bias + residual), ddof=1 ----------------
__global__ __launch_bounds__(256) void k_add_norm(const float* __restrict__ A, const float* __restrict__ A2,
                                                  const float* __restrict__ A3, const float* __restrict__ A4,
                                                  const float* __restrict__ bias,
                                                  const float* __restrict__ Bv,
                                                  float* __restrict__ O, u16* __restrict__ Ob) {
  int row = blockIdx.x, tid = threadIdx.x;
  size_t base = (size_t)row * DD;
  __shared__ float red[256];
  float v[4]; float s = 0.f;
  #pragma unroll
  for (int i = 0; i < 4; ++i) {
    int c = tid + (i << 8);
    float t = A[base + c] + Bv[base + c];
    if (A2) t += A2[base + c];
    if (A3) t += A3[base + c];
    if (A4) t += A4[base + c];
    if (bias) t += bias[c];
    v[i] = t; s += t;
  }
  red[tid] = s; __syncthreads();
  for (int t = 128; t > 0; t >>= 1) { if (tid < t) red[tid] += red[tid + t]; __syncthreads(); }
  float mean = red[0] * (1.f / 1024.f);
  __syncthreads();
  float vs = 0.f;
  #pragma unroll
  for (int i = 0; i < 4; ++i) { float d = v[i] - mean; vs += d * d; }
  red[tid] = vs; __syncthreads();
  for (int t = 128; t > 0; t >>= 1) { if (tid < t) red[tid] += red[tid + t]; __syncthreads(); }
  float inv = rsqrtf(red[0] * (1.f / 1023.f));
  #pragma unroll
  for (int i = 0; i < 4; ++i) {
    float o = (v[i] - mean) * inv;
    O[base + tid + (i << 8)] = o;
    if (Ob) Ob[base + tid + (i << 8)] = f2bf(o);
  }
}

extern "C" void kernel_launch(void* const* d_in, const int* in_sizes, int n_in,
                              void* d_out, int out_size, void* d_ws, size_t ws_size,
                              hipStream_t stream) {
  (void)in_sizes; (void)n_in; (void)out_size; (void)ws_size;
  const float* x    = (const float*)d_in[0];
  const float* y    = (const float*)d_in[1];
  const float* Wq1  = (const float*)d_in[2];
  const float* Wk1  = (const float*)d_in[3];
  const float* Wv1  = (const float*)d_in[4];
  const float* Wo1  = (const float*)d_in[5];
  const float* Wq2  = (const float*)d_in[6];
  const float* Wk2  = (const float*)d_in[7];
  const float* Wv2  = (const float*)d_in[8];
  const float* Wo2  = (const float*)d_in[9];
  const float* w_in  = (const float*)d_in[10];
  const float* b_in  = (const float*)d_in[11];
  const float* w_out = (const float*)d_in[12];
  const float* b_out = (const float*)d_in[13];

  float* ws = (float*)d_ws;
  size_t off = 0;
  auto allocw = [&](size_t nw) { float* p = ws + off; off += nw; return p; };
  const size_t MR = (size_t)BB * TT;           // 4096
  const size_t ND = MR * DD;                   // 4.19M elems

  u16* Bq   = (u16*)allocw(512 * 1024);        // Bq|Bk|Bv contiguous => fused B (3072 x 1024)
  u16* Bk   = (u16*)allocw(512 * 1024);
  u16* Bv   = (u16*)allocw(512 * 1024);
  u16* Bwo  = (u16*)allocw(512 * 1024);
  u16* Wi   = (u16*)allocw(2 * 1024 * 1024);
  u16* Wob  = (u16*)allocw(2 * 1024 * 1024);
  u16* xbf  = (u16*)allocw(ND / 2);            // xbf|ybf f32 span = FF2 partial 4
  u16* ybf  = (u16*)allocw(ND / 2);
  u16* REG  = (u16*)allocw(ND * 2);
  float* ff2  = allocw(ND);
  float* out1 = allocw(ND);
  float* out2 = allocw(ND);
  float* csum = allocw((size_t)BB * HH * TT);

  u16* Qb = REG;
  u16* Kb = REG + ND;
  u16* Vt = REG + 2 * ND;   // V col-major (1024 x 4096), pitch 4096
  u16* Mb = REG + 3 * ND;   // mhaO; also out1_bf between layers
  u16* ff1b = REG;
  u16* out2bf = ybf;
  float* doutHi = (float*)d_out + ND;  // free until final add_norm writes it
  float* pXY = (float*)xbf;            // xbf|ybf span (dead after KV proj / FF1)

  dim3 blk(256), blkG(512), blkA(512);
  dim3 gConv(4096);
  dim3 gSm(1024);
  dim3 gRw(16, 16);
  dim3 gQKV(24, 32);         // N=3072
  dim3 gKV(16, 32);          // N=2048
  dim3 gP2(8, 32, 2);        // N=1024, split-K=2
  dim3 gF1(32, 32);          // N=4096
  dim3 gFF2(8, 32, 4);       // N=1024, split-K=4 (K=4096)
  dim3 gAttn(BB * HH, TT / 128);
  dim3 gNorm(MR);

  // x passthrough + bf16 convert, one pass
  k_xprep<<<gConv, blk, 0, stream>>>(x, (float*)d_out, xbf, (int)ND);
  k_f2bf<<<gConv, blk, 0, stream>>>(y, ybf, (int)ND);
  k_f2bf<<<gConv, blk, 0, stream>>>(w_in, Wi, FFF * DD);
  k_f2bf<<<gConv, blk, 0, stream>>>(w_out, Wob, DD * FFF);

  // ---- Layer 1: masked self-attention on y ----
  k_softmax_w_bf<<<gSm, blk, 0, stream>>>(Wq1, Bq);
  k_softmax_w_bf<<<gSm, blk, 0, stream>>>(Wk1, Bk);
  k_reorder_w_bf<<<gRw, blk, 0, stream>>>(Wv1, Bv);
  k_transpose_bf<<<gRw, blk, 0, stream>>>(Wo1, Bwo);
  k_mfma_nt<<<gQKV, blkG, 0, stream>>>(ybf, Bq, nullptr, nullptr, nullptr, nullptr, Qb, Kb, Vt, nullptr, 0, 1, 4096, 3072, 1024);
  k_attn_stats_mfma<<<gAttn, blkA, 0, stream>>>(Qb, Kb, csum);
  k_attn_apply_mfma<<<gAttn, blkA, 0, stream>>>(Qb, Kb, Vt, csum, Mb);
  // out-proj split-K=2: partials ff2 + out2 (out2 unused until layer 2)
  k_mfma_nt<<<gP2, blkG, 0, stream>>>(Mb, Bwo, ff2, out2, nullptr, nullptr, nullptr, nullptr, nullptr, nullptr, 0, 0, 4096, 1024, 1024);
  k_add_norm<<<gNorm, blk, 0, stream>>>(ff2, out2, nullptr, nullptr, nullptr, y, out1, Mb /* out1_bf */);

  // ---- Layer 2: cross-attention (Q from out1, K/V from x) ----
  k_reorder_w_bf<<<gRw, blk, 0, stream>>>(Wq2, Bq);
  k_reorder_w_bf<<<gRw, blk, 0, stream>>>(Wk2, Bk);
  k_reorder_w_bf<<<gRw, blk, 0, stream>>>(Wv2, Bv);
  k_transpose_bf<<<gRw, blk, 0, stream>>>(Wo2, Bwo);
  // Q2 proj split-K=2 into dead f32 buffers, then combine -> Qb bf16
  k_mfma_nt<<<gP2, blkG, 0, stream>>>(Mb /* out1_bf */, Bq, ff2, out2, nullptr, nullptr, nullptr, nullptr, nullptr, nullptr, 0, 0, 4096, 1024, 1024);
  k_combine_bf<<<gConv, blk, 0, stream>>>(ff2, out2, Qb, (int)ND);
  k_mfma_nt<<<gKV, blkG, 0, stream>>>(xbf, Bk, nullptr, nullptr, nullptr, nullptr, Kb, nullptr, Vt, nullptr, 0, 2, 4096, 2048, 1024);
  k_attn_stats_mfma<<<gAttn, blkA, 0, stream>>>(Qb, Kb, csum);
  k_attn_apply_mfma<<<gAttn, blkA, 0, stream>>>(Qb, Kb, Vt, csum, Mb);
  // out-proj split-K=2: partials ff2 + doutHi
  k_mfma_nt<<<gP2, blkG, 0, stream>>>(Mb, Bwo, ff2, doutHi, nullptr, nullptr, nullptr, nullptr, nullptr, nullptr, 0, 0, 4096, 1024, 1024);
  k_add_norm<<<gNorm, blk, 0, stream>>>(ff2, doutHi, nullptr, nullptr, nullptr, out1, out2, out2bf);

  // ---- FF ----
  k_mfma_nt<<<gF1, blkG, 0, stream>>>(out2bf, Wi, nullptr, nullptr, nullptr, nullptr, ff1b, nullptr, nullptr, b_in, 1, 0, 4096, 4096, 1024);
  // FF2 split-K=4: partials ff2, doutHi, out1, pXY (all dead here); bias ONCE in final norm
  k_mfma_nt<<<gFF2, blkG, 0, stream>>>(ff1b, Wob, ff2, doutHi, out1, pXY, nullptr, nullptr, nullptr, nullptr, 0, 0, 4096, 1024, 4096);
  k_add_norm<<<gNorm, blk, 0, stream>>>(ff2, doutHi, out1, pXY, b_out, out2, doutHi, nullptr);
}

// Round 11
// 407.240 us; speedup vs baseline: 1.1290x; 1.0645x over previous
//
#include <hip/hip_runtime.h>
#include <hip/hip_bf16.h>

#define BB 4
#define TT 1024
#define DD 1024
#define HH 16
#define DKK 64
#define FFF 4096

typedef unsigned short u16;
typedef unsigned int u32;
typedef __attribute__((ext_vector_type(8))) short s16x8;
typedef __attribute__((ext_vector_type(4))) float f32x4;

static __device__ __forceinline__ float bf2f(u16 s) {
  union { u32 u; float f; } v; v.u = ((u32)s) << 16; return v.f;
}
static __device__ __forceinline__ u16 f2bf(float f) {
  union { float f; u32 u; } v; v.f = f;
  u32 r = v.u + 0x7FFFu + ((v.u >> 16) & 1u);
  return (u16)(r >> 16);
}

#define GLDS(gp, lp) __builtin_amdgcn_global_load_lds( \
    (const __attribute__((address_space(1))) u32*)(gp), \
    (__attribute__((address_space(3))) u32*)(lp), 16, 0, 0)

// XCD-chunked bijective block swizzle (m204 formula), 8-row supertiles.
static __device__ __forceinline__ void swz_block(int& bx, int& by) {
  int gx = gridDim.x, gy = gridDim.y;
  int nwg = gx * gy;
  int orig = by * gx + bx;
  int q = nwg >> 3, r = nwg & 7;
  int xcd = orig & 7, sl = orig >> 3;
  int wgid = (xcd < r ? xcd * (q + 1) : r * (q + 1) + (xcd - r) * q) + sl;
  int g = gx << 3;
  int grp = wgid / g, rem = wgid % g;
  bx = rem >> 3;
  by = (grp << 3) + (rem & 7);
}

// attention swizzle: 512 blocks (8 tiles x 64 bh); XCD j owns bh [8j, 8j+8) x all tiles
// so the 8 blocks sweeping the same Q/K/V stream share one XCD's L2.
static __device__ __forceinline__ void swz_attn(int& tileIdx, int& bh) {
  int orig = blockIdx.y * 8 + blockIdx.x;
  int wgid = ((orig & 7) << 6) | (orig >> 3);
  tileIdx = wgid & 7;
  bh = wgid >> 3;
}

// ---------------- f32 -> bf16 elementwise ----------------
__global__ __launch_bounds__(256) void k_f2bf(const float* __restrict__ s, u16* __restrict__ d, int n) {
  int i = (blockIdx.x * 256 + threadIdx.x) * 4;
  if (i < n) {
    float4 v = *(const float4*)(s + i);
    u16 o[4] = { f2bf(v.x), f2bf(v.y), f2bf(v.z), f2bf(v.w) };
    *(ushort4*)(d + i) = *(ushort4*)o;
  }
}

// ---------------- bf16 a + bf16 b -> bf16 (split-K combine) ----------------
__global__ __launch_bounds__(256) void k_combine_bf(const u16* __restrict__ a, const u16* __restrict__ b,
                                                    u16* __restrict__ d, int n) {
  int i = (blockIdx.x * 256 + threadIdx.x) * 4;
  if (i < n) {
    ushort4 va = *(const ushort4*)(a + i);
    ushort4 vb = *(const ushort4*)(b + i);
    u16 o[4] = { f2bf(bf2f(va.x) + bf2f(vb.x)), f2bf(bf2f(va.y) + bf2f(vb.y)),
                 f2bf(bf2f(va.z) + bf2f(vb.z)), f2bf(bf2f(va.w) + bf2f(vb.w)) };
    *(ushort4*)(d + i) = *(ushort4*)o;
  }
}

// ---------------- x passthrough to d_out + bf16 convert, one read ----------------
__global__ __launch_bounds__(256) void k_xprep(const float* __restrict__ x, float* __restrict__ dout,
                                               u16* __restrict__ xb, int n) {
  int i = (blockIdx.x * 256 + threadIdx.x) * 4;
  if (i < n) {
    float4 v = *(const float4*)(x + i);
    *(float4*)(dout + i) = v;
    u16 o[4] = { f2bf(v.x), f2bf(v.y), f2bf(v.z), f2bf(v.w) };
    *(ushort4*)(xb + i) = *(ushort4*)o;
  }
}

// ---------------- masked softmax over d (axis -2), write bf16 B[n= h*64+k][d] ----------------
__global__ __launch_bounds__(256) void k_softmax_w_bf(const float* __restrict__ W, u16* __restrict__ Bt) {
  int col = blockIdx.x;           // h*64 + k
  int h = col >> 6, k = col & 63;
  int tid = threadIdx.x;
  const float* w = W + ((size_t)h * DD) * DKK + k;
  __shared__ float red[256];
  float m = -1e30f;
  for (int d = k + tid; d < DD; d += 256) m = fmaxf(m, w[(size_t)d * DKK]);
  red[tid] = m; __syncthreads();
  for (int s = 128; s > 0; s >>= 1) { if (tid < s) red[tid] = fmaxf(red[tid], red[tid + s]); __syncthreads(); }
  m = red[0]; __syncthreads();
  float sum = 0.f;
  for (int d = k + tid; d < DD; d += 256) sum += __expf(w[(size_t)d * DKK] - m);
  red[tid] = sum; __syncthreads();
  for (int s = 128; s > 0; s >>= 1) { if (tid < s) red[tid] += red[tid + s]; __syncthreads(); }
  float inv = 1.f / red[0];
  for (int d = tid; d < DD; d += 256) {
    float v = (d >= k) ? __expf(w[(size_t)d * DKK] - m) * inv : 0.f;
    Bt[(size_t)col * DD + d] = f2bf(v);
  }
}

// ---------------- reorder (H, D, DK) -> bf16 B[n=h*64+k][d] ----------------
__global__ __launch_bounds__(256) void k_reorder_w_bf(const float* __restrict__ W, u16* __restrict__ Bt) {
  int d0 = blockIdx.x << 6, h = blockIdx.y;
  __shared__ float t[64][65];
  int tid = threadIdx.x;
  const float* src = W + (size_t)h * DD * DKK + (size_t)d0 * DKK;
  #pragma unroll
  for (int i = 0; i < 16; ++i) {
    int e = i * 256 + tid; int r = e >> 6, c = e & 63;
    t[r][c] = src[(size_t)r * DKK + c];
  }
  __syncthreads();
  #pragma unroll
  for (int i = 0; i < 16; ++i) {
    int e = i * 256 + tid; int c = e >> 6, r = e & 63;
    Bt[((size_t)(h * 64 + c)) * DD + d0 + r] = f2bf(t[r][c]);
  }
}

// ---------------- transpose (K,N) f32 -> bf16 B[n][k] ----------------
__global__ __launch_bounds__(256) void k_transpose_bf(const float* __restrict__ W, u16* __restrict__ Bt) {
  int k0 = blockIdx.x << 6, n0 = blockIdx.y << 6;
  __shared__ float t[64][65];
  int tid = threadIdx.x;
  #pragma unroll
  for (int i = 0; i < 16; ++i) {
    int e = i * 256 + tid; int r = e >> 6, c = e & 63;
    t[r][c] = W[(size_t)(k0 + r) * DD + n0 + c];
  }
  __syncthreads();
  #pragma unroll
  for (int i = 0; i < 16; ++i) {
    int e = i * 256 + tid; int c = e >> 6, r = e & 63;
    Bt[(size_t)(n0 + c) * DD + k0 + r] = f2bf(t[r][c]);
  }
}

// ---------------- MFMA NT GEMM: C = A(MxK) * B(NxK)^T (bf16 in, f32 acc) ----------------
// 128x128 tile, BK=32, 512 threads (8 waves 2x4, wave-tile 64x32), 2-phase dbuf LDS,
// GLDS staging (1 load/thread), XCD swizzle, split-K via blockIdx.z.
// All outputs bf16 via per-wave LDS slab (coalesced). Split-K partials are bf16 (P0..P3).
// mode 0: z-split -> P[z] row-major pitch N; else Cb row-major + bias/relu.
// mode 1 (QKV, N=3072): q=0 -> Cb, q=1 -> Cb2, q=2 -> col-major Ct (pitch M).
// mode 2 (KV,  N=2048): q=0 -> Cb, q=1 -> col-major Ct.
__global__ __launch_bounds__(512) void k_mfma_nt(
    const u16* __restrict__ A, const u16* __restrict__ B,
    u16* __restrict__ P0, u16* __restrict__ P1, u16* __restrict__ P2, u16* __restrict__ P3,
    u16* __restrict__ Cb, u16* __restrict__ Cb2, u16* __restrict__ Ct,
    const float* __restrict__ bias, int relu, int mode, int M, int N, int K) {
  __shared__ u16 SLDS[4 * 4096];   // [0,8192)=A bufs, [8192,16384)=B bufs; epilogue: wave*2048 slabs
  int bx = blockIdx.x, by = blockIdx.y;
  swz_block(bx, by);
  int tid = threadIdx.x, wave = tid >> 6, lane = tid & 63;
  int row0 = by << 7, col0 = bx << 7;
  int wm = (wave >> 2) << 6;        // 0 / 64
  int wn = (wave & 3) << 5;         // 0 / 32 / 64 / 96

  int Ksl = K / gridDim.z;
  int kbase = blockIdx.z * Ksl;
  int kend = kbase + Ksl;

  f32x4 acc[4][2];
  #pragma unroll
  for (int m = 0; m < 4; ++m)
    #pragma unroll
    for (int n = 0; n < 2; ++n) acc[m][n] = f32x4{0.f, 0.f, 0.f, 0.f};

  // staging: [128][32] bf16 = 8 KB per matrix; 512 threads x 16B = exactly one GLDS each.
  int srow = tid >> 2, scol = (tid & 3) << 3;
  const u16* Ag = A + (size_t)(row0 + srow) * K + scol;
  const u16* Bg = B + (size_t)(col0 + srow) * K + scol;
  int wbase = wave << 9;            // u16 offset of this wave's 1KB chunk

  int fr = lane & 15, kg = (lane >> 4) << 3;
  int ardo = (wm + fr) * 32 + kg;
  int brdo = 8192 + (wn + fr) * 32 + kg;

  auto STAGE = [&](int buf, int k0) {
    GLDS(Ag + k0, SLDS + buf * 4096 + wbase);
    GLDS(Bg + k0, SLDS + 8192 + buf * 4096 + wbase);
  };

  STAGE(0, kbase);
  __syncthreads();
  int cur = 0;
  for (int k0 = kbase; k0 < kend; k0 += 32) {
    int nxt = k0 + 32;
    if (nxt < kend) STAGE(cur ^ 1, nxt);   // next-tile loads fly under current MFMA
    const u16* Ard = SLDS + cur * 4096 + ardo;
    const u16* Brd = SLDS + cur * 4096 + brdo;
    s16x8 aF[4], bF[2];
    #pragma unroll
    for (int m = 0; m < 4; ++m) aF[m] = *(const s16x8*)(Ard + m * 16 * 32);
    #pragma unroll
    for (int n = 0; n < 2; ++n) bF[n] = *(const s16x8*)(Brd + n * 16 * 32);
    #pragma unroll
    for (int m = 0; m < 4; ++m)
      #pragma unroll
      for (int n = 0; n < 2; ++n)
        acc[m][n] = __builtin_amdgcn_mfma_f32_16x16x32_bf16(aF[m], bF[n], acc[m][n], 0, 0, 0);
    __syncthreads();                       // drains vmcnt(0): next buf ready, cur free
    cur ^= 1;
  }

  int fq = (lane >> 4) << 2;

  // ---- all outputs bf16 via per-wave [16][40] LDS slab, 4 m-passes -> coalesced stores ----
  u16* dstRow = nullptr; u16* dstCol = nullptr;
  int rowPitch = 1024, colBase = col0 & 1023;
  if (mode == 0) {
    rowPitch = N; colBase = col0;
    if (gridDim.z > 1) {
      int z = blockIdx.z;
      dstRow = (z == 0) ? P0 : ((z == 1) ? P1 : ((z == 2) ? P2 : P3));
    } else dstRow = Cb;
  }
  else if (mode == 1) { int q = col0 >> 10; if (q == 0) dstRow = Cb; else if (q == 1) dstRow = Cb2; else dstCol = Ct; }
  else { int q = col0 >> 10; if (q == 0) dstRow = Cb; else dstCol = Ct; }

  u16* Ep = SLDS + wave * 2048;   // wave-private slab (16*40=640 u16 used)
  #pragma unroll
  for (int m = 0; m < 4; ++m) {
    #pragma unroll
    for (int n = 0; n < 2; ++n) {
      int col = col0 + wn + n * 16 + fr;
      float bs = bias ? bias[col] : 0.f;
      #pragma unroll
      for (int r = 0; r < 4; ++r) {
        float v = acc[m][n][r] + bs;
        if (relu) v = fmaxf(v, 0.f);
        Ep[(fq + r) * 40 + n * 16 + fr] = f2bf(v);
      }
    }
    if (dstRow) {
      int rw = lane >> 2, seg = lane & 3;                  // 16 rows x 4 segs of 8
      const u16* src = Ep + rw * 40 + seg * 8;
      u16* gd = dstRow + (size_t)(row0 + wm + m * 16 + rw) * rowPitch + colBase + wn + seg * 8;
      *(uint4*)gd = *(const uint4*)src;                    // 4 lanes x 16B = 64B line
    } else {
      int c = lane >> 1, half = lane & 1;                  // 32 cols x 2 halves of 8 rows
      u16 tmp[8];
      #pragma unroll
      for (int j = 0; j < 8; ++j) tmp[j] = Ep[(half * 8 + j) * 40 + c];
      u16* gd = dstCol + (size_t)(colBase + wn + c) * 4096 + row0 + wm + m * 16 + half * 8;
      *(uint4*)gd = *(const uint4*)tmp;                    // 2 lanes x 16B = 32B per col
    }
  }
}

// ---------------- stage one 64x64 bf16 tile (512 threads, 1 uint4 each) -> LDS [64][72] ----------------
static __device__ __forceinline__ void stage_tile512(const u16* __restrict__ g, int gp, u16* L, int tid) {
  int row = tid >> 3, col8 = (tid & 7) << 3;
  *(uint4*)(L + row * 72 + col8) = *(const uint4*)(g + (size_t)row * gp + col8);
}

// ---------------- attention pass 1 (MFMA, 8 waves, 2 s-tiles/block) ----------------
// csum[s] = sum_t exp(S[t][s]); no-max softmax (S small, exp-safe; shift-invariant).
__global__ __launch_bounds__(512) void k_attn_stats_mfma(const u16* __restrict__ Qb, const u16* __restrict__ Kb,
                                                         float* __restrict__ csum) {
  __shared__ u16 Ks[2 * 4608];
  __shared__ u16 Qs[4608];
  int tid = threadIdx.x, wave = tid >> 6, lane = tid & 63;
  int tileIdx, bh;
  swz_attn(tileIdx, bh);
  int b = bh >> 4, h = bh & 15;
  int s0 = tileIdx << 7;                  // 128 s-cols per block
  int tile = wave >> 2, sw = wave & 3;
  stage_tile512(Kb + ((size_t)(b * TT + s0)) * DD + h * 64, DD, Ks, tid);
  stage_tile512(Kb + ((size_t)(b * TT + s0 + 64)) * DD + h * 64, DD, Ks + 4608, tid);
  int row = tid >> 3, col8 = (tid & 7) << 3;
  const u16* Qg = Qb + ((size_t)(b * TT) + row) * DD + h * 64 + col8;
  uint4 qreg = *(const uint4*)Qg;          // tile t0=0
  __syncthreads();                          // Ks visible
  int fr = lane & 15, g = lane >> 4;
  const u16* Bbase = Ks + tile * 4608 + (sw * 16 + fr) * 72 + g * 8;   // B-frag: K rows (n = s)
  const u16* Abase = Qs + fr * 72 + g * 8;                             // A-frag: Q rows (m = t)
  s16x8 bF0 = *(const s16x8*)(Bbase);
  s16x8 bF1 = *(const s16x8*)(Bbase + 32);
  float sum = 0.f;
  for (int t0 = 0; t0 < TT; t0 += 64) {
    __syncthreads();                        // prior Qs reads done
    *(uint4*)(Qs + row * 72 + col8) = qreg;
    __syncthreads();                        // Qs visible
    if (t0 + 64 < TT) qreg = *(const uint4*)(Qg + (size_t)(t0 + 64) * DD);
    #pragma unroll
    for (int mt = 0; mt < 4; ++mt) {
      f32x4 acc = f32x4{0.f, 0.f, 0.f, 0.f};
      s16x8 a0 = *(const s16x8*)(Abase + mt * 16 * 72);
      s16x8 a1 = *(const s16x8*)(Abase + mt * 16 * 72 + 32);
      acc = __builtin_amdgcn_mfma_f32_16x16x32_bf16(a0, bF0, acc, 0, 0, 0);
      acc = __builtin_amdgcn_mfma_f32_16x16x32_bf16(a1, bF1, acc, 0, 0, 0);
      sum += __expf(acc[0] * 0.125f) + __expf(acc[1] * 0.125f)
           + __expf(acc[2] * 0.125f) + __expf(acc[3] * 0.125f);
    }
  }
  sum += __shfl_xor(sum, 16, 64);
  sum += __shfl_xor(sum, 32, 64);
  if (lane < 16) csum[(size_t)bh * TT + s0 + tile * 64 + sw * 16 + lane] = sum;
}

// ---------------- attention pass 2 (MFMA, 8 waves, 2 t-tiles/block) ----------------
__global__ __launch_bounds__(512) void k_attn_apply_mfma(const u16* __restrict__ Qb, const u16* __restrict__ Kb,
                                                         const u16* __restrict__ Vt,
                                                         const float* __restrict__ csum,
                                                         u16* __restrict__ Op) {
  __shared__ u16 Qs[2 * 4608];
  __shared__ u16 KV2[2 * 4608];    // Ks | VTs; reused by the write epilogue
  __shared__ u16 Pl[8 * 1024];     // per-wave [16 t][64 s] bf16, XOR-swizzled
  __shared__ float rcsL[64];
  u16* Ks = KV2;
  u16* VTs = KV2 + 4608;
  int tid = threadIdx.x, wave = tid >> 6, lane = tid & 63;
  int tileIdx, bh;
  swz_attn(tileIdx, bh);
  int b = bh >> 4, h = bh & 15;
  int t0 = tileIdx << 7;                  // 128 t-rows per block
  int tile = wave >> 2, tw = wave & 3;
  stage_tile512(Qb + ((size_t)(b * TT + t0)) * DD + h * 64, DD, Qs, tid);
  stage_tile512(Qb + ((size_t)(b * TT + t0 + 64)) * DD + h * 64, DD, Qs + 4608, tid);
  int row = tid >> 3, col8 = (tid & 7) << 3;
  const u16* Kg = Kb + ((size_t)(b * TT) + row) * DD + h * 64 + col8;
  const u16* Vg = Vt + ((size_t)(h * 64) + row) * 4096 + (size_t)b * TT + col8;
  const size_t cbase = (size_t)bh * TT;
  uint4 kreg = *(const uint4*)Kg;          // s0 = 0
  uint4 vreg = *(const uint4*)Vg;
  float rc0 = (tid < 64) ? csum[cbase + tid] : 0.f;
  __syncthreads();                          // Qs visible
  int fr = lane & 15, g = lane >> 4;
  const u16* QbF = Qs + tile * 4608 + (tw * 16 + fr) * 72 + g * 8;   // B-frag (n = t)
  const u16* KaF = Ks + fr * 72 + g * 8;                             // A-frag rows s
  char* Pw = (char*)(Pl + wave * 1024);
  uint swz = ((uint)(lane & 7)) << 4;
  s16x8 qF0 = *(const s16x8*)(QbF);
  s16x8 qF1 = *(const s16x8*)(QbF + 32);
  f32x4 acc_o[4];
  #pragma unroll
  for (int nt = 0; nt < 4; ++nt) acc_o[nt] = f32x4{0.f, 0.f, 0.f, 0.f};

  for (int s0 = 0; s0 < TT; s0 += 64) {
    __syncthreads();                        // prior Ks/VTs reads done
    *(uint4*)(Ks + row * 72 + col8) = kreg;
    *(uint4*)(VTs + row * 72 + col8) = vreg;
    if (tid < 64) rcsL[tid] = 1.f / rc0;
    __syncthreads();                        // visible
    if (s0 + 64 < TT) {                     // issue next-tile loads; hide under compute
      kreg = *(const uint4*)(Kg + (size_t)(s0 + 64) * DD);
      vreg = *(const uint4*)(Vg + s0 + 64);
      if (tid < 64) rc0 = csum[cbase + s0 + 64 + tid];
    }
    // S^T tiles + exp -> P (per-wave)
    #pragma unroll
    for (int mt = 0; mt < 4; ++mt) {
      f32x4 acc = f32x4{0.f, 0.f, 0.f, 0.f};
      s16x8 a0 = *(const s16x8*)(KaF + mt * 16 * 72);
      s16x8 a1 = *(const s16x8*)(KaF + mt * 16 * 72 + 32);
      acc = __builtin_amdgcn_mfma_f32_16x16x32_bf16(a0, qF0, acc, 0, 0, 0);
      acc = __builtin_amdgcn_mfma_f32_16x16x32_bf16(a1, qF1, acc, 0, 0, 0);
      f32x4 rc4 = *(const f32x4*)&rcsL[mt * 16 + g * 4];
      u16 pb[4];
      #pragma unroll
      for (int r = 0; r < 4; ++r)
        pb[r] = f2bf(__expf(acc[r] * 0.125f) * rc4[r]);
      uint woff = (uint)fr * 128 + (uint)(mt * 16 + g * 4) * 2;
      uint2 wv; wv.x = (u32)pb[0] | ((u32)pb[1] << 16); wv.y = (u32)pb[2] | ((u32)pb[3] << 16);
      *(uint2*)(Pw + (woff ^ swz)) = wv;
    }
    // PV: A = P (own wave's tile), B = V^T
    uint rbase = (uint)fr * 128;
    s16x8 pF0 = *(const s16x8*)(Pw + ((rbase + g * 16) ^ swz));
    s16x8 pF1 = *(const s16x8*)(Pw + ((rbase + 64 + g * 16) ^ swz));
    #pragma unroll
    for (int nt = 0; nt < 4; ++nt) {
      s16x8 v0 = *(const s16x8*)(VTs + (nt * 16 + fr) * 72 + g * 8);
      s16x8 v1 = *(const s16x8*)(VTs + (nt * 16 + fr) * 72 + 32 + g * 8);
      acc_o[nt] = __builtin_amdgcn_mfma_f32_16x16x32_bf16(pF0, v0, acc_o[nt], 0, 0, 0);
      acc_o[nt] = __builtin_amdgcn_mfma_f32_16x16x32_bf16(pF1, v1, acc_o[nt], 0, 0, 0);
    }
  }
  // write epilogue: per-wave LDS transpose (reuse KV2) -> coalesced 32B/lane stores
  __syncthreads();                         // all waves done reading Ks/VTs
  u16* Ep = KV2 + wave * 1088;             // per-wave [16][68]
  #pragma unroll
  for (int nt = 0; nt < 4; ++nt)
    #pragma unroll
    for (int r = 0; r < 4; ++r)
      Ep[(g * 4 + r) * 68 + nt * 16 + fr] = f2bf(acc_o[nt][r]);
  {
    int rw = lane >> 2, seg = lane & 3;
    const u16* src = Ep + rw * 68 + seg * 16;
    u16* gd = Op + ((size_t)(b * TT + t0 + tile * 64 + tw * 16 + rw)) * DD + h * 64 + seg * 16;
    #pragma unroll
    for (int i = 0; i < 4; ++i) *(uint2*)(gd + i * 4) = *(const uint2*)(src + i * 4);
  }
}

// ---------------- O = norm(sum of bf16 partials + bias + residual), ddof=1 ----------------
__global__ __launch_bounds__(256) void k_add_norm(const u16* __restrict__ A, const u16* __restrict__ A2,
                                                  const u16* __restrict__ A3, const u16* __restrict__ A4,
                                                  const float* __restrict__ bias,
                                                  const float* __restrict__ Bv,
                                                  float* __restrict__ O, u16* __restrict__ Ob) {
  int row = blockIdx.x, tid = threadIdx.x;
  size_t base = (size_t)row * DD;
  int c0 = tid * 4;
  __shared__ float red[256];
  float v[4];
  {
    ushort4 a = *(const ushort4*)(A + base + c0);
    float4 bv = *(const float4*)(Bv + base + c0);
    v[0] = bf2f(a.x) + bv.x; v[1] = bf2f(a.y) + bv.y;
    v[2] = bf2f(a.z) + bv.z; v[3] = bf2f(a.w) + bv.w;
  }
  if (A2) {
    ushort4 a = *(const ushort4*)(A2 + base + c0);
    v[0] += bf2f(a.x); v[1] += bf2f(a.y); v[2] += bf2f(a.z); v[3] += bf2f(a.w);
  }
  if (A3) {
    ushort4 a = *(const ushort4*)(A3 + base + c0);
    v[0] += bf2f(a.x); v[1] += bf2f(a.y); v[2] += bf2f(a.z); v[3] += bf2f(a.w);
  }
  if (A4) {
    ushort4 a = *(const ushort4*)(A4 + base + c0);
    v[0] += bf2f(a.x); v[1] += bf2f(a.y); v[2] += bf2f(a.z); v[3] += bf2f(a.w);
  }
  if (bias) {
    float4 bs = *(const float4*)(bias + c0);
    v[0] += bs.x; v[1] += bs.y; v[2] += bs.z; v[3] += bs.w;
  }
  float s = v[0] + v[1] + v[2] + v[3];
  red[tid] = s; __syncthreads();
  for (int t = 128; t > 0; t >>= 1) { if (tid < t) red[tid] += red[tid + t]; __syncthreads(); }
  float mean = red[0] * (1.f / 1024.f);
  __syncthreads();
  float vs = 0.f;
  #pragma unroll
  for (int i = 0; i < 4; ++i) { float d = v[i] - mean; vs += d * d; }
  red[tid] = vs; __syncthreads();
  for (int t = 128; t > 0; t >>= 1) { if (tid < t) red[tid] += red[tid + t]; __syncthreads(); }
  float inv = rsqrtf(red[0] * (1.f / 1023.f));
  float o[4];
  #pragma unroll
  for (int i = 0; i < 4; ++i) o[i] = (v[i] - mean) * inv;
  *(float4*)(O + base + c0) = *(float4*)o;
  if (Ob) {
    u16 ob[4] = { f2bf(o[0]), f2bf(o[1]), f2bf(o[2]), f2bf(o[3]) };
    *(ushort4*)(Ob + base + c0) = *(ushort4*)ob;
  }
}

extern "C" void kernel_launch(void* const* d_in, const int* in_sizes, int n_in,
                              void* d_out, int out_size, void* d_ws, size_t ws_size,
                              hipStream_t stream) {
  (void)in_sizes; (void)n_in; (void)out_size; (void)ws_size;
  const float* x    = (const float*)d_in[0];
  const float* y    = (const float*)d_in[1];
  const float* Wq1  = (const float*)d_in[2];
  const float* Wk1  = (const float*)d_in[3];
  const float* Wv1  = (const float*)d_in[4];
  const float* Wo1  = (const float*)d_in[5];
  const float* Wq2  = (const float*)d_in[6];
  const float* Wk2  = (const float*)d_in[7];
  const float* Wv2  = (const float*)d_in[8];
  const float* Wo2  = (const float*)d_in[9];
  const float* w_in  = (const float*)d_in[10];
  const float* b_in  = (const float*)d_in[11];
  const float* w_out = (const float*)d_in[12];
  const float* b_out = (const float*)d_in[13];

  float* ws = (float*)d_ws;
  size_t off = 0;
  auto allocw = [&](size_t nw) { float* p = ws + off; off += nw; return p; };
  const size_t MR = (size_t)BB * TT;           // 4096
  const size_t ND = MR * DD;                   // 4.19M elems

  u16* Bq   = (u16*)allocw(512 * 1024);        // Bq|Bk|Bv contiguous => fused B (3072 x 1024)
  u16* Bk   = (u16*)allocw(512 * 1024);
  u16* Bv   = (u16*)allocw(512 * 1024);
  u16* Bwo  = (u16*)allocw(512 * 1024);
  u16* Wi   = (u16*)allocw(2 * 1024 * 1024);
  u16* Wob  = (u16*)allocw(2 * 1024 * 1024);
  u16* xbf  = (u16*)allocw(ND / 2);
  u16* ybf  = (u16*)allocw(ND / 2);
  u16* REG  = (u16*)allocw(ND * 2);
  float* ff2  = allocw(ND);                    // partial slabs p0|p1 (bf16)
  float* out1 = allocw(ND);                    // residual; later partial slabs p2|p3
  float* out2 = allocw(ND);
  float* csum = allocw((size_t)BB * HH * TT);

  u16* Qb = REG;
  u16* Kb = REG + ND;
  u16* Vt = REG + 2 * ND;   // V col-major (1024 x 4096), pitch 4096
  u16* Mb = REG + 3 * ND;   // mhaO; also out1_bf between layers
  u16* ff1b = REG;
  u16* out2bf = ybf;
  float* doutHi = (float*)d_out + ND;
  u16* p0 = (u16*)ff2;          // bf16 partial slabs
  u16* p1 = (u16*)ff2 + ND;
  u16* p2 = (u16*)out1;         // only after out1 is dead (post-L2-norm)
  u16* p3 = (u16*)out1 + ND;

  dim3 blk(256), blkG(512), blkA(512);
  dim3 gConv(4096);
  dim3 gSm(1024);
  dim3 gRw(16, 16);
  dim3 gQKV(24, 32);         // N=3072
  dim3 gKV(16, 32);          // N=2048
  dim3 gP2(8, 32, 2);        // N=1024, split-K=2
  dim3 gF1(32, 32);          // N=4096
  dim3 gFF2(8, 32, 4);       // N=1024, split-K=4 (K=4096)
  dim3 gAttn(8, 64);         // (tiles, bh) + swz_attn -> per-XCD bh grouping
  dim3 gNorm(MR);

  // x passthrough + bf16 convert, one pass
  k_xprep<<<gConv, blk, 0, stream>>>(x, (float*)d_out, xbf, (int)ND);
  k_f2bf<<<gConv, blk, 0, stream>>>(y, ybf, (int)ND);
  k_f2bf<<<gConv, blk, 0, stream>>>(w_in, Wi, FFF * DD);
  k_f2bf<<<gConv, blk, 0, stream>>>(w_out, Wob, DD * FFF);

  // ---- Layer 1: masked self-attention on y ----
  k_softmax_w_bf<<<gSm, blk, 0, stream>>>(Wq1, Bq);
  k_softmax_w_bf<<<gSm, blk, 0, stream>>>(Wk1, Bk);
  k_reorder_w_bf<<<gRw, blk, 0, stream>>>(Wv1, Bv);
  k_transpose_bf<<<gRw, blk, 0, stream>>>(Wo1, Bwo);
  k_mfma_nt<<<gQKV, blkG, 0, stream>>>(ybf, Bq, nullptr, nullptr, nullptr, nullptr, Qb, Kb, Vt, nullptr, 0, 1, 4096, 3072, 1024);
  k_attn_stats_mfma<<<gAttn, blkA, 0, stream>>>(Qb, Kb, csum);
  k_attn_apply_mfma<<<gAttn, blkA, 0, stream>>>(Qb, Kb, Vt, csum, Mb);
  // out-proj split-K=2: bf16 partials p0,p1
  k_mfma_nt<<<gP2, blkG, 0, stream>>>(Mb, Bwo, p0, p1, nullptr, nullptr, nullptr, nullptr, nullptr, nullptr, 0, 0, 4096, 1024, 1024);
  k_add_norm<<<gNorm, blk, 0, stream>>>(p0, p1, nullptr, nullptr, nullptr, y, out1, Mb /* out1_bf */);

  // ---- Layer 2: cross-attention (Q from out1, K/V from x) ----
  k_reorder_w_bf<<<gRw, blk, 0, stream>>>(Wq2, Bq);
  k_reorder_w_bf<<<gRw, blk, 0, stream>>>(Wk2, Bk);
  k_reorder_w_bf<<<gRw, blk, 0, stream>>>(Wv2, Bv);
  k_transpose_bf<<<gRw, blk, 0, stream>>>(Wo2, Bwo);
  // Q2 proj split-K=2 -> bf16 partials, then combine -> Qb bf16
  k_mfma_nt<<<gP2, blkG, 0, stream>>>(Mb /* out1_bf */, Bq, p0, p1, nullptr, nullptr, nullptr, nullptr, nullptr, nullptr, 0, 0, 4096, 1024, 1024);
  k_combine_bf<<<gConv, blk, 0, stream>>>(p0, p1, Qb, (int)ND);
  k_mfma_nt<<<gKV, blkG, 0, stream>>>(xbf, Bk, nullptr, nullptr, nullptr, nullptr, Kb, nullptr, Vt, nullptr, 0, 2, 4096, 2048, 1024);
  k_attn_stats_mfma<<<gAttn, blkA, 0, stream>>>(Qb, Kb, csum);
  k_attn_apply_mfma<<<gAttn, blkA, 0, stream>>>(Qb, Kb, Vt, csum, Mb);
  // out-proj split-K=2: bf16 partials
  k_mfma_nt<<<gP2, blkG, 0, stream>>>(Mb, Bwo, p0, p1, nullptr, nullptr, nullptr, nullptr, nullptr, nullptr, 0, 0, 4096, 1024, 1024);
  k_add_norm<<<gNorm, blk, 0, stream>>>(p0, p1, nullptr, nullptr, nullptr, out1, out2, out2bf);

  // ---- FF ----  (out1 dead from here; p2/p3 alias it)
  k_mfma_nt<<<gF1, blkG, 0, stream>>>(out2bf, Wi, nullptr, nullptr, nullptr, nullptr, ff1b, nullptr, nullptr, b_in, 1, 0, 4096, 4096, 1024);
  // FF2 split-K=4: bf16 partials p0..p3; bias ONCE in final norm
  k_mfma_nt<<<gFF2, blkG, 0, stream>>>(ff1b, Wob, p0, p1, p2, p3, nullptr, nullptr, nullptr, nullptr, 0, 0, 4096, 1024, 4096);
  k_add_norm<<<gNorm, blk, 0, stream>>>(p0, p1, p2, p3, b_out, out2, doutHi, nullptr);
}

// Round 12
// 403.642 us; speedup vs baseline: 1.1391x; 1.0089x over previous
//
#include <hip/hip_runtime.h>
#include <hip/hip_bf16.h>

#define BB 4
#define TT 1024
#define DD 1024
#define HH 16
#define DKK 64
#define FFF 4096

typedef unsigned short u16;
typedef unsigned int u32;
typedef __attribute__((ext_vector_type(8))) short s16x8;
typedef __attribute__((ext_vector_type(4))) float f32x4;

static __device__ __forceinline__ float bf2f(u16 s) {
  union { u32 u; float f; } v; v.u = ((u32)s) << 16; return v.f;
}
static __device__ __forceinline__ u16 f2bf(float f) {
  union { float f; u32 u; } v; v.f = f;
  u32 r = v.u + 0x7FFFu + ((v.u >> 16) & 1u);
  return (u16)(r >> 16);
}

#define GLDS(gp, lp) __builtin_amdgcn_global_load_lds( \
    (const __attribute__((address_space(1))) u32*)(gp), \
    (__attribute__((address_space(3))) u32*)(lp), 16, 0, 0)

// XCD-chunked bijective block swizzle (m204 formula), 8-row supertiles.
static __device__ __forceinline__ void swz_block(int& bx, int& by) {
  int gx = gridDim.x, gy = gridDim.y;
  int nwg = gx * gy;
  int orig = by * gx + bx;
  int q = nwg >> 3, r = nwg & 7;
  int xcd = orig & 7, sl = orig >> 3;
  int wgid = (xcd < r ? xcd * (q + 1) : r * (q + 1) + (xcd - r) * q) + sl;
  int g = gx << 3;
  int grp = wgid / g, rem = wgid % g;
  bx = rem >> 3;
  by = (grp << 3) + (rem & 7);
}

// attention swizzle: 512 blocks (8 tiles x 64 bh); XCD j owns bh [8j, 8j+8) x all tiles.
static __device__ __forceinline__ void swz_attn(int& tileIdx, int& bh) {
  int orig = blockIdx.y * 8 + blockIdx.x;
  int wgid = ((orig & 7) << 6) | (orig >> 3);
  tileIdx = wgid & 7;
  bh = wgid >> 3;
}

// ---------------- f32 -> bf16 elementwise ----------------
__global__ __launch_bounds__(256) void k_f2bf(const float* __restrict__ s, u16* __restrict__ d, int n) {
  int i = (blockIdx.x * 256 + threadIdx.x) * 4;
  if (i < n) {
    float4 v = *(const float4*)(s + i);
    u16 o[4] = { f2bf(v.x), f2bf(v.y), f2bf(v.z), f2bf(v.w) };
    *(ushort4*)(d + i) = *(ushort4*)o;
  }
}

// ---------------- bf16 a + bf16 b -> bf16 (split-K combine) ----------------
__global__ __launch_bounds__(256) void k_combine_bf(const u16* __restrict__ a, const u16* __restrict__ b,
                                                    u16* __restrict__ d, int n) {
  int i = (blockIdx.x * 256 + threadIdx.x) * 4;
  if (i < n) {
    ushort4 va = *(const ushort4*)(a + i);
    ushort4 vb = *(const ushort4*)(b + i);
    u16 o[4] = { f2bf(bf2f(va.x) + bf2f(vb.x)), f2bf(bf2f(va.y) + bf2f(vb.y)),
                 f2bf(bf2f(va.z) + bf2f(vb.z)), f2bf(bf2f(va.w) + bf2f(vb.w)) };
    *(ushort4*)(d + i) = *(ushort4*)o;
  }
}

// ---------------- x passthrough to d_out + bf16 convert, one read ----------------
__global__ __launch_bounds__(256) void k_xprep(const float* __restrict__ x, float* __restrict__ dout,
                                               u16* __restrict__ xb, int n) {
  int i = (blockIdx.x * 256 + threadIdx.x) * 4;
  if (i < n) {
    float4 v = *(const float4*)(x + i);
    *(float4*)(dout + i) = v;
    u16 o[4] = { f2bf(v.x), f2bf(v.y), f2bf(v.z), f2bf(v.w) };
    *(ushort4*)(xb + i) = *(ushort4*)o;
  }
}

// ---------------- masked softmax over d (axis -2), write bf16 B[n= h*64+k][d] ----------------
__global__ __launch_bounds__(256) void k_softmax_w_bf(const float* __restrict__ W, u16* __restrict__ Bt) {
  int col = blockIdx.x;           // h*64 + k
  int h = col >> 6, k = col & 63;
  int tid = threadIdx.x;
  const float* w = W + ((size_t)h * DD) * DKK + k;
  __shared__ float red[256];
  float m = -1e30f;
  for (int d = k + tid; d < DD; d += 256) m = fmaxf(m, w[(size_t)d * DKK]);
  red[tid] = m; __syncthreads();
  for (int s = 128; s > 0; s >>= 1) { if (tid < s) red[tid] = fmaxf(red[tid], red[tid + s]); __syncthreads(); }
  m = red[0]; __syncthreads();
  float sum = 0.f;
  for (int d = k + tid; d < DD; d += 256) sum += __expf(w[(size_t)d * DKK] - m);
  red[tid] = sum; __syncthreads();
  for (int s = 128; s > 0; s >>= 1) { if (tid < s) red[tid] += red[tid + s]; __syncthreads(); }
  float inv = 1.f / red[0];
  for (int d = tid; d < DD; d += 256) {
    float v = (d >= k) ? __expf(w[(size_t)d * DKK] - m) * inv : 0.f;
    Bt[(size_t)col * DD + d] = f2bf(v);
  }
}

// ---------------- reorder (H, D, DK) -> bf16 B[n=h*64+k][d] ----------------
__global__ __launch_bounds__(256) void k_reorder_w_bf(const float* __restrict__ W, u16* __restrict__ Bt) {
  int d0 = blockIdx.x << 6, h = blockIdx.y;
  __shared__ float t[64][65];
  int tid = threadIdx.x;
  const float* src = W + (size_t)h * DD * DKK + (size_t)d0 * DKK;
  #pragma unroll
  for (int i = 0; i < 16; ++i) {
    int e = i * 256 + tid; int r = e >> 6, c = e & 63;
    t[r][c] = src[(size_t)r * DKK + c];
  }
  __syncthreads();
  #pragma unroll
  for (int i = 0; i < 16; ++i) {
    int e = i * 256 + tid; int c = e >> 6, r = e & 63;
    Bt[((size_t)(h * 64 + c)) * DD + d0 + r] = f2bf(t[r][c]);
  }
}

// ---------------- transpose (K,N) f32 -> bf16 B[n][k] ----------------
__global__ __launch_bounds__(256) void k_transpose_bf(const float* __restrict__ W, u16* __restrict__ Bt) {
  int k0 = blockIdx.x << 6, n0 = blockIdx.y << 6;
  __shared__ float t[64][65];
  int tid = threadIdx.x;
  #pragma unroll
  for (int i = 0; i < 16; ++i) {
    int e = i * 256 + tid; int r = e >> 6, c = e & 63;
    t[r][c] = W[(size_t)(k0 + r) * DD + n0 + c];
  }
  __syncthreads();
  #pragma unroll
  for (int i = 0; i < 16; ++i) {
    int e = i * 256 + tid; int c = e >> 6, r = e & 63;
    Bt[(size_t)(n0 + c) * DD + k0 + r] = f2bf(t[r][c]);
  }
}

// ---------------- MFMA NT GEMM: C = A(MxK) * B(NxK)^T (bf16 in, f32 acc) ----------------
// 128x128 tile, BK=32, 512 threads (8 waves 2x4, wave-tile 64x32), XCD swizzle,
// split-K via blockIdx.z, bf16 outputs via per-wave LDS slab.
// T4-lite pipeline: 3-buffer rotation, issue-ahead-2, ONE raw s_barrier +
// counted s_waitcnt vmcnt(2) per K-step (loads stay in flight across barriers).
__global__ __launch_bounds__(512) void k_mfma_nt(
    const u16* __restrict__ A, const u16* __restrict__ B,
    u16* __restrict__ P0, u16* __restrict__ P1, u16* __restrict__ P2, u16* __restrict__ P3,
    u16* __restrict__ Cb, u16* __restrict__ Cb2, u16* __restrict__ Ct,
    const float* __restrict__ bias, int relu, int mode, int M, int N, int K) {
  __shared__ u16 SLDS[24576];   // A bufs [0,12288), B bufs [12288,24576); epilogue reuses [0,16384)
  int bx = blockIdx.x, by = blockIdx.y;
  swz_block(bx, by);
  int tid = threadIdx.x, wave = tid >> 6, lane = tid & 63;
  int row0 = by << 7, col0 = bx << 7;
  int wm = (wave >> 2) << 6;        // 0 / 64
  int wn = (wave & 3) << 5;         // 0 / 32 / 64 / 96

  int Ksl = K / gridDim.z;
  int kbase = blockIdx.z * Ksl;
  int nt = Ksl >> 5;                // K-steps of 32

  f32x4 acc[4][2];
  #pragma unroll
  for (int m = 0; m < 4; ++m)
    #pragma unroll
    for (int n = 0; n < 2; ++n) acc[m][n] = f32x4{0.f, 0.f, 0.f, 0.f};

  // staging: [128][32] bf16 = 8 KB per matrix; 512 threads x 16B = exactly one GLDS each.
  int srow = tid >> 2, scol = (tid & 3) << 3;
  const u16* Ag = A + (size_t)(row0 + srow) * K + scol;
  const u16* Bg = B + (size_t)(col0 + srow) * K + scol;
  int wbase = wave << 9;            // u16 offset of this wave's 1KB chunk

  int fr = lane & 15, kg = (lane >> 4) << 3;
  int ardo = (wm + fr) * 32 + kg;
  int brdo = 12288 + (wn + fr) * 32 + kg;

  auto STAGE = [&](int buf, int k0) {
    GLDS(Ag + k0, SLDS + buf * 4096 + wbase);
    GLDS(Bg + k0, SLDS + 12288 + buf * 4096 + wbase);
  };

  STAGE(0, kbase);
  if (nt > 1) STAGE(1, kbase + 32);
  int bufT = 0;
  for (int t = 0; t < nt; ++t) {
    // wait for buf[t]'s own loads; STAGE(t+1) (2 loads) may stay in flight
    if (t + 1 < nt) asm volatile("s_waitcnt vmcnt(2)" ::: "memory");
    else            asm volatile("s_waitcnt vmcnt(0)" ::: "memory");
    __builtin_amdgcn_s_barrier();     // all threads' buf[t] chunks landed
    asm volatile("" ::: "memory");
    if (t + 2 < nt) {
      int b2 = bufT + 2; if (b2 >= 3) b2 -= 3;
      STAGE(b2, kbase + (t + 2) * 32);  // overwrites buf[t-1]: safe, reads done pre-barrier
    }
    const u16* Ard = SLDS + bufT * 4096 + ardo;
    const u16* Brd = SLDS + bufT * 4096 + brdo;
    s16x8 aF[4], bF[2];
    #pragma unroll
    for (int m = 0; m < 4; ++m) aF[m] = *(const s16x8*)(Ard + m * 16 * 32);
    #pragma unroll
    for (int n = 0; n < 2; ++n) bF[n] = *(const s16x8*)(Brd + n * 16 * 32);
    #pragma unroll
    for (int m = 0; m < 4; ++m)
      #pragma unroll
      for (int n = 0; n < 2; ++n)
        acc[m][n] = __builtin_amdgcn_mfma_f32_16x16x32_bf16(aF[m], bF[n], acc[m][n], 0, 0, 0);
    ++bufT; if (bufT == 3) bufT = 0;
  }
  __syncthreads();                    // epilogue slab aliases staging bufs: wait all reads done

  int fq = (lane >> 4) << 2;

  // ---- all outputs bf16 via per-wave [16][40] LDS slab, 4 m-passes -> coalesced stores ----
  u16* dstRow = nullptr; u16* dstCol = nullptr;
  int rowPitch = 1024, colBase = col0 & 1023;
  if (mode == 0) {
    rowPitch = N; colBase = col0;
    if (gridDim.z > 1) {
      int z = blockIdx.z;
      dstRow = (z == 0) ? P0 : ((z == 1) ? P1 : ((z == 2) ? P2 : P3));
    } else dstRow = Cb;
  }
  else if (mode == 1) { int q = col0 >> 10; if (q == 0) dstRow = Cb; else if (q == 1) dstRow = Cb2; else dstCol = Ct; }
  else { int q = col0 >> 10; if (q == 0) dstRow = Cb; else dstCol = Ct; }

  u16* Ep = SLDS + wave * 2048;   // wave-private slab (16*40=640 u16 used)
  #pragma unroll
  for (int m = 0; m < 4; ++m) {
    #pragma unroll
    for (int n = 0; n < 2; ++n) {
      int col = col0 + wn + n * 16 + fr;
      float bs = bias ? bias[col] : 0.f;
      #pragma unroll
      for (int r = 0; r < 4; ++r) {
        float v = acc[m][n][r] + bs;
        if (relu) v = fmaxf(v, 0.f);
        Ep[(fq + r) * 40 + n * 16 + fr] = f2bf(v);
      }
    }
    if (dstRow) {
      int rw = lane >> 2, seg = lane & 3;                  // 16 rows x 4 segs of 8
      const u16* src = Ep + rw * 40 + seg * 8;
      u16* gd = dstRow + (size_t)(row0 + wm + m * 16 + rw) * rowPitch + colBase + wn + seg * 8;
      *(uint4*)gd = *(const uint4*)src;                    // 4 lanes x 16B = 64B line
    } else {
      int c = lane >> 1, half = lane & 1;                  // 32 cols x 2 halves of 8 rows
      u16 tmp[8];
      #pragma unroll
      for (int j = 0; j < 8; ++j) tmp[j] = Ep[(half * 8 + j) * 40 + c];
      u16* gd = dstCol + (size_t)(colBase + wn + c) * 4096 + row0 + wm + m * 16 + half * 8;
      *(uint4*)gd = *(const uint4*)tmp;                    // 2 lanes x 16B = 32B per col
    }
  }
}

// ---------------- stage one 64x64 bf16 tile (512 threads, 1 uint4 each) -> LDS [64][72] ----------------
static __device__ __forceinline__ void stage_tile512(const u16* __restrict__ g, int gp, u16* L, int tid) {
  int row = tid >> 3, col8 = (tid & 7) << 3;
  *(uint4*)(L + row * 72 + col8) = *(const uint4*)(g + (size_t)row * gp + col8);
}

// ---------------- attention pass 1 (MFMA, 8 waves, 2 s-tiles/block) ----------------
// csum[s] = sum_t exp(S[t][s]); no-max softmax (S small, exp-safe; shift-invariant).
__global__ __launch_bounds__(512) void k_attn_stats_mfma(const u16* __restrict__ Qb, const u16* __restrict__ Kb,
                                                         float* __restrict__ csum) {
  __shared__ u16 Ks[2 * 4608];
  __shared__ u16 Qs[4608];
  int tid = threadIdx.x, wave = tid >> 6, lane = tid & 63;
  int tileIdx, bh;
  swz_attn(tileIdx, bh);
  int b = bh >> 4, h = bh & 15;
  int s0 = tileIdx << 7;                  // 128 s-cols per block
  int tile = wave >> 2, sw = wave & 3;
  stage_tile512(Kb + ((size_t)(b * TT + s0)) * DD + h * 64, DD, Ks, tid);
  stage_tile512(Kb + ((size_t)(b * TT + s0 + 64)) * DD + h * 64, DD, Ks + 4608, tid);
  int row = tid >> 3, col8 = (tid & 7) << 3;
  const u16* Qg = Qb + ((size_t)(b * TT) + row) * DD + h * 64 + col8;
  uint4 qreg = *(const uint4*)Qg;          // tile t0=0
  __syncthreads();                          // Ks visible
  int fr = lane & 15, g = lane >> 4;
  const u16* Bbase = Ks + tile * 4608 + (sw * 16 + fr) * 72 + g * 8;   // B-frag: K rows (n = s)
  const u16* Abase = Qs + fr * 72 + g * 8;                             // A-frag: Q rows (m = t)
  s16x8 bF0 = *(const s16x8*)(Bbase);
  s16x8 bF1 = *(const s16x8*)(Bbase + 32);
  float sum = 0.f;
  for (int t0 = 0; t0 < TT; t0 += 64) {
    __syncthreads();                        // prior Qs reads done
    *(uint4*)(Qs + row * 72 + col8) = qreg;
    __syncthreads();                        // Qs visible
    if (t0 + 64 < TT) qreg = *(const uint4*)(Qg + (size_t)(t0 + 64) * DD);
    #pragma unroll
    for (int mt = 0; mt < 4; ++mt) {
      f32x4 acc = f32x4{0.f, 0.f, 0.f, 0.f};
      s16x8 a0 = *(const s16x8*)(Abase + mt * 16 * 72);
      s16x8 a1 = *(const s16x8*)(Abase + mt * 16 * 72 + 32);
      acc = __builtin_amdgcn_mfma_f32_16x16x32_bf16(a0, bF0, acc, 0, 0, 0);
      acc = __builtin_amdgcn_mfma_f32_16x16x32_bf16(a1, bF1, acc, 0, 0, 0);
      sum += __expf(acc[0] * 0.125f) + __expf(acc[1] * 0.125f)
           + __expf(acc[2] * 0.125f) + __expf(acc[3] * 0.125f);
    }
  }
  sum += __shfl_xor(sum, 16, 64);
  sum += __shfl_xor(sum, 32, 64);
  if (lane < 16) csum[(size_t)bh * TT + s0 + tile * 64 + sw * 16 + lane] = sum;
}

// ---------------- attention pass 2 (MFMA, 8 waves, 2 t-tiles/block) ----------------
__global__ __launch_bounds__(512) void k_attn_apply_mfma(const u16* __restrict__ Qb, const u16* __restrict__ Kb,
                                                         const u16* __restrict__ Vt,
                                                         const float* __restrict__ csum,
                                                         u16* __restrict__ Op) {
  __shared__ u16 Qs[2 * 4608];
  __shared__ u16 KV2[2 * 4608];    // Ks | VTs; reused by the write epilogue
  __shared__ u16 Pl[8 * 1024];     // per-wave [16 t][64 s] bf16, XOR-swizzled
  __shared__ float rcsL[64];
  u16* Ks = KV2;
  u16* VTs = KV2 + 4608;
  int tid = threadIdx.x, wave = tid >> 6, lane = tid & 63;
  int tileIdx, bh;
  swz_attn(tileIdx, bh);
  int b = bh >> 4, h = bh & 15;
  int t0 = tileIdx << 7;                  // 128 t-rows per block
  int tile = wave >> 2, tw = wave & 3;
  stage_tile512(Qb + ((size_t)(b * TT + t0)) * DD + h * 64, DD, Qs, tid);
  stage_tile512(Qb + ((size_t)(b * TT + t0 + 64)) * DD + h * 64, DD, Qs + 4608, tid);
  int row = tid >> 3, col8 = (tid & 7) << 3;
  const u16* Kg = Kb + ((size_t)(b * TT) + row) * DD + h * 64 + col8;
  const u16* Vg = Vt + ((size_t)(h * 64) + row) * 4096 + (size_t)b * TT + col8;
  const size_t cbase = (size_t)bh * TT;
  uint4 kreg = *(const uint4*)Kg;          // s0 = 0
  uint4 vreg = *(const uint4*)Vg;
  float rc0 = (tid < 64) ? csum[cbase + tid] : 0.f;
  __syncthreads();                          // Qs visible
  int fr = lane & 15, g = lane >> 4;
  const u16* QbF = Qs + tile * 4608 + (tw * 16 + fr) * 72 + g * 8;   // B-frag (n = t)
  const u16* KaF = Ks + fr * 72 + g * 8;                             // A-frag rows s
  char* Pw = (char*)(Pl + wave * 1024);
  uint swz = ((uint)(lane & 7)) << 4;
  s16x8 qF0 = *(const s16x8*)(QbF);
  s16x8 qF1 = *(const s16x8*)(QbF + 32);
  f32x4 acc_o[4];
  #pragma unroll
  for (int nt = 0; nt < 4; ++nt) acc_o[nt] = f32x4{0.f, 0.f, 0.f, 0.f};

  for (int s0 = 0; s0 < TT; s0 += 64) {
    __syncthreads();                        // prior Ks/VTs reads done
    *(uint4*)(Ks + row * 72 + col8) = kreg;
    *(uint4*)(VTs + row * 72 + col8) = vreg;
    if (tid < 64) rcsL[tid] = 1.f / rc0;
    __syncthreads();                        // visible
    if (s0 + 64 < TT) {                     // issue next-tile loads; hide under compute
      kreg = *(const uint4*)(Kg + (size_t)(s0 + 64) * DD);
      vreg = *(const uint4*)(Vg + s0 + 64);
      if (tid < 64) rc0 = csum[cbase + s0 + 64 + tid];
    }
    // S^T tiles + exp -> P (per-wave)
    #pragma unroll
    for (int mt = 0; mt < 4; ++mt) {
      f32x4 acc = f32x4{0.f, 0.f, 0.f, 0.f};
      s16x8 a0 = *(const s16x8*)(KaF + mt * 16 * 72);
      s16x8 a1 = *(const s16x8*)(KaF + mt * 16 * 72 + 32);
      acc = __builtin_amdgcn_mfma_f32_16x16x32_bf16(a0, qF0, acc, 0, 0, 0);
      acc = __builtin_amdgcn_mfma_f32_16x16x32_bf16(a1, qF1, acc, 0, 0, 0);
      f32x4 rc4 = *(const f32x4*)&rcsL[mt * 16 + g * 4];
      u16 pb[4];
      #pragma unroll
      for (int r = 0; r < 4; ++r)
        pb[r] = f2bf(__expf(acc[r] * 0.125f) * rc4[r]);
      uint woff = (uint)fr * 128 + (uint)(mt * 16 + g * 4) * 2;
      uint2 wv; wv.x = (u32)pb[0] | ((u32)pb[1] << 16); wv.y = (u32)pb[2] | ((u32)pb[3] << 16);
      *(uint2*)(Pw + (woff ^ swz)) = wv;
    }
    // PV: A = P (own wave's tile), B = V^T
    uint rbase = (uint)fr * 128;
    s16x8 pF0 = *(const s16x8*)(Pw + ((rbase + g * 16) ^ swz));
    s16x8 pF1 = *(const s16x8*)(Pw + ((rbase + 64 + g * 16) ^ swz));
    #pragma unroll
    for (int nt = 0; nt < 4; ++nt) {
      s16x8 v0 = *(const s16x8*)(VTs + (nt * 16 + fr) * 72 + g * 8);
      s16x8 v1 = *(const s16x8*)(VTs + (nt * 16 + fr) * 72 + 32 + g * 8);
      acc_o[nt] = __builtin_amdgcn_mfma_f32_16x16x32_bf16(pF0, v0, acc_o[nt], 0, 0, 0);
      acc_o[nt] = __builtin_amdgcn_mfma_f32_16x16x32_bf16(pF1, v1, acc_o[nt], 0, 0, 0);
    }
  }
  // write epilogue: per-wave LDS transpose (reuse KV2) -> coalesced 32B/lane stores
  __syncthreads();                         // all waves done reading Ks/VTs
  u16* Ep = KV2 + wave * 1088;             // per-wave [16][68]
  #pragma unroll
  for (int nt = 0; nt < 4; ++nt)
    #pragma unroll
    for (int r = 0; r < 4; ++r)
      Ep[(g * 4 + r) * 68 + nt * 16 + fr] = f2bf(acc_o[nt][r]);
  {
    int rw = lane >> 2, seg = lane & 3;
    const u16* src = Ep + rw * 68 + seg * 16;
    u16* gd = Op + ((size_t)(b * TT + t0 + tile * 64 + tw * 16 + rw)) * DD + h * 64 + seg * 16;
    #pragma unroll
    for (int i = 0; i < 4; ++i) *(uint2*)(gd + i * 4) = *(const uint2*)(src + i * 4);
  }
}

// ---------------- O = norm(sum of bf16 partials + bias + residual), ddof=1 ----------------
__global__ __launch_bounds__(256) void k_add_norm(const u16* __restrict__ A, const u16* __restrict__ A2,
                                                  const u16* __restrict__ A3, const u16* __restrict__ A4,
                                                  const float* __restrict__ bias,
                                                  const float* __restrict__ Bv,
                                                  float* __restrict__ O, u16* __restrict__ Ob) {
  int row = blockIdx.x, tid = threadIdx.x;
  size_t base = (size_t)row * DD;
  int c0 = tid * 4;
  __shared__ float red[256];
  float v[4];
  {
    ushort4 a = *(const ushort4*)(A + base + c0);
    float4 bv = *(const float4*)(Bv + base + c0);
    v[0] = bf2f(a.x) + bv.x; v[1] = bf2f(a.y) + bv.y;
    v[2] = bf2f(a.z) + bv.z; v[3] = bf2f(a.w) + bv.w;
  }
  if (A2) {
    ushort4 a = *(const ushort4*)(A2 + base + c0);
    v[0] += bf2f(a.x); v[1] += bf2f(a.y); v[2] += bf2f(a.z); v[3] += bf2f(a.w);
  }
  if (A3) {
    ushort4 a = *(const ushort4*)(A3 + base + c0);
    v[0] += bf2f(a.x); v[1] += bf2f(a.y); v[2] += bf2f(a.z); v[3] += bf2f(a.w);
  }
  if (A4) {
    ushort4 a = *(const ushort4*)(A4 + base + c0);
    v[0] += bf2f(a.x); v[1] += bf2f(a.y); v[2] += bf2f(a.z); v[3] += bf2f(a.w);
  }
  if (bias) {
    float4 bs = *(const float4*)(bias + c0);
    v[0] += bs.x; v[1] += bs.y; v[2] += bs.z; v[3] += bs.w;
  }
  float s = v[0] + v[1] + v[2] + v[3];
  red[tid] = s; __syncthreads();
  for (int t = 128; t > 0; t >>= 1) { if (tid < t) red[tid] += red[tid + t]; __syncthreads(); }
  float mean = red[0] * (1.f / 1024.f);
  __syncthreads();
  float vs = 0.f;
  #pragma unroll
  for (int i = 0; i < 4; ++i) { float d = v[i] - mean; vs += d * d; }
  red[tid] = vs; __syncthreads();
  for (int t = 128; t > 0; t >>= 1) { if (tid < t) red[tid] += red[tid + t]; __syncthreads(); }
  float inv = rsqrtf(red[0] * (1.f / 1023.f));
  float o[4];
  #pragma unroll
  for (int i = 0; i < 4; ++i) o[i] = (v[i] - mean) * inv;
  *(float4*)(O + base + c0) = *(float4*)o;
  if (Ob) {
    u16 ob[4] = { f2bf(o[0]), f2bf(o[1]), f2bf(o[2]), f2bf(o[3]) };
    *(ushort4*)(Ob + base + c0) = *(ushort4*)ob;
  }
}

extern "C" void kernel_launch(void* const* d_in, const int* in_sizes, int n_in,
                              void* d_out, int out_size, void* d_ws, size_t ws_size,
                              hipStream_t stream) {
  (void)in_sizes; (void)n_in; (void)out_size; (void)ws_size;
  const float* x    = (const float*)d_in[0];
  const float* y    = (const float*)d_in[1];
  const float* Wq1  = (const float*)d_in[2];
  const float* Wk1  = (const float*)d_in[3];
  const float* Wv1  = (const float*)d_in[4];
  const float* Wo1  = (const float*)d_in[5];
  const float* Wq2  = (const float*)d_in[6];
  const float* Wk2  = (const float*)d_in[7];
  const float* Wv2  = (const float*)d_in[8];
  const float* Wo2  = (const float*)d_in[9];
  const float* w_in  = (const float*)d_in[10];
  const float* b_in  = (const float*)d_in[11];
  const float* w_out = (const float*)d_in[12];
  const float* b_out = (const float*)d_in[13];

  float* ws = (float*)d_ws;
  size_t off = 0;
  auto allocw = [&](size_t nw) { float* p = ws + off; off += nw; return p; };
  const size_t MR = (size_t)BB * TT;           // 4096
  const size_t ND = MR * DD;                   // 4.19M elems

  u16* Bq   = (u16*)allocw(512 * 1024);        // Bq|Bk|Bv contiguous => fused B (3072 x 1024)
  u16* Bk   = (u16*)allocw(512 * 1024);
  u16* Bv   = (u16*)allocw(512 * 1024);
  u16* Bwo  = (u16*)allocw(512 * 1024);
  u16* Wi   = (u16*)allocw(2 * 1024 * 1024);
  u16* Wob  = (u16*)allocw(2 * 1024 * 1024);
  u16* xbf  = (u16*)allocw(ND / 2);
  u16* ybf  = (u16*)allocw(ND / 2);
  u16* REG  = (u16*)allocw(ND * 2);
  float* ff2  = allocw(ND);                    // partial slabs p0|p1 (bf16)
  float* out1 = allocw(ND);                    // residual; later partial slabs p2|p3
  float* out2 = allocw(ND);
  float* csum = allocw((size_t)BB * HH * TT);

  u16* Qb = REG;
  u16* Kb = REG + ND;
  u16* Vt = REG + 2 * ND;   // V col-major (1024 x 4096), pitch 4096
  u16* Mb = REG + 3 * ND;   // mhaO; also out1_bf between layers
  u16* ff1b = REG;
  u16* out2bf = ybf;
  float* doutHi = (float*)d_out + ND;
  u16* p0 = (u16*)ff2;          // bf16 partial slabs
  u16* p1 = (u16*)ff2 + ND;
  u16* p2 = (u16*)out1;         // only after out1 is dead (post-L2-norm)
  u16* p3 = (u16*)out1 + ND;

  dim3 blk(256), blkG(512), blkA(512);
  dim3 gConv(4096);
  dim3 gSm(1024);
  dim3 gRw(16, 16);
  dim3 gQKV(24, 32);         // N=3072
  dim3 gKV(16, 32);          // N=2048
  dim3 gP2(8, 32, 2);        // N=1024, split-K=2
  dim3 gF1(32, 32);          // N=4096
  dim3 gFF2(8, 32, 4);       // N=1024, split-K=4 (K=4096)
  dim3 gAttn(8, 64);         // (tiles, bh) + swz_attn -> per-XCD bh grouping
  dim3 gNorm(MR);

  // x passthrough + bf16 convert, one pass
  k_xprep<<<gConv, blk, 0, stream>>>(x, (float*)d_out, xbf, (int)ND);
  k_f2bf<<<gConv, blk, 0, stream>>>(y, ybf, (int)ND);
  k_f2bf<<<gConv, blk, 0, stream>>>(w_in, Wi, FFF * DD);
  k_f2bf<<<gConv, blk, 0, stream>>>(w_out, Wob, DD * FFF);

  // ---- Layer 1: masked self-attention on y ----
  k_softmax_w_bf<<<gSm, blk, 0, stream>>>(Wq1, Bq);
  k_softmax_w_bf<<<gSm, blk, 0, stream>>>(Wk1, Bk);
  k_reorder_w_bf<<<gRw, blk, 0, stream>>>(Wv1, Bv);
  k_transpose_bf<<<gRw, blk, 0, stream>>>(Wo1, Bwo);
  k_mfma_nt<<<gQKV, blkG, 0, stream>>>(ybf, Bq, nullptr, nullptr, nullptr, nullptr, Qb, Kb, Vt, nullptr, 0, 1, 4096, 3072, 1024);
  k_attn_stats_mfma<<<gAttn, blkA, 0, stream>>>(Qb, Kb, csum);
  k_attn_apply_mfma<<<gAttn, blkA, 0, stream>>>(Qb, Kb, Vt, csum, Mb);
  // out-proj split-K=2: bf16 partials p0,p1
  k_mfma_nt<<<gP2, blkG, 0, stream>>>(Mb, Bwo, p0, p1, nullptr, nullptr, nullptr, nullptr, nullptr, nullptr, 0, 0, 4096, 1024, 1024);
  k_add_norm<<<gNorm, blk, 0, stream>>>(p0, p1, nullptr, nullptr, nullptr, y, out1, Mb /* out1_bf */);

  // ---- Layer 2: cross-attention (Q from out1, K/V from x) ----
  k_reorder_w_bf<<<gRw, blk, 0, stream>>>(Wq2, Bq);
  k_reorder_w_bf<<<gRw, blk, 0, stream>>>(Wk2, Bk);
  k_reorder_w_bf<<<gRw, blk, 0, stream>>>(Wv2, Bv);
  k_transpose_bf<<<gRw, blk, 0, stream>>>(Wo2, Bwo);
  // Q2 proj split-K=2 -> bf16 partials, then combine -> Qb bf16
  k_mfma_nt<<<gP2, blkG, 0, stream>>>(Mb /* out1_bf */, Bq, p0, p1, nullptr, nullptr, nullptr, nullptr, nullptr, nullptr, 0, 0, 4096, 1024, 1024);
  k_combine_bf<<<gConv, blk, 0, stream>>>(p0, p1, Qb, (int)ND);
  k_mfma_nt<<<gKV, blkG, 0, stream>>>(xbf, Bk, nullptr, nullptr, nullptr, nullptr, Kb, nullptr, Vt, nullptr, 0, 2, 4096, 2048, 1024);
  k_attn_stats_mfma<<<gAttn, blkA, 0, stream>>>(Qb, Kb, csum);
  k_attn_apply_mfma<<<gAttn, blkA, 0, stream>>>(Qb, Kb, Vt, csum, Mb);
  // out-proj split-K=2: bf16 partials
  k_mfma_nt<<<gP2, blkG, 0, stream>>>(Mb, Bwo, p0, p1, nullptr, nullptr, nullptr, nullptr, nullptr, nullptr, 0, 0, 4096, 1024, 1024);
  k_add_norm<<<gNorm, blk, 0, stream>>>(p0, p1, nullptr, nullptr, nullptr, out1, out2, out2bf);

  // ---- FF ----  (out1 dead from here; p2/p3 alias it)
  k_mfma_nt<<<gF1, blkG, 0, stream>>>(out2bf, Wi, nullptr, nullptr, nullptr, nullptr, ff1b, nullptr, nullptr, b_in, 1, 0, 4096, 4096, 1024);
  // FF2 split-K=4: bf16 partials p0..p3; bias ONCE in final norm
  k_mfma_nt<<<gFF2, blkG, 0, stream>>>(ff1b, Wob, p0, p1, p2, p3, nullptr, nullptr, nullptr, nullptr, 0, 0, 4096, 1024, 4096);
  k_add_norm<<<gNorm, blk, 0, stream>>>(p0, p1, p2, p3, b_out, out2, doutHi, nullptr);
}

// Round 13
// 385.440 us; speedup vs baseline: 1.1929x; 1.0472x over previous
//
#include <hip/hip_runtime.h>
#include <hip/hip_bf16.h>

#define BB 4
#define TT 1024
#define DD 1024
#define HH 16
#define DKK 64
#define FFF 4096

typedef unsigned short u16;
typedef unsigned int u32;
typedef __attribute__((ext_vector_type(8))) short s16x8;
typedef __attribute__((ext_vector_type(4))) float f32x4;

static __device__ __forceinline__ float bf2f(u16 s) {
  union { u32 u; float f; } v; v.u = ((u32)s) << 16; return v.f;
}
static __device__ __forceinline__ u16 f2bf(float f) {
  union { float f; u32 u; } v; v.f = f;
  u32 r = v.u + 0x7FFFu + ((v.u >> 16) & 1u);
  return (u16)(r >> 16);
}

#define GLDS(gp, lp) __builtin_amdgcn_global_load_lds( \
    (const __attribute__((address_space(1))) u32*)(gp), \
    (__attribute__((address_space(3))) u32*)(lp), 16, 0, 0)

// XCD-chunked bijective block swizzle (m204 formula), 8-row supertiles.
static __device__ __forceinline__ void swz_block(int& bx, int& by) {
  int gx = gridDim.x, gy = gridDim.y;
  int nwg = gx * gy;
  int orig = by * gx + bx;
  int q = nwg >> 3, r = nwg & 7;
  int xcd = orig & 7, sl = orig >> 3;
  int wgid = (xcd < r ? xcd * (q + 1) : r * (q + 1) + (xcd - r) * q) + sl;
  int g = gx << 3;
  int grp = wgid / g, rem = wgid % g;
  bx = rem >> 3;
  by = (grp << 3) + (rem & 7);
}

// attention swizzle: 512 blocks (8 tiles x 64 bh); XCD j owns bh [8j, 8j+8) x all tiles.
static __device__ __forceinline__ void swz_attn(int& tileIdx, int& bh) {
  int orig = blockIdx.y * 8 + blockIdx.x;
  int wgid = ((orig & 7) << 6) | (orig >> 3);
  tileIdx = wgid & 7;
  bh = wgid >> 3;
}

// ---------------- merged prep: x->dout+xbf | y->ybf | w_in->Wi | w_out->Wob ----------------
__global__ __launch_bounds__(256) void k_prep(const float* __restrict__ x, float* __restrict__ dout,
                                              u16* __restrict__ xb,
                                              const float* __restrict__ y, u16* __restrict__ yb,
                                              const float* __restrict__ wi, u16* __restrict__ Wi,
                                              const float* __restrict__ wo, u16* __restrict__ Wob) {
  int seg = blockIdx.x >> 12;                 // 4096 blocks per segment
  int i = ((blockIdx.x & 4095) * 256 + threadIdx.x) * 4;
  if (seg == 0) {
    float4 v = *(const float4*)(x + i);
    *(float4*)(dout + i) = v;
    u16 o[4] = { f2bf(v.x), f2bf(v.y), f2bf(v.z), f2bf(v.w) };
    *(ushort4*)(xb + i) = *(ushort4*)o;
    return;
  }
  const float* s = (seg == 1) ? y : ((seg == 2) ? wi : wo);
  u16* d = (seg == 1) ? yb : ((seg == 2) ? Wi : Wob);
  float4 v = *(const float4*)(s + i);
  u16 o[4] = { f2bf(v.x), f2bf(v.y), f2bf(v.z), f2bf(v.w) };
  *(ushort4*)(d + i) = *(ushort4*)o;
}

// ---------------- masked softmax over d (axis -2) for TWO weights, write bf16 B[n][d] ----------------
__global__ __launch_bounds__(256) void k_softmax_w2_bf(const float* __restrict__ Wq, const float* __restrict__ Wk,
                                                       u16* __restrict__ Bq, u16* __restrict__ Bk) {
  int sel = blockIdx.x >> 10;
  int col = blockIdx.x & 1023;    // h*64 + k
  const float* W = sel ? Wk : Wq;
  u16* Bt = sel ? Bk : Bq;
  int h = col >> 6, k = col & 63;
  int tid = threadIdx.x;
  const float* w = W + ((size_t)h * DD) * DKK + k;
  __shared__ float red[256];
  float m = -1e30f;
  for (int d = k + tid; d < DD; d += 256) m = fmaxf(m, w[(size_t)d * DKK]);
  red[tid] = m; __syncthreads();
  for (int s = 128; s > 0; s >>= 1) { if (tid < s) red[tid] = fmaxf(red[tid], red[tid + s]); __syncthreads(); }
  m = red[0]; __syncthreads();
  float sum = 0.f;
  for (int d = k + tid; d < DD; d += 256) sum += __expf(w[(size_t)d * DKK] - m);
  red[tid] = sum; __syncthreads();
  for (int s = 128; s > 0; s >>= 1) { if (tid < s) red[tid] += red[tid + s]; __syncthreads(); }
  float inv = 1.f / red[0];
  for (int d = tid; d < DD; d += 256) {
    float v = (d >= k) ? __expf(w[(size_t)d * DKK] - m) * inv : 0.f;
    Bt[(size_t)col * DD + d] = f2bf(v);
  }
}

// ---------------- reorder (H, D, DK) -> bf16 B[n=h*64+k][d]; z picks one of 3 weights ----------------
__global__ __launch_bounds__(256) void k_reorder3_bf(const float* __restrict__ W0, const float* __restrict__ W1,
                                                     const float* __restrict__ W2, u16* __restrict__ Bt0) {
  int z = blockIdx.z;
  const float* W = (z == 0) ? W0 : ((z == 1) ? W1 : W2);
  u16* Bt = Bt0 + (size_t)z * 1024 * 1024;
  int d0 = blockIdx.x << 6, h = blockIdx.y;
  __shared__ float t[64][65];
  int tid = threadIdx.x;
  const float* src = W + (size_t)h * DD * DKK + (size_t)d0 * DKK;
  #pragma unroll
  for (int i = 0; i < 16; ++i) {
    int e = i * 256 + tid; int r = e >> 6, c = e & 63;
    t[r][c] = src[(size_t)r * DKK + c];
  }
  __syncthreads();
  #pragma unroll
  for (int i = 0; i < 16; ++i) {
    int e = i * 256 + tid; int c = e >> 6, r = e & 63;
    Bt[((size_t)(h * 64 + c)) * DD + d0 + r] = f2bf(t[r][c]);
  }
}

// ---------------- reorder single (H, D, DK) -> bf16 B[n][d] ----------------
__global__ __launch_bounds__(256) void k_reorder_w_bf(const float* __restrict__ W, u16* __restrict__ Bt) {
  int d0 = blockIdx.x << 6, h = blockIdx.y;
  __shared__ float t[64][65];
  int tid = threadIdx.x;
  const float* src = W + (size_t)h * DD * DKK + (size_t)d0 * DKK;
  #pragma unroll
  for (int i = 0; i < 16; ++i) {
    int e = i * 256 + tid; int r = e >> 6, c = e & 63;
    t[r][c] = src[(size_t)r * DKK + c];
  }
  __syncthreads();
  #pragma unroll
  for (int i = 0; i < 16; ++i) {
    int e = i * 256 + tid; int c = e >> 6, r = e & 63;
    Bt[((size_t)(h * 64 + c)) * DD + d0 + r] = f2bf(t[r][c]);
  }
}

// ---------------- transpose (K,N) f32 -> bf16 B[n][k] ----------------
__global__ __launch_bounds__(256) void k_transpose_bf(const float* __restrict__ W, u16* __restrict__ Bt) {
  int k0 = blockIdx.x << 6, n0 = blockIdx.y << 6;
  __shared__ float t[64][65];
  int tid = threadIdx.x;
  #pragma unroll
  for (int i = 0; i < 16; ++i) {
    int e = i * 256 + tid; int r = e >> 6, c = e & 63;
    t[r][c] = W[(size_t)(k0 + r) * DD + n0 + c];
  }
  __syncthreads();
  #pragma unroll
  for (int i = 0; i < 16; ++i) {
    int e = i * 256 + tid; int c = e >> 6, r = e & 63;
    Bt[(size_t)(n0 + c) * DD + k0 + r] = f2bf(t[r][c]);
  }
}

// ---------------- MFMA NT GEMM: C = A(MxK) * B(NxK)^T (bf16 in, f32 acc) ----------------
// 128x128 tile, BK=32, 512 threads (8 waves 2x4, wave-tile 64x32), XCD swizzle,
// split-K via blockIdx.z, bf16 outputs via per-wave LDS slab.
// T4-lite pipeline: 3-buffer rotation, issue-ahead-2, ONE raw s_barrier +
// counted s_waitcnt vmcnt(2) per K-step (loads stay in flight across barriers).
// mode 1 with A2: blocks with col0>=1024 read A2 instead of A (fused QKV, mixed A).
__global__ __launch_bounds__(512) void k_mfma_nt(
    const u16* __restrict__ A, const u16* __restrict__ A2,
    const u16* __restrict__ B,
    u16* __restrict__ P0, u16* __restrict__ P1, u16* __restrict__ P2, u16* __restrict__ P3,
    u16* __restrict__ Cb, u16* __restrict__ Cb2, u16* __restrict__ Ct,
    const float* __restrict__ bias, int relu, int mode, int M, int N, int K) {
  __shared__ u16 SLDS[24576];   // A bufs [0,12288), B bufs [12288,24576); epilogue reuses [0,16384)
  int bx = blockIdx.x, by = blockIdx.y;
  swz_block(bx, by);
  int tid = threadIdx.x, wave = tid >> 6, lane = tid & 63;
  int row0 = by << 7, col0 = bx << 7;
  int wm = (wave >> 2) << 6;        // 0 / 64
  int wn = (wave & 3) << 5;         // 0 / 32 / 64 / 96

  const u16* Asrc = (mode == 1 && A2 && (col0 >> 10) > 0) ? A2 : A;

  int Ksl = K / gridDim.z;
  int kbase = blockIdx.z * Ksl;
  int nt = Ksl >> 5;                // K-steps of 32

  f32x4 acc[4][2];
  #pragma unroll
  for (int m = 0; m < 4; ++m)
    #pragma unroll
    for (int n = 0; n < 2; ++n) acc[m][n] = f32x4{0.f, 0.f, 0.f, 0.f};

  // staging: [128][32] bf16 = 8 KB per matrix; 512 threads x 16B = exactly one GLDS each.
  int srow = tid >> 2, scol = (tid & 3) << 3;
  const u16* Ag = Asrc + (size_t)(row0 + srow) * K + scol;
  const u16* Bg = B + (size_t)(col0 + srow) * K + scol;
  int wbase = wave << 9;            // u16 offset of this wave's 1KB chunk

  int fr = lane & 15, kg = (lane >> 4) << 3;
  int ardo = (wm + fr) * 32 + kg;
  int brdo = 12288 + (wn + fr) * 32 + kg;

  auto STAGE = [&](int buf, int k0) {
    GLDS(Ag + k0, SLDS + buf * 4096 + wbase);
    GLDS(Bg + k0, SLDS + 12288 + buf * 4096 + wbase);
  };

  STAGE(0, kbase);
  if (nt > 1) STAGE(1, kbase + 32);
  int bufT = 0;
  for (int t = 0; t < nt; ++t) {
    // wait for buf[t]'s own loads; STAGE(t+1) (2 loads) may stay in flight
    if (t + 1 < nt) asm volatile("s_waitcnt vmcnt(2)" ::: "memory");
    else            asm volatile("s_waitcnt vmcnt(0)" ::: "memory");
    __builtin_amdgcn_s_barrier();     // all threads' buf[t] chunks landed
    asm volatile("" ::: "memory");
    if (t + 2 < nt) {
      int b2 = bufT + 2; if (b2 >= 3) b2 -= 3;
      STAGE(b2, kbase + (t + 2) * 32);  // overwrites buf[t-1]: safe, reads done pre-barrier
    }
    const u16* Ard = SLDS + bufT * 4096 + ardo;
    const u16* Brd = SLDS + bufT * 4096 + brdo;
    s16x8 aF[4], bF[2];
    #pragma unroll
    for (int m = 0; m < 4; ++m) aF[m] = *(const s16x8*)(Ard + m * 16 * 32);
    #pragma unroll
    for (int n = 0; n < 2; ++n) bF[n] = *(const s16x8*)(Brd + n * 16 * 32);
    #pragma unroll
    for (int m = 0; m < 4; ++m)
      #pragma unroll
      for (int n = 0; n < 2; ++n)
        acc[m][n] = __builtin_amdgcn_mfma_f32_16x16x32_bf16(aF[m], bF[n], acc[m][n], 0, 0, 0);
    ++bufT; if (bufT == 3) bufT = 0;
  }
  __syncthreads();                    // epilogue slab aliases staging bufs: wait all reads done

  int fq = (lane >> 4) << 2;

  // ---- all outputs bf16 via per-wave [16][40] LDS slab, 4 m-passes -> coalesced stores ----
  u16* dstRow = nullptr; u16* dstCol = nullptr;
  int rowPitch = 1024, colBase = col0 & 1023;
  if (mode == 0) {
    rowPitch = N; colBase = col0;
    if (gridDim.z > 1) {
      int z = blockIdx.z;
      dstRow = (z == 0) ? P0 : ((z == 1) ? P1 : ((z == 2) ? P2 : P3));
    } else dstRow = Cb;
  }
  else if (mode == 1) { int q = col0 >> 10; if (q == 0) dstRow = Cb; else if (q == 1) dstRow = Cb2; else dstCol = Ct; }
  else { int q = col0 >> 10; if (q == 0) dstRow = Cb; else dstCol = Ct; }

  u16* Ep = SLDS + wave * 2048;   // wave-private slab (16*40=640 u16 used)
  #pragma unroll
  for (int m = 0; m < 4; ++m) {
    #pragma unroll
    for (int n = 0; n < 2; ++n) {
      int col = col0 + wn + n * 16 + fr;
      float bs = bias ? bias[col] : 0.f;
      #pragma unroll
      for (int r = 0; r < 4; ++r) {
        float v = acc[m][n][r] + bs;
        if (relu) v = fmaxf(v, 0.f);
        Ep[(fq + r) * 40 + n * 16 + fr] = f2bf(v);
      }
    }
    if (dstRow) {
      int rw = lane >> 2, seg = lane & 3;                  // 16 rows x 4 segs of 8
      const u16* src = Ep + rw * 40 + seg * 8;
      u16* gd = dstRow + (size_t)(row0 + wm + m * 16 + rw) * rowPitch + colBase + wn + seg * 8;
      *(uint4*)gd = *(const uint4*)src;                    // 4 lanes x 16B = 64B line
    } else {
      int c = lane >> 1, half = lane & 1;                  // 32 cols x 2 halves of 8 rows
      u16 tmp[8];
      #pragma unroll
      for (int j = 0; j < 8; ++j) tmp[j] = Ep[(half * 8 + j) * 40 + c];
      u16* gd = dstCol + (size_t)(colBase + wn + c) * 4096 + row0 + wm + m * 16 + half * 8;
      *(uint4*)gd = *(const uint4*)tmp;                    // 2 lanes x 16B = 32B per col
    }
  }
}

// ---------------- stage one 64x64 bf16 tile (512 threads, 1 uint4 each) -> LDS [64][72] ----------------
static __device__ __forceinline__ void stage_tile512(const u16* __restrict__ g, int gp, u16* L, int tid) {
  int row = tid >> 3, col8 = (tid & 7) << 3;
  *(uint4*)(L + row * 72 + col8) = *(const uint4*)(g + (size_t)row * gp + col8);
}

// ---------------- attention pass 1 (MFMA, 8 waves, 2 s-tiles/block) ----------------
// csum[s] = sum_t exp(S[t][s]); no-max softmax (S small, exp-safe; shift-invariant).
__global__ __launch_bounds__(512) void k_attn_stats_mfma(const u16* __restrict__ Qb, const u16* __restrict__ Kb,
                                                         float* __restrict__ csum) {
  __shared__ u16 Ks[2 * 4608];
  __shared__ u16 Qs[4608];
  int tid = threadIdx.x, wave = tid >> 6, lane = tid & 63;
  int tileIdx, bh;
  swz_attn(tileIdx, bh);
  int b = bh >> 4, h = bh & 15;
  int s0 = tileIdx << 7;                  // 128 s-cols per block
  int tile = wave >> 2, sw = wave & 3;
  stage_tile512(Kb + ((size_t)(b * TT + s0)) * DD + h * 64, DD, Ks, tid);
  stage_tile512(Kb + ((size_t)(b * TT + s0 + 64)) * DD + h * 64, DD, Ks + 4608, tid);
  int row = tid >> 3, col8 = (tid & 7) << 3;
  const u16* Qg = Qb + ((size_t)(b * TT) + row) * DD + h * 64 + col8;
  uint4 qreg = *(const uint4*)Qg;          // tile t0=0
  __syncthreads();                          // Ks visible
  int fr = lane & 15, g = lane >> 4;
  const u16* Bbase = Ks + tile * 4608 + (sw * 16 + fr) * 72 + g * 8;   // B-frag: K rows (n = s)
  const u16* Abase = Qs + fr * 72 + g * 8;                             // A-frag: Q rows (m = t)
  s16x8 bF0 = *(const s16x8*)(Bbase);
  s16x8 bF1 = *(const s16x8*)(Bbase + 32);
  float sum = 0.f;
  for (int t0 = 0; t0 < TT; t0 += 64) {
    __syncthreads();                        // prior Qs reads done
    *(uint4*)(Qs + row * 72 + col8) = qreg;
    __syncthreads();                        // Qs visible
    if (t0 + 64 < TT) qreg = *(const uint4*)(Qg + (size_t)(t0 + 64) * DD);
    #pragma unroll
    for (int mt = 0; mt < 4; ++mt) {
      f32x4 acc = f32x4{0.f, 0.f, 0.f, 0.f};
      s16x8 a0 = *(const s16x8*)(Abase + mt * 16 * 72);
      s16x8 a1 = *(const s16x8*)(Abase + mt * 16 * 72 + 32);
      acc = __builtin_amdgcn_mfma_f32_16x16x32_bf16(a0, bF0, acc, 0, 0, 0);
      acc = __builtin_amdgcn_mfma_f32_16x16x32_bf16(a1, bF1, acc, 0, 0, 0);
      sum += __expf(acc[0] * 0.125f) + __expf(acc[1] * 0.125f)
           + __expf(acc[2] * 0.125f) + __expf(acc[3] * 0.125f);
    }
  }
  sum += __shfl_xor(sum, 16, 64);
  sum += __shfl_xor(sum, 32, 64);
  if (lane < 16) csum[(size_t)bh * TT + s0 + tile * 64 + sw * 16 + lane] = sum;
}

// ---------------- attention pass 2 (MFMA, 8 waves, 2 t-tiles/block) ----------------
__global__ __launch_bounds__(512) void k_attn_apply_mfma(const u16* __restrict__ Qb, const u16* __restrict__ Kb,
                                                         const u16* __restrict__ Vt,
                                                         const float* __restrict__ csum,
                                                         u16* __restrict__ Op) {
  __shared__ u16 Qs[2 * 4608];
  __shared__ u16 KV2[2 * 4608];    // Ks | VTs; reused by the write epilogue
  __shared__ u16 Pl[8 * 1024];     // per-wave [16 t][64 s] bf16, XOR-swizzled
  __shared__ float rcsL[64];
  u16* Ks = KV2;
  u16* VTs = KV2 + 4608;
  int tid = threadIdx.x, wave = tid >> 6, lane = tid & 63;
  int tileIdx, bh;
  swz_attn(tileIdx, bh);
  int b = bh >> 4, h = bh & 15;
  int t0 = tileIdx << 7;                  // 128 t-rows per block
  int tile = wave >> 2, tw = wave & 3;
  stage_tile512(Qb + ((size_t)(b * TT + t0)) * DD + h * 64, DD, Qs, tid);
  stage_tile512(Qb + ((size_t)(b * TT + t0 + 64)) * DD + h * 64, DD, Qs + 4608, tid);
  int row = tid >> 3, col8 = (tid & 7) << 3;
  const u16* Kg = Kb + ((size_t)(b * TT) + row) * DD + h * 64 + col8;
  const u16* Vg = Vt + ((size_t)(h * 64) + row) * 4096 + (size_t)b * TT + col8;
  const size_t cbase = (size_t)bh * TT;
  uint4 kreg = *(const uint4*)Kg;          // s0 = 0
  uint4 vreg = *(const uint4*)Vg;
  float rc0 = (tid < 64) ? csum[cbase + tid] : 0.f;
  __syncthreads();                          // Qs visible
  int fr = lane & 15, g = lane >> 4;
  const u16* QbF = Qs + tile * 4608 + (tw * 16 + fr) * 72 + g * 8;   // B-frag (n = t)
  const u16* KaF = Ks + fr * 72 + g * 8;                             // A-frag rows s
  char* Pw = (char*)(Pl + wave * 1024);
  uint swz = ((uint)(lane & 7)) << 4;
  s16x8 qF0 = *(const s16x8*)(QbF);
  s16x8 qF1 = *(const s16x8*)(QbF + 32);
  f32x4 acc_o[4];
  #pragma unroll
  for (int nt = 0; nt < 4; ++nt) acc_o[nt] = f32x4{0.f, 0.f, 0.f, 0.f};

  for (int s0 = 0; s0 < TT; s0 += 64) {
    __syncthreads();                        // prior Ks/VTs reads done
    *(uint4*)(Ks + row * 72 + col8) = kreg;
    *(uint4*)(VTs + row * 72 + col8) = vreg;
    if (tid < 64) rcsL[tid] = 1.f / rc0;
    __syncthreads();                        // visible
    if (s0 + 64 < TT) {                     // issue next-tile loads; hide under compute
      kreg = *(const uint4*)(Kg + (size_t)(s0 + 64) * DD);
      vreg = *(const uint4*)(Vg + s0 + 64);
      if (tid < 64) rc0 = csum[cbase + s0 + 64 + tid];
    }
    // S^T tiles + exp -> P (per-wave)
    #pragma unroll
    for (int mt = 0; mt < 4; ++mt) {
      f32x4 acc = f32x4{0.f, 0.f, 0.f, 0.f};
      s16x8 a0 = *(const s16x8*)(KaF + mt * 16 * 72);
      s16x8 a1 = *(const s16x8*)(KaF + mt * 16 * 72 + 32);
      acc = __builtin_amdgcn_mfma_f32_16x16x32_bf16(a0, qF0, acc, 0, 0, 0);
      acc = __builtin_amdgcn_mfma_f32_16x16x32_bf16(a1, qF1, acc, 0, 0, 0);
      f32x4 rc4 = *(const f32x4*)&rcsL[mt * 16 + g * 4];
      u16 pb[4];
      #pragma unroll
      for (int r = 0; r < 4; ++r)
        pb[r] = f2bf(__expf(acc[r] * 0.125f) * rc4[r]);
      uint woff = (uint)fr * 128 + (uint)(mt * 16 + g * 4) * 2;
      uint2 wv; wv.x = (u32)pb[0] | ((u32)pb[1] << 16); wv.y = (u32)pb[2] | ((u32)pb[3] << 16);
      *(uint2*)(Pw + (woff ^ swz)) = wv;
    }
    // PV: A = P (own wave's tile), B = V^T
    uint rbase = (uint)fr * 128;
    s16x8 pF0 = *(const s16x8*)(Pw + ((rbase + g * 16) ^ swz));
    s16x8 pF1 = *(const s16x8*)(Pw + ((rbase + 64 + g * 16) ^ swz));
    #pragma unroll
    for (int nt = 0; nt < 4; ++nt) {
      s16x8 v0 = *(const s16x8*)(VTs + (nt * 16 + fr) * 72 + g * 8);
      s16x8 v1 = *(const s16x8*)(VTs + (nt * 16 + fr) * 72 + 32 + g * 8);
      acc_o[nt] = __builtin_amdgcn_mfma_f32_16x16x32_bf16(pF0, v0, acc_o[nt], 0, 0, 0);
      acc_o[nt] = __builtin_amdgcn_mfma_f32_16x16x32_bf16(pF1, v1, acc_o[nt], 0, 0, 0);
    }
  }
  // write epilogue: per-wave LDS transpose (reuse KV2) -> coalesced 32B/lane stores
  __syncthreads();                         // all waves done reading Ks/VTs
  u16* Ep = KV2 + wave * 1088;             // per-wave [16][68]
  #pragma unroll
  for (int nt = 0; nt < 4; ++nt)
    #pragma unroll
    for (int r = 0; r < 4; ++r)
      Ep[(g * 4 + r) * 68 + nt * 16 + fr] = f2bf(acc_o[nt][r]);
  {
    int rw = lane >> 2, seg = lane & 3;
    const u16* src = Ep + rw * 68 + seg * 16;
    u16* gd = Op + ((size_t)(b * TT + t0 + tile * 64 + tw * 16 + rw)) * DD + h * 64 + seg * 16;
    #pragma unroll
    for (int i = 0; i < 4; ++i) *(uint2*)(gd + i * 4) = *(const uint2*)(src + i * 4);
  }
}

// ---------------- O = norm(sum of bf16 partials + bias + residual), ddof=1 ----------------
__global__ __launch_bounds__(256) void k_add_norm(const u16* __restrict__ A, const u16* __restrict__ A2,
                                                  const u16* __restrict__ A3, const u16* __restrict__ A4,
                                                  const float* __restrict__ bias,
                                                  const float* __restrict__ Bv,
                                                  float* __restrict__ O, u16* __restrict__ Ob) {
  int row = blockIdx.x, tid = threadIdx.x;
  size_t base = (size_t)row * DD;
  int c0 = tid * 4;
  __shared__ float red[256];
  float v[4];
  {
    ushort4 a = *(const ushort4*)(A + base + c0);
    float4 bv = *(const float4*)(Bv + base + c0);
    v[0] = bf2f(a.x) + bv.x; v[1] = bf2f(a.y) + bv.y;
    v[2] = bf2f(a.z) + bv.z; v[3] = bf2f(a.w) + bv.w;
  }
  if (A2) {
    ushort4 a = *(const ushort4*)(A2 + base + c0);
    v[0] += bf2f(a.x); v[1] += bf2f(a.y); v[2] += bf2f(a.z); v[3] += bf2f(a.w);
  }
  if (A3) {
    ushort4 a = *(const ushort4*)(A3 + base + c0);
    v[0] += bf2f(a.x); v[1] += bf2f(a.y); v[2] += bf2f(a.z); v[3] += bf2f(a.w);
  }
  if (A4) {
    ushort4 a = *(const ushort4*)(A4 + base + c0);
    v[0] += bf2f(a.x); v[1] += bf2f(a.y); v[2] += bf2f(a.z); v[3] += bf2f(a.w);
  }
  if (bias) {
    float4 bs = *(const float4*)(bias + c0);
    v[0] += bs.x; v[1] += bs.y; v[2] += bs.z; v[3] += bs.w;
  }
  float s = v[0] + v[1] + v[2] + v[3];
  red[tid] = s; __syncthreads();
  for (int t = 128; t > 0; t >>= 1) { if (tid < t) red[tid] += red[tid + t]; __syncthreads(); }
  float mean = red[0] * (1.f / 1024.f);
  __syncthreads();
  float vs = 0.f;
  #pragma unroll
  for (int i = 0; i < 4; ++i) { float d = v[i] - mean; vs += d * d; }
  red[tid] = vs; __syncthreads();
  for (int t = 128; t > 0; t >>= 1) { if (tid < t) red[tid] += red[tid + t]; __syncthreads(); }
  float inv = rsqrtf(red[0] * (1.f / 1023.f));
  float o[4];
  #pragma unroll
  for (int i = 0; i < 4; ++i) o[i] = (v[i] - mean) * inv;
  *(float4*)(O + base + c0) = *(float4*)o;
  if (Ob) {
    u16 ob[4] = { f2bf(o[0]), f2bf(o[1]), f2bf(o[2]), f2bf(o[3]) };
    *(ushort4*)(Ob + base + c0) = *(ushort4*)ob;
  }
}

extern "C" void kernel_launch(void* const* d_in, const int* in_sizes, int n_in,
                              void* d_out, int out_size, void* d_ws, size_t ws_size,
                              hipStream_t stream) {
  (void)in_sizes; (void)n_in; (void)out_size; (void)ws_size;
  const float* x    = (const float*)d_in[0];
  const float* y    = (const float*)d_in[1];
  const float* Wq1  = (const float*)d_in[2];
  const float* Wk1  = (const float*)d_in[3];
  const float* Wv1  = (const float*)d_in[4];
  const float* Wo1  = (const float*)d_in[5];
  const float* Wq2  = (const float*)d_in[6];
  const float* Wk2  = (const float*)d_in[7];
  const float* Wv2  = (const float*)d_in[8];
  const float* Wo2  = (const float*)d_in[9];
  const float* w_in  = (const float*)d_in[10];
  const float* b_in  = (const float*)d_in[11];
  const float* w_out = (const float*)d_in[12];
  const float* b_out = (const float*)d_in[13];

  float* ws = (float*)d_ws;
  size_t off = 0;
  auto allocw = [&](size_t nw) { float* p = ws + off; off += nw; return p; };
  const size_t MR = (size_t)BB * TT;           // 4096
  const size_t ND = MR * DD;                   // 4.19M elems

  u16* Bq   = (u16*)allocw(512 * 1024);        // Bq|Bk|Bv contiguous => fused B (3072 x 1024)
  u16* Bk   = (u16*)allocw(512 * 1024);
  u16* Bv   = (u16*)allocw(512 * 1024);
  u16* Bwo  = (u16*)allocw(512 * 1024);
  u16* Wi   = (u16*)allocw(2 * 1024 * 1024);
  u16* Wob  = (u16*)allocw(2 * 1024 * 1024);
  u16* xbf  = (u16*)allocw(ND / 2);
  u16* ybf  = (u16*)allocw(ND / 2);
  u16* REG  = (u16*)allocw(ND * 2);
  float* ff2  = allocw(ND);                    // partial slabs p0|p1 (bf16)
  float* out1 = allocw(ND);                    // residual; later partial slabs p2|p3
  float* out2 = allocw(ND);
  float* csum = allocw((size_t)BB * HH * TT);

  u16* Qb = REG;
  u16* Kb = REG + ND;
  u16* Vt = REG + 2 * ND;   // V col-major (1024 x 4096), pitch 4096
  u16* Mb = REG + 3 * ND;   // mhaO; also out1_bf between layers
  u16* ff1b = REG;
  u16* out2bf = ybf;
  float* doutHi = (float*)d_out + ND;
  u16* p0 = (u16*)ff2;          // bf16 partial slabs
  u16* p1 = (u16*)ff2 + ND;
  u16* p2 = (u16*)out1;         // only after out1 is dead (post-L2-norm)
  u16* p3 = (u16*)out1 + ND;
  (void)Bv;

  dim3 blk(256), blkG(512), blkA(512);
  dim3 gPrep(16384);
  dim3 gSm2(2048);
  dim3 gRw(16, 16);
  dim3 gRw3(16, 16, 3);
  dim3 gQKV(24, 32);         // N=3072
  dim3 gP2(8, 32, 2);        // N=1024, split-K=2
  dim3 gF1(32, 32);          // N=4096
  dim3 gFF2(8, 32, 4);       // N=1024, split-K=4 (K=4096)
  dim3 gAttn(8, 64);         // (tiles, bh) + swz_attn -> per-XCD bh grouping
  dim3 gNorm(MR);

  // merged prep: x->dout+xbf, y->ybf, w_in->Wi, w_out->Wob
  k_prep<<<gPrep, blk, 0, stream>>>(x, (float*)d_out, xbf, y, ybf, w_in, Wi, w_out, Wob);

  // ---- Layer 1: masked self-attention on y ----
  k_softmax_w2_bf<<<gSm2, blk, 0, stream>>>(Wq1, Wk1, Bq, Bk);
  k_reorder_w_bf<<<gRw, blk, 0, stream>>>(Wv1, Bv);
  k_transpose_bf<<<gRw, blk, 0, stream>>>(Wo1, Bwo);
  k_mfma_nt<<<gQKV, blkG, 0, stream>>>(ybf, nullptr, Bq, nullptr, nullptr, nullptr, nullptr, Qb, Kb, Vt, nullptr, 0, 1, 4096, 3072, 1024);
  k_attn_stats_mfma<<<gAttn, blkA, 0, stream>>>(Qb, Kb, csum);
  k_attn_apply_mfma<<<gAttn, blkA, 0, stream>>>(Qb, Kb, Vt, csum, Mb);
  // out-proj split-K=2: bf16 partials p0,p1
  k_mfma_nt<<<gP2, blkG, 0, stream>>>(Mb, nullptr, Bwo, p0, p1, nullptr, nullptr, nullptr, nullptr, nullptr, nullptr, 0, 0, 4096, 1024, 1024);
  k_add_norm<<<gNorm, blk, 0, stream>>>(p0, p1, nullptr, nullptr, nullptr, y, out1, Mb /* out1_bf */);

  // ---- Layer 2: cross-attention (Q from out1, K/V from x) ----
  k_reorder3_bf<<<gRw3, blk, 0, stream>>>(Wq2, Wk2, Wv2, Bq);
  k_transpose_bf<<<gRw, blk, 0, stream>>>(Wo2, Bwo);
  // fused QKV2: Q-cols read A=Mb (out1_bf), K/V-cols read A2=xbf; B=[Bq2|Bk2|Bv2]
  k_mfma_nt<<<gQKV, blkG, 0, stream>>>(Mb, xbf, Bq, nullptr, nullptr, nullptr, nullptr, Qb, Kb, Vt, nullptr, 0, 1, 4096, 3072, 1024);
  k_attn_stats_mfma<<<gAttn, blkA, 0, stream>>>(Qb, Kb, csum);
  k_attn_apply_mfma<<<gAttn, blkA, 0, stream>>>(Qb, Kb, Vt, csum, Mb);
  // out-proj split-K=2: bf16 partials
  k_mfma_nt<<<gP2, blkG, 0, stream>>>(Mb, nullptr, Bwo, p0, p1, nullptr, nullptr, nullptr, nullptr, nullptr, nullptr, 0, 0, 4096, 1024, 1024);
  k_add_norm<<<gNorm, blk, 0, stream>>>(p0, p1, nullptr, nullptr, nullptr, out1, out2, out2bf);

  // ---- FF ----  (out1 dead from here; p2/p3 alias it)
  k_mfma_nt<<<gF1, blkG, 0, stream>>>(out2bf, nullptr, Wi, nullptr, nullptr, nullptr, nullptr, ff1b, nullptr, nullptr, b_in, 1, 0, 4096, 4096, 1024);
  // FF2 split-K=4: bf16 partials p0..p3; bias ONCE in final norm
  k_mfma_nt<<<gFF2, blkG, 0, stream>>>(ff1b, nullptr, Wob, p0, p1, p2, p3, nullptr, nullptr, nullptr, nullptr, 0, 0, 4096, 1024, 4096);
  k_add_norm<<<gNorm, blk, 0, stream>>>(p0, p1, p2, p3, b_out, out2, doutHi, nullptr);
}

// Round 14
// 381.426 us; speedup vs baseline: 1.2054x; 1.0105x over previous
//
#include <hip/hip_runtime.h>
#include <hip/hip_bf16.h>

#define BB 4
#define TT 1024
#define DD 1024
#define HH 16
#define DKK 64
#define FFF 4096

typedef unsigned short u16;
typedef unsigned int u32;
typedef __attribute__((ext_vector_type(8))) short s16x8;
typedef __attribute__((ext_vector_type(4))) float f32x4;

static __device__ __forceinline__ float bf2f(u16 s) {
  union { u32 u; float f; } v; v.u = ((u32)s) << 16; return v.f;
}
static __device__ __forceinline__ u16 f2bf(float f) {
  union { float f; u32 u; } v; v.f = f;
  u32 r = v.u + 0x7FFFu + ((v.u >> 16) & 1u);
  return (u16)(r >> 16);
}

#define GLDS(gp, lp) __builtin_amdgcn_global_load_lds( \
    (const __attribute__((address_space(1))) u32*)(gp), \
    (__attribute__((address_space(3))) u32*)(lp), 16, 0, 0)

// XCD-chunked bijective block swizzle (m204 formula), 8-row supertiles.
static __device__ __forceinline__ void swz_block(int& bx, int& by) {
  int gx = gridDim.x, gy = gridDim.y;
  int nwg = gx * gy;
  int orig = by * gx + bx;
  int q = nwg >> 3, r = nwg & 7;
  int xcd = orig & 7, sl = orig >> 3;
  int wgid = (xcd < r ? xcd * (q + 1) : r * (q + 1) + (xcd - r) * q) + sl;
  int g = gx << 3;
  int grp = wgid / g, rem = wgid % g;
  bx = rem >> 3;
  by = (grp << 3) + (rem & 7);
}

// attention swizzle: 512 blocks (8 tiles x 64 bh); XCD j owns bh [8j, 8j+8) x all tiles.
static __device__ __forceinline__ void swz_attn(int& tileIdx, int& bh) {
  int orig = blockIdx.y * 8 + blockIdx.x;
  int wgid = ((orig & 7) << 6) | (orig >> 3);
  tileIdx = wgid & 7;
  bh = wgid >> 3;
}

// ---------------- merged prep: x->dout+xbf | y->ybf | w_in->Wi | w_out->Wob ----------------
__global__ __launch_bounds__(256) void k_prep(const float* __restrict__ x, float* __restrict__ dout,
                                              u16* __restrict__ xb,
                                              const float* __restrict__ y, u16* __restrict__ yb,
                                              const float* __restrict__ wi, u16* __restrict__ Wi,
                                              const float* __restrict__ wo, u16* __restrict__ Wob) {
  int seg = blockIdx.x >> 12;                 // 4096 blocks per segment
  int i = ((blockIdx.x & 4095) * 256 + threadIdx.x) * 4;
  if (seg == 0) {
    float4 v = *(const float4*)(x + i);
    *(float4*)(dout + i) = v;
    u16 o[4] = { f2bf(v.x), f2bf(v.y), f2bf(v.z), f2bf(v.w) };
    *(ushort4*)(xb + i) = *(ushort4*)o;
    return;
  }
  const float* s = (seg == 1) ? y : ((seg == 2) ? wi : wo);
  u16* d = (seg == 1) ? yb : ((seg == 2) ? Wi : Wob);
  float4 v = *(const float4*)(s + i);
  u16 o[4] = { f2bf(v.x), f2bf(v.y), f2bf(v.z), f2bf(v.w) };
  *(ushort4*)(d + i) = *(ushort4*)o;
}

// ---------------- masked softmax over d (axis -2) for TWO weights, write bf16 B[n][d] ----------------
__global__ __launch_bounds__(256) void k_softmax_w2_bf(const float* __restrict__ Wq, const float* __restrict__ Wk,
                                                       u16* __restrict__ Bq, u16* __restrict__ Bk) {
  int sel = blockIdx.x >> 10;
  int col = blockIdx.x & 1023;    // h*64 + k
  const float* W = sel ? Wk : Wq;
  u16* Bt = sel ? Bk : Bq;
  int h = col >> 6, k = col & 63;
  int tid = threadIdx.x;
  const float* w = W + ((size_t)h * DD) * DKK + k;
  __shared__ float red[256];
  float m = -1e30f;
  for (int d = k + tid; d < DD; d += 256) m = fmaxf(m, w[(size_t)d * DKK]);
  red[tid] = m; __syncthreads();
  for (int s = 128; s > 0; s >>= 1) { if (tid < s) red[tid] = fmaxf(red[tid], red[tid + s]); __syncthreads(); }
  m = red[0]; __syncthreads();
  float sum = 0.f;
  for (int d = k + tid; d < DD; d += 256) sum += __expf(w[(size_t)d * DKK] - m);
  red[tid] = sum; __syncthreads();
  for (int s = 128; s > 0; s >>= 1) { if (tid < s) red[tid] += red[tid + s]; __syncthreads(); }
  float inv = 1.f / red[0];
  for (int d = tid; d < DD; d += 256) {
    float v = (d >= k) ? __expf(w[(size_t)d * DKK] - m) * inv : 0.f;
    Bt[(size_t)col * DD + d] = f2bf(v);
  }
}

// ---------------- reorder (H, D, DK) -> bf16 B[n=h*64+k][d]; z picks one of 3 weights ----------------
__global__ __launch_bounds__(256) void k_reorder3_bf(const float* __restrict__ W0, const float* __restrict__ W1,
                                                     const float* __restrict__ W2, u16* __restrict__ Bt0) {
  int z = blockIdx.z;
  const float* W = (z == 0) ? W0 : ((z == 1) ? W1 : W2);
  u16* Bt = Bt0 + (size_t)z * 1024 * 1024;
  int d0 = blockIdx.x << 6, h = blockIdx.y;
  __shared__ float t[64][65];
  int tid = threadIdx.x;
  const float* src = W + (size_t)h * DD * DKK + (size_t)d0 * DKK;
  #pragma unroll
  for (int i = 0; i < 16; ++i) {
    int e = i * 256 + tid; int r = e >> 6, c = e & 63;
    t[r][c] = src[(size_t)r * DKK + c];
  }
  __syncthreads();
  #pragma unroll
  for (int i = 0; i < 16; ++i) {
    int e = i * 256 + tid; int c = e >> 6, r = e & 63;
    Bt[((size_t)(h * 64 + c)) * DD + d0 + r] = f2bf(t[r][c]);
  }
}

// ---------------- reorder single (H, D, DK) -> bf16 B[n][d] ----------------
__global__ __launch_bounds__(256) void k_reorder_w_bf(const float* __restrict__ W, u16* __restrict__ Bt) {
  int d0 = blockIdx.x << 6, h = blockIdx.y;
  __shared__ float t[64][65];
  int tid = threadIdx.x;
  const float* src = W + (size_t)h * DD * DKK + (size_t)d0 * DKK;
  #pragma unroll
  for (int i = 0; i < 16; ++i) {
    int e = i * 256 + tid; int r = e >> 6, c = e & 63;
    t[r][c] = src[(size_t)r * DKK + c];
  }
  __syncthreads();
  #pragma unroll
  for (int i = 0; i < 16; ++i) {
    int e = i * 256 + tid; int c = e >> 6, r = e & 63;
    Bt[((size_t)(h * 64 + c)) * DD + d0 + r] = f2bf(t[r][c]);
  }
}

// ---------------- transpose (K,N) f32 -> bf16 B[n][k] ----------------
__global__ __launch_bounds__(256) void k_transpose_bf(const float* __restrict__ W, u16* __restrict__ Bt) {
  int k0 = blockIdx.x << 6, n0 = blockIdx.y << 6;
  __shared__ float t[64][65];
  int tid = threadIdx.x;
  #pragma unroll
  for (int i = 0; i < 16; ++i) {
    int e = i * 256 + tid; int r = e >> 6, c = e & 63;
    t[r][c] = W[(size_t)(k0 + r) * DD + n0 + c];
  }
  __syncthreads();
  #pragma unroll
  for (int i = 0; i < 16; ++i) {
    int e = i * 256 + tid; int c = e >> 6, r = e & 63;
    Bt[(size_t)(n0 + c) * DD + k0 + r] = f2bf(t[r][c]);
  }
}

// ---------------- MFMA NT GEMM: C = A(MxK) * B(NxK)^T (bf16 in, f32 acc) ----------------
// 128x128 tile, BK=32, 512 threads (8 waves 2x4, wave-tile 64x32), XCD swizzle,
// split-K via blockIdx.z, bf16 outputs via per-wave LDS slab.
// T4-lite pipeline: 3-buffer rotation, issue-ahead-2, counted s_waitcnt vmcnt(2).
// T2 chunk-XOR swizzle: LDS (row, chunk) holds global chunk (chunk ^ ((row>>1)&3));
// source pre-swizzled per-lane (rule #21: linear GLDS dest + inv-swz source + swz read).
// Spreads the 16 fr-lanes across all 8 four-bank slots: 8-way -> 2-way (free).
__global__ __launch_bounds__(512) void k_mfma_nt(
    const u16* __restrict__ A, const u16* __restrict__ A2,
    const u16* __restrict__ B,
    u16* __restrict__ P0, u16* __restrict__ P1, u16* __restrict__ P2, u16* __restrict__ P3,
    u16* __restrict__ Cb, u16* __restrict__ Cb2, u16* __restrict__ Ct,
    const float* __restrict__ bias, int relu, int mode, int M, int N, int K) {
  __shared__ u16 SLDS[24576];   // A bufs [0,12288), B bufs [12288,24576); epilogue reuses [0,16384)
  int bx = blockIdx.x, by = blockIdx.y;
  swz_block(bx, by);
  int tid = threadIdx.x, wave = tid >> 6, lane = tid & 63;
  int row0 = by << 7, col0 = bx << 7;
  int wm = (wave >> 2) << 6;        // 0 / 64
  int wn = (wave & 3) << 5;         // 0 / 32 / 64 / 96

  const u16* Asrc = (mode == 1 && A2 && (col0 >> 10) > 0) ? A2 : A;

  int Ksl = K / gridDim.z;
  int kbase = blockIdx.z * Ksl;
  int nt = Ksl >> 5;                // K-steps of 32

  f32x4 acc[4][2];
  #pragma unroll
  for (int m = 0; m < 4; ++m)
    #pragma unroll
    for (int n = 0; n < 2; ++n) acc[m][n] = f32x4{0.f, 0.f, 0.f, 0.f};

  // staging: [128][32] bf16 = 8 KB per matrix; 512 threads x 16B = exactly one GLDS each.
  // source chunk pre-swizzled so LDS (srow, tid&3) holds global chunk (tid&3)^((srow>>1)&3);
  // same 64B global segment per 4 threads -> coalescing unchanged.
  int srow = tid >> 2;
  int scol = ((tid & 3) ^ ((srow >> 1) & 3)) << 3;
  const u16* Ag = Asrc + (size_t)(row0 + srow) * K + scol;
  const u16* Bg = B + (size_t)(col0 + srow) * K + scol;
  int wbase = wave << 9;            // u16 offset of this wave's 1KB chunk

  // read side: logical chunk (lane>>4) lives at physical chunk (lane>>4)^((fr>>1)&3).
  // invariant under row += 16, so fragment offsets m*16*32 stay compile-time.
  int fr = lane & 15;
  int kg = (((lane >> 4) ^ ((fr >> 1) & 3))) << 3;
  int ardo = (wm + fr) * 32 + kg;
  int brdo = 12288 + (wn + fr) * 32 + kg;

  auto STAGE = [&](int buf, int k0) {
    GLDS(Ag + k0, SLDS + buf * 4096 + wbase);
    GLDS(Bg + k0, SLDS + 12288 + buf * 4096 + wbase);
  };

  STAGE(0, kbase);
  if (nt > 1) STAGE(1, kbase + 32);
  int bufT = 0;
  for (int t = 0; t < nt; ++t) {
    // wait for buf[t]'s own loads; STAGE(t+1) (2 loads) may stay in flight
    if (t + 1 < nt) asm volatile("s_waitcnt vmcnt(2)" ::: "memory");
    else            asm volatile("s_waitcnt vmcnt(0)" ::: "memory");
    __builtin_amdgcn_s_barrier();     // all threads' buf[t] chunks landed
    asm volatile("" ::: "memory");
    if (t + 2 < nt) {
      int b2 = bufT + 2; if (b2 >= 3) b2 -= 3;
      STAGE(b2, kbase + (t + 2) * 32);  // overwrites buf[t-1]: safe, reads done pre-barrier
    }
    const u16* Ard = SLDS + bufT * 4096 + ardo;
    const u16* Brd = SLDS + bufT * 4096 + brdo;
    s16x8 aF[4], bF[2];
    #pragma unroll
    for (int m = 0; m < 4; ++m) aF[m] = *(const s16x8*)(Ard + m * 16 * 32);
    #pragma unroll
    for (int n = 0; n < 2; ++n) bF[n] = *(const s16x8*)(Brd + n * 16 * 32);
    #pragma unroll
    for (int m = 0; m < 4; ++m)
      #pragma unroll
      for (int n = 0; n < 2; ++n)
        acc[m][n] = __builtin_amdgcn_mfma_f32_16x16x32_bf16(aF[m], bF[n], acc[m][n], 0, 0, 0);
    ++bufT; if (bufT == 3) bufT = 0;
  }
  __syncthreads();                    // epilogue slab aliases staging bufs: wait all reads done

  int fq = (lane >> 4) << 2;

  // ---- all outputs bf16 via per-wave [16][40] LDS slab, 4 m-passes -> coalesced stores ----
  u16* dstRow = nullptr; u16* dstCol = nullptr;
  int rowPitch = 1024, colBase = col0 & 1023;
  if (mode == 0) {
    rowPitch = N; colBase = col0;
    if (gridDim.z > 1) {
      int z = blockIdx.z;
      dstRow = (z == 0) ? P0 : ((z == 1) ? P1 : ((z == 2) ? P2 : P3));
    } else dstRow = Cb;
  }
  else if (mode == 1) { int q = col0 >> 10; if (q == 0) dstRow = Cb; else if (q == 1) dstRow = Cb2; else dstCol = Ct; }
  else { int q = col0 >> 10; if (q == 0) dstRow = Cb; else dstCol = Ct; }

  u16* Ep = SLDS + wave * 2048;   // wave-private slab (16*40=640 u16 used)
  #pragma unroll
  for (int m = 0; m < 4; ++m) {
    #pragma unroll
    for (int n = 0; n < 2; ++n) {
      int col = col0 + wn + n * 16 + fr;
      float bs = bias ? bias[col] : 0.f;
      #pragma unroll
      for (int r = 0; r < 4; ++r) {
        float v = acc[m][n][r] + bs;
        if (relu) v = fmaxf(v, 0.f);
        Ep[(fq + r) * 40 + n * 16 + fr] = f2bf(v);
      }
    }
    if (dstRow) {
      int rw = lane >> 2, seg = lane & 3;                  // 16 rows x 4 segs of 8
      const u16* src = Ep + rw * 40 + seg * 8;
      u16* gd = dstRow + (size_t)(row0 + wm + m * 16 + rw) * rowPitch + colBase + wn + seg * 8;
      *(uint4*)gd = *(const uint4*)src;                    // 4 lanes x 16B = 64B line
    } else {
      int c = lane >> 1, half = lane & 1;                  // 32 cols x 2 halves of 8 rows
      u16 tmp[8];
      #pragma unroll
      for (int j = 0; j < 8; ++j) tmp[j] = Ep[(half * 8 + j) * 40 + c];
      u16* gd = dstCol + (size_t)(colBase + wn + c) * 4096 + row0 + wm + m * 16 + half * 8;
      *(uint4*)gd = *(const uint4*)tmp;                    // 2 lanes x 16B = 32B per col
    }
  }
}

// ---------------- stage one 64x64 bf16 tile (512 threads, 1 uint4 each) -> LDS [64][72] ----------------
static __device__ __forceinline__ void stage_tile512(const u16* __restrict__ g, int gp, u16* L, int tid) {
  int row = tid >> 3, col8 = (tid & 7) << 3;
  *(uint4*)(L + row * 72 + col8) = *(const uint4*)(g + (size_t)row * gp + col8);
}

// ---------------- attention pass 1 (MFMA, 8 waves, 2 s-tiles/block) ----------------
// csum[s] = sum_t exp(S[t][s]); no-max softmax (S small, exp-safe; shift-invariant).
__global__ __launch_bounds__(512) void k_attn_stats_mfma(const u16* __restrict__ Qb, const u16* __restrict__ Kb,
                                                         float* __restrict__ csum) {
  __shared__ u16 Ks[2 * 4608];
  __shared__ u16 Qs[4608];
  int tid = threadIdx.x, wave = tid >> 6, lane = tid & 63;
  int tileIdx, bh;
  swz_attn(tileIdx, bh);
  int b = bh >> 4, h = bh & 15;
  int s0 = tileIdx << 7;                  // 128 s-cols per block
  int tile = wave >> 2, sw = wave & 3;
  stage_tile512(Kb + ((size_t)(b * TT + s0)) * DD + h * 64, DD, Ks, tid);
  stage_tile512(Kb + ((size_t)(b * TT + s0 + 64)) * DD + h * 64, DD, Ks + 4608, tid);
  int row = tid >> 3, col8 = (tid & 7) << 3;
  const u16* Qg = Qb + ((size_t)(b * TT) + row) * DD + h * 64 + col8;
  uint4 qreg = *(const uint4*)Qg;          // tile t0=0
  __syncthreads();                          // Ks visible
  int fr = lane & 15, g = lane >> 4;
  const u16* Bbase = Ks + tile * 4608 + (sw * 16 + fr) * 72 + g * 8;   // B-frag: K rows (n = s)
  const u16* Abase = Qs + fr * 72 + g * 8;                             // A-frag: Q rows (m = t)
  s16x8 bF0 = *(const s16x8*)(Bbase);
  s16x8 bF1 = *(const s16x8*)(Bbase + 32);
  float sum = 0.f;
  for (int t0 = 0; t0 < TT; t0 += 64) {
    __syncthreads();                        // prior Qs reads done
    *(uint4*)(Qs + row * 72 + col8) = qreg;
    __syncthreads();                        // Qs visible
    if (t0 + 64 < TT) qreg = *(const uint4*)(Qg + (size_t)(t0 + 64) * DD);
    #pragma unroll
    for (int mt = 0; mt < 4; ++mt) {
      f32x4 acc = f32x4{0.f, 0.f, 0.f, 0.f};
      s16x8 a0 = *(const s16x8*)(Abase + mt * 16 * 72);
      s16x8 a1 = *(const s16x8*)(Abase + mt * 16 * 72 + 32);
      acc = __builtin_amdgcn_mfma_f32_16x16x32_bf16(a0, bF0, acc, 0, 0, 0);
      acc = __builtin_amdgcn_mfma_f32_16x16x32_bf16(a1, bF1, acc, 0, 0, 0);
      sum += __expf(acc[0] * 0.125f) + __expf(acc[1] * 0.125f)
           + __expf(acc[2] * 0.125f) + __expf(acc[3] * 0.125f);
    }
  }
  sum += __shfl_xor(sum, 16, 64);
  sum += __shfl_xor(sum, 32, 64);
  if (lane < 16) csum[(size_t)bh * TT + s0 + tile * 64 + sw * 16 + lane] = sum;
}

// ---------------- attention pass 2 (MFMA, 8 waves, 2 t-tiles/block) ----------------
__global__ __launch_bounds__(512) void k_attn_apply_mfma(const u16* __restrict__ Qb, const u16* __restrict__ Kb,
                                                         const u16* __restrict__ Vt,
                                                         const float* __restrict__ csum,
                                                         u16* __restrict__ Op) {
  __shared__ u16 Qs[2 * 4608];
  __shared__ u16 KV2[2 * 4608];    // Ks | VTs; reused by the write epilogue
  __shared__ u16 Pl[8 * 1024];     // per-wave [16 t][64 s] bf16, XOR-swizzled
  __shared__ float rcsL[64];
  u16* Ks = KV2;
  u16* VTs = KV2 + 4608;
  int tid = threadIdx.x, wave = tid >> 6, lane = tid & 63;
  int tileIdx, bh;
  swz_attn(tileIdx, bh);
  int b = bh >> 4, h = bh & 15;
  int t0 = tileIdx << 7;                  // 128 t-rows per block
  int tile = wave >> 2, tw = wave & 3;
  stage_tile512(Qb + ((size_t)(b * TT + t0)) * DD + h * 64, DD, Qs, tid);
  stage_tile512(Qb + ((size_t)(b * TT + t0 + 64)) * DD + h * 64, DD, Qs + 4608, tid);
  int row = tid >> 3, col8 = (tid & 7) << 3;
  const u16* Kg = Kb + ((size_t)(b * TT) + row) * DD + h * 64 + col8;
  const u16* Vg = Vt + ((size_t)(h * 64) + row) * 4096 + (size_t)b * TT + col8;
  const size_t cbase = (size_t)bh * TT;
  uint4 kreg = *(const uint4*)Kg;          // s0 = 0
  uint4 vreg = *(const uint4*)Vg;
  float rc0 = (tid < 64) ? csum[cbase + tid] : 0.f;
  __syncthreads();                          // Qs visible
  int fr = lane & 15, g = lane >> 4;
  const u16* QbF = Qs + tile * 4608 + (tw * 16 + fr) * 72 + g * 8;   // B-frag (n = t)
  const u16* KaF = Ks + fr * 72 + g * 8;                             // A-frag rows s
  char* Pw = (char*)(Pl + wave * 1024);
  uint swz = ((uint)(lane & 7)) << 4;
  s16x8 qF0 = *(const s16x8*)(QbF);
  s16x8 qF1 = *(const s16x8*)(QbF + 32);
  f32x4 acc_o[4];
  #pragma unroll
  for (int nt = 0; nt < 4; ++nt) acc_o[nt] = f32x4{0.f, 0.f, 0.f, 0.f};

  for (int s0 = 0; s0 < TT; s0 += 64) {
    __syncthreads();                        // prior Ks/VTs reads done
    *(uint4*)(Ks + row * 72 + col8) = kreg;
    *(uint4*)(VTs + row * 72 + col8) = vreg;
    if (tid < 64) rcsL[tid] = 1.f / rc0;
    __syncthreads();                        // visible
    if (s0 + 64 < TT) {                     // issue next-tile loads; hide under compute
      kreg = *(const uint4*)(Kg + (size_t)(s0 + 64) * DD);
      vreg = *(const uint4*)(Vg + s0 + 64);
      if (tid < 64) rc0 = csum[cbase + s0 + 64 + tid];
    }
    // S^T tiles + exp -> P (per-wave)
    #pragma unroll
    for (int mt = 0; mt < 4; ++mt) {
      f32x4 acc = f32x4{0.f, 0.f, 0.f, 0.f};
      s16x8 a0 = *(const s16x8*)(KaF + mt * 16 * 72);
      s16x8 a1 = *(const s16x8*)(KaF + mt * 16 * 72 + 32);
      acc = __builtin_amdgcn_mfma_f32_16x16x32_bf16(a0, qF0, acc, 0, 0, 0);
      acc = __builtin_amdgcn_mfma_f32_16x16x32_bf16(a1, qF1, acc, 0, 0, 0);
      f32x4 rc4 = *(const f32x4*)&rcsL[mt * 16 + g * 4];
      u16 pb[4];
      #pragma unroll
      for (int r = 0; r < 4; ++r)
        pb[r] = f2bf(__expf(acc[r] * 0.125f) * rc4[r]);
      uint woff = (uint)fr * 128 + (uint)(mt * 16 + g * 4) * 2;
      uint2 wv; wv.x = (u32)pb[0] | ((u32)pb[1] << 16); wv.y = (u32)pb[2] | ((u32)pb[3] << 16);
      *(uint2*)(Pw + (woff ^ swz)) = wv;
    }
    // PV: A = P (own wave's tile), B = V^T
    uint rbase = (uint)fr * 128;
    s16x8 pF0 = *(const s16x8*)(Pw + ((rbase + g * 16) ^ swz));
    s16x8 pF1 = *(const s16x8*)(Pw + ((rbase + 64 + g * 16) ^ swz));
    #pragma unroll
    for (int nt = 0; nt < 4; ++nt) {
      s16x8 v0 = *(const s16x8*)(VTs + (nt * 16 + fr) * 72 + g * 8);
      s16x8 v1 = *(const s16x8*)(VTs + (nt * 16 + fr) * 72 + 32 + g * 8);
      acc_o[nt] = __builtin_amdgcn_mfma_f32_16x16x32_bf16(pF0, v0, acc_o[nt], 0, 0, 0);
      acc_o[nt] = __builtin_amdgcn_mfma_f32_16x16x32_bf16(pF1, v1, acc_o[nt], 0, 0, 0);
    }
  }
  // write epilogue: per-wave LDS transpose (reuse KV2) -> coalesced 32B/lane stores
  __syncthreads();                         // all waves done reading Ks/VTs
  u16* Ep = KV2 + wave * 1088;             // per-wave [16][68]
  #pragma unroll
  for (int nt = 0; nt < 4; ++nt)
    #pragma unroll
    for (int r = 0; r < 4; ++r)
      Ep[(g * 4 + r) * 68 + nt * 16 + fr] = f2bf(acc_o[nt][r]);
  {
    int rw = lane >> 2, seg = lane & 3;
    const u16* src = Ep + rw * 68 + seg * 16;
    u16* gd = Op + ((size_t)(b * TT + t0 + tile * 64 + tw * 16 + rw)) * DD + h * 64 + seg * 16;
    #pragma unroll
    for (int i = 0; i < 4; ++i) *(uint2*)(gd + i * 4) = *(const uint2*)(src + i * 4);
  }
}

// ---------------- O = norm(sum of bf16 partials + bias + residual), ddof=1 ----------------
__global__ __launch_bounds__(256) void k_add_norm(const u16* __restrict__ A, const u16* __restrict__ A2,
                                                  const u16* __restrict__ A3, const u16* __restrict__ A4,
                                                  const float* __restrict__ bias,
                                                  const float* __restrict__ Bv,
                                                  float* __restrict__ O, u16* __restrict__ Ob) {
  int row = blockIdx.x, tid = threadIdx.x;
  size_t base = (size_t)row * DD;
  int c0 = tid * 4;
  __shared__ float red[256];
  float v[4];
  {
    ushort4 a = *(const ushort4*)(A + base + c0);
    float4 bv = *(const float4*)(Bv + base + c0);
    v[0] = bf2f(a.x) + bv.x; v[1] = bf2f(a.y) + bv.y;
    v[2] = bf2f(a.z) + bv.z; v[3] = bf2f(a.w) + bv.w;
  }
  if (A2) {
    ushort4 a = *(const ushort4*)(A2 + base + c0);
    v[0] += bf2f(a.x); v[1] += bf2f(a.y); v[2] += bf2f(a.z); v[3] += bf2f(a.w);
  }
  if (A3) {
    ushort4 a = *(const ushort4*)(A3 + base + c0);
    v[0] += bf2f(a.x); v[1] += bf2f(a.y); v[2] += bf2f(a.z); v[3] += bf2f(a.w);
  }
  if (A4) {
    ushort4 a = *(const ushort4*)(A4 + base + c0);
    v[0] += bf2f(a.x); v[1] += bf2f(a.y); v[2] += bf2f(a.z); v[3] += bf2f(a.w);
  }
  if (bias) {
    float4 bs = *(const float4*)(bias + c0);
    v[0] += bs.x; v[1] += bs.y; v[2] += bs.z; v[3] += bs.w;
  }
  float s = v[0] + v[1] + v[2] + v[3];
  red[tid] = s; __syncthreads();
  for (int t = 128; t > 0; t >>= 1) { if (tid < t) red[tid] += red[tid + t]; __syncthreads(); }
  float mean = red[0] * (1.f / 1024.f);
  __syncthreads();
  float vs = 0.f;
  #pragma unroll
  for (int i = 0; i < 4; ++i) { float d = v[i] - mean; vs += d * d; }
  red[tid] = vs; __syncthreads();
  for (int t = 128; t > 0; t >>= 1) { if (tid < t) red[tid] += red[tid + t]; __syncthreads(); }
  float inv = rsqrtf(red[0] * (1.f / 1023.f));
  float o[4];
  #pragma unroll
  for (int i = 0; i < 4; ++i) o[i] = (v[i] - mean) * inv;
  *(float4*)(O + base + c0) = *(float4*)o;
  if (Ob) {
    u16 ob[4] = { f2bf(o[0]), f2bf(o[1]), f2bf(o[2]), f2bf(o[3]) };
    *(ushort4*)(Ob + base + c0) = *(ushort4*)ob;
  }
}

extern "C" void kernel_launch(void* const* d_in, const int* in_sizes, int n_in,
                              void* d_out, int out_size, void* d_ws, size_t ws_size,
                              hipStream_t stream) {
  (void)in_sizes; (void)n_in; (void)out_size; (void)ws_size;
  const float* x    = (const float*)d_in[0];
  const float* y    = (const float*)d_in[1];
  const float* Wq1  = (const float*)d_in[2];
  const float* Wk1  = (const float*)d_in[3];
  const float* Wv1  = (const float*)d_in[4];
  const float* Wo1  = (const float*)d_in[5];
  const float* Wq2  = (const float*)d_in[6];
  const float* Wk2  = (const float*)d_in[7];
  const float* Wv2  = (const float*)d_in[8];
  const float* Wo2  = (const float*)d_in[9];
  const float* w_in  = (const float*)d_in[10];
  const float* b_in  = (const float*)d_in[11];
  const float* w_out = (const float*)d_in[12];
  const float* b_out = (const float*)d_in[13];

  float* ws = (float*)d_ws;
  size_t off = 0;
  auto allocw = [&](size_t nw) { float* p = ws + off; off += nw; return p; };
  const size_t MR = (size_t)BB * TT;           // 4096
  const size_t ND = MR * DD;                   // 4.19M elems

  u16* Bq   = (u16*)allocw(512 * 1024);        // Bq|Bk|Bv contiguous => fused B (3072 x 1024)
  u16* Bk   = (u16*)allocw(512 * 1024);
  u16* Bv   = (u16*)allocw(512 * 1024);
  u16* Bwo  = (u16*)allocw(512 * 1024);
  u16* Wi   = (u16*)allocw(2 * 1024 * 1024);
  u16* Wob  = (u16*)allocw(2 * 1024 * 1024);
  u16* xbf  = (u16*)allocw(ND / 2);
  u16* ybf  = (u16*)allocw(ND / 2);
  u16* REG  = (u16*)allocw(ND * 2);
  float* ff2  = allocw(ND);                    // partial slabs p0|p1 (bf16)
  float* out1 = allocw(ND);                    // residual; later partial slabs p2|p3
  float* out2 = allocw(ND);
  float* csum = allocw((size_t)BB * HH * TT);

  u16* Qb = REG;
  u16* Kb = REG + ND;
  u16* Vt = REG + 2 * ND;   // V col-major (1024 x 4096), pitch 4096
  u16* Mb = REG + 3 * ND;   // mhaO; also out1_bf between layers
  u16* ff1b = REG;
  u16* out2bf = ybf;
  float* doutHi = (float*)d_out + ND;
  u16* p0 = (u16*)ff2;          // bf16 partial slabs
  u16* p1 = (u16*)ff2 + ND;
  u16* p2 = (u16*)out1;         // only after out1 is dead (post-L2-norm)
  u16* p3 = (u16*)out1 + ND;
  (void)Bv;

  dim3 blk(256), blkG(512), blkA(512);
  dim3 gPrep(16384);
  dim3 gSm2(2048);
  dim3 gRw(16, 16);
  dim3 gRw3(16, 16, 3);
  dim3 gQKV(24, 32);         // N=3072
  dim3 gP2(8, 32, 2);        // N=1024, split-K=2
  dim3 gF1(32, 32);          // N=4096
  dim3 gFF2(8, 32, 4);       // N=1024, split-K=4 (K=4096)
  dim3 gAttn(8, 64);         // (tiles, bh) + swz_attn -> per-XCD bh grouping
  dim3 gNorm(MR);

  // merged prep: x->dout+xbf, y->ybf, w_in->Wi, w_out->Wob
  k_prep<<<gPrep, blk, 0, stream>>>(x, (float*)d_out, xbf, y, ybf, w_in, Wi, w_out, Wob);

  // ---- Layer 1: masked self-attention on y ----
  k_softmax_w2_bf<<<gSm2, blk, 0, stream>>>(Wq1, Wk1, Bq, Bk);
  k_reorder_w_bf<<<gRw, blk, 0, stream>>>(Wv1, Bv);
  k_transpose_bf<<<gRw, blk, 0, stream>>>(Wo1, Bwo);
  k_mfma_nt<<<gQKV, blkG, 0, stream>>>(ybf, nullptr, Bq, nullptr, nullptr, nullptr, nullptr, Qb, Kb, Vt, nullptr, 0, 1, 4096, 3072, 1024);
  k_attn_stats_mfma<<<gAttn, blkA, 0, stream>>>(Qb, Kb, csum);
  k_attn_apply_mfma<<<gAttn, blkA, 0, stream>>>(Qb, Kb, Vt, csum, Mb);
  // out-proj split-K=2: bf16 partials p0,p1
  k_mfma_nt<<<gP2, blkG, 0, stream>>>(Mb, nullptr, Bwo, p0, p1, nullptr, nullptr, nullptr, nullptr, nullptr, nullptr, 0, 0, 4096, 1024, 1024);
  k_add_norm<<<gNorm, blk, 0, stream>>>(p0, p1, nullptr, nullptr, nullptr, y, out1, Mb /* out1_bf */);

  // ---- Layer 2: cross-attention (Q from out1, K/V from x) ----
  k_reorder3_bf<<<gRw3, blk, 0, stream>>>(Wq2, Wk2, Wv2, Bq);
  k_transpose_bf<<<gRw, blk, 0, stream>>>(Wo2, Bwo);
  // fused QKV2: Q-cols read A=Mb (out1_bf), K/V-cols read A2=xbf; B=[Bq2|Bk2|Bv2]
  k_mfma_nt<<<gQKV, blkG, 0, stream>>>(Mb, xbf, Bq, nullptr, nullptr, nullptr, nullptr, Qb, Kb, Vt, nullptr, 0, 1, 4096, 3072, 1024);
  k_attn_stats_mfma<<<gAttn, blkA, 0, stream>>>(Qb, Kb, csum);
  k_attn_apply_mfma<<<gAttn, blkA, 0, stream>>>(Qb, Kb, Vt, csum, Mb);
  // out-proj split-K=2: bf16 partials
  k_mfma_nt<<<gP2, blkG, 0, stream>>>(Mb, nullptr, Bwo, p0, p1, nullptr, nullptr, nullptr, nullptr, nullptr, nullptr, 0, 0, 4096, 1024, 1024);
  k_add_norm<<<gNorm, blk, 0, stream>>>(p0, p1, nullptr, nullptr, nullptr, out1, out2, out2bf);

  // ---- FF ----  (out1 dead from here; p2/p3 alias it)
  k_mfma_nt<<<gF1, blkG, 0, stream>>>(out2bf, nullptr, Wi, nullptr, nullptr, nullptr, nullptr, ff1b, nullptr, nullptr, b_in, 1, 0, 4096, 4096, 1024);
  // FF2 split-K=4: bf16 partials p0..p3; bias ONCE in final norm
  k_mfma_nt<<<gFF2, blkG, 0, stream>>>(ff1b, nullptr, Wob, p0, p1, p2, p3, nullptr, nullptr, nullptr, nullptr, 0, 0, 4096, 1024, 4096);
  k_add_norm<<<gNorm, blk, 0, stream>>>(p0, p1, p2, p3, b_out, out2, doutHi, nullptr);
}